// Round 3
// baseline (1214.910 us; speedup 1.0000x reference)
//
#include <hip/hip_runtime.h>
#include <hip/hip_bf16.h>

#define LNUM 2048
#define DNUM 2048
#define HNUM 16
#define DHNUM 128
#define MTOK 4096   // B*L
#define WINSZ 512

typedef __attribute__((ext_vector_type(8))) short bf16x8;
typedef __attribute__((ext_vector_type(4))) short bf16x4;
typedef __attribute__((ext_vector_type(4))) float f32x4;

#define GLOBAL_AS __attribute__((address_space(1)))
#define LDS_AS __attribute__((address_space(3)))

__device__ __forceinline__ unsigned short f2bf(float f) {
  union { float f; unsigned u; } v; v.f = f;
  unsigned r = v.u + 0x7FFFu + ((v.u >> 16) & 1u);
  return (unsigned short)(r >> 16);
}
__device__ __forceinline__ float bf2f(unsigned short h) {
  union { unsigned u; float f; } v; v.u = ((unsigned)h) << 16;
  return v.f;
}

// ---------------- weight fp32 -> bf16 convert ----------------
__global__ __launch_bounds__(256) void cvtw_k(
    const float* __restrict__ s0, const float* __restrict__ s1,
    const float* __restrict__ s2, const float* __restrict__ s3,
    unsigned short* __restrict__ d0, unsigned short* __restrict__ d1,
    unsigned short* __restrict__ d2, unsigned short* __restrict__ d3) {
  const int z = blockIdx.y;
  const float* s = z==0?s0:z==1?s1:z==2?s2:s3;
  unsigned short* d = z==0?d0:z==1?d1:z==2?d2:d3;
  const size_t i = (size_t)blockIdx.x * 256 + threadIdx.x;
  const float4* sp = (const float4*)s + i*2;
  float4 a = sp[0], b = sp[1];
  ushort4 oa; oa.x=f2bf(a.x); oa.y=f2bf(a.y); oa.z=f2bf(a.z); oa.w=f2bf(a.w);
  ushort4 ob; ob.x=f2bf(b.x); ob.y=f2bf(b.y); ob.z=f2bf(b.z); ob.w=f2bf(b.w);
  ((ushort4*)d)[i*2] = oa; ((ushort4*)d)[i*2+1] = ob;
}

// ---------------- RMSNorm -> bf16 ----------------
__global__ __launch_bounds__(256) void rmsnorm_k(const float* __restrict__ x,
                                                 const float* __restrict__ w,
                                                 unsigned short* __restrict__ h) {
  const int row = blockIdx.x;
  const int t = threadIdx.x;
  const float4* xr = (const float4*)(x + (size_t)row * DNUM);
  float4 v0 = xr[t];
  float4 v1 = xr[t + 256];
  float ss = v0.x*v0.x + v0.y*v0.y + v0.z*v0.z + v0.w*v0.w +
             v1.x*v1.x + v1.y*v1.y + v1.z*v1.z + v1.w*v1.w;
  #pragma unroll
  for (int off = 32; off > 0; off >>= 1) ss += __shfl_xor(ss, off);
  __shared__ float red[4];
  if ((t & 63) == 0) red[t >> 6] = ss;
  __syncthreads();
  const float r = rsqrtf((red[0]+red[1]+red[2]+red[3]) * (1.0f/DNUM) + 1e-6f);
  const float4* wr4 = (const float4*)w;
  float4 w0 = wr4[t], w1 = wr4[t+256];
  ushort4 o0, o1;
  o0.x = f2bf(v0.x*r*w0.x); o0.y = f2bf(v0.y*r*w0.y);
  o0.z = f2bf(v0.z*r*w0.z); o0.w = f2bf(v0.w*r*w0.w);
  o1.x = f2bf(v1.x*r*w1.x); o1.y = f2bf(v1.y*r*w1.y);
  o1.z = f2bf(v1.z*r*w1.z); o1.w = f2bf(v1.w*r*w1.w);
  ushort4* hp = (ushort4*)(h + (size_t)row * DNUM);
  hp[t] = o0; hp[t + 256] = o1;
}

// ---------------- LoRA t = src @ A^T  (rank 16) ----------------
__global__ __launch_bounds__(256) void lorat_k(const unsigned short* __restrict__ src,
    const float* __restrict__ A0, const float* __restrict__ A1, const float* __restrict__ A2,
    float* __restrict__ T0, float* __restrict__ T1, float* __restrict__ T2) {
  const int wv = threadIdx.x >> 6, lane = threadIdx.x & 63;
  const int row = blockIdx.x * 4 + wv;
  const int z = blockIdx.y;
  const float* A = z==0 ? A0 : (z==1 ? A1 : A2);
  float* T = z==0 ? T0 : (z==1 ? T1 : T2);
  const unsigned short* s = src + (size_t)row * DNUM;
  float acc[16];
  #pragma unroll
  for (int r2=0;r2<16;r2++) acc[r2]=0.f;
  for (int j = 0; j < DNUM; j += 64) {
    const float hv = bf2f(s[j + lane]);
    #pragma unroll
    for (int r2 = 0; r2 < 16; r2++)
      acc[r2] = fmaf(hv, A[(size_t)r2*DNUM + j + lane], acc[r2]);
  }
  #pragma unroll
  for (int r2 = 0; r2 < 16; r2++) {
    #pragma unroll
    for (int off = 32; off > 0; off >>= 1) acc[r2] += __shfl_xor(acc[r2], off);
  }
  if (lane == 0) {
    #pragma unroll
    for (int r2 = 0; r2 < 16; r2++) T[row*16 + r2] = acc[r2];
  }
}

// ---------------- GEMM: C = A(bf16,MxK) @ W^T(bf16,NxK) + lscale*(T @ LB^T) [+resid] ----------------
template<bool OUTF32>
__global__ __launch_bounds__(256) void gemm_k(
    const unsigned short* __restrict__ Am,
    const unsigned short* __restrict__ W0, const unsigned short* __restrict__ W1, const unsigned short* __restrict__ W2,
    const float* __restrict__ T0, const float* __restrict__ T1, const float* __restrict__ T2,
    const float* __restrict__ B0, const float* __restrict__ B1, const float* __restrict__ B2,
    unsigned short* __restrict__ O0, unsigned short* __restrict__ O1, unsigned short* __restrict__ O2,
    const float* __restrict__ resid, float* __restrict__ Of, float lscale)
{
  const int z = blockIdx.z;
  const unsigned short* W = z==0?W0:(z==1?W1:W2);
  const float* T = z==0?T0:(z==1?T1:T2);
  const float* LB = z==0?B0:(z==1?B1:B2);
  unsigned short* Ob = z==0?O0:(z==1?O1:O2);

  const int row0 = blockIdx.y * 128;
  const int col0 = blockIdx.x * 128;
  const int tid = threadIdx.x;
  const int wv = tid >> 6, lane = tid & 63;
  const int wr = wv >> 1, wc = wv & 1;
  const int g = lane >> 4, r4 = lane & 15;

  __shared__ unsigned short lds[2][2][4096];   // [buf][A/B][128*32]

  f32x4 acc[4][4];
  #pragma unroll
  for (int m=0;m<4;m++)
    #pragma unroll
    for (int n=0;n<4;n++) acc[m][n] = f32x4{0.f,0.f,0.f,0.f};

  auto stage = [&](int buf, int k0) {
    #pragma unroll
    for (int qq = 0; qq < 2; qq++) {
      const int chunk = wv*2 + qq;
      const int rp = chunk*16 + (lane >> 2);
      const int cl = (lane & 3) ^ ((rp >> 1) & 3);   // XOR swizzle (involution)
      const unsigned short* ga = Am + (size_t)(row0 + rp) * DNUM + k0 + cl*8;
      __builtin_amdgcn_global_load_lds((const GLOBAL_AS void*)ga,
          (LDS_AS void*)&lds[buf][0][chunk*512], 16, 0, 0);
      const unsigned short* gb = W + (size_t)(col0 + rp) * DNUM + k0 + cl*8;
      __builtin_amdgcn_global_load_lds((const GLOBAL_AS void*)gb,
          (LDS_AS void*)&lds[buf][1][chunk*512], 16, 0, 0);
    }
  };

  stage(0, 0);
  const int nk = DNUM / 32;
  for (int kt = 0; kt < nk; kt++) {
    __syncthreads();
    if (kt + 1 < nk) stage((kt+1) & 1, (kt+1)*32);
    const unsigned short* As = &lds[kt&1][0][0];
    const unsigned short* Bs = &lds[kt&1][1][0];
    bf16x8 af[4], bb[4];
    #pragma unroll
    for (int m = 0; m < 4; m++) {
      const int R = wr*64 + m*16 + r4;
      af[m] = *(const bf16x8*)((const char*)As + R*64 + ((g ^ ((R>>1)&3))*16));
    }
    #pragma unroll
    for (int n = 0; n < 4; n++) {
      const int R = wc*64 + n*16 + r4;
      bb[n] = *(const bf16x8*)((const char*)Bs + R*64 + ((g ^ ((R>>1)&3))*16));
    }
    #pragma unroll
    for (int m = 0; m < 4; m++)
      #pragma unroll
      for (int n = 0; n < 4; n++)
        acc[m][n] = __builtin_amdgcn_mfma_f32_16x16x32_bf16(af[m], bb[n], acc[m][n], 0, 0, 0);
  }

  // epilogue: + lscale * (T_row . LB_col) [+ residual]
  #pragma unroll
  for (int m = 0; m < 4; m++) {
    #pragma unroll
    for (int rg = 0; rg < 4; rg++) {
      const int row = row0 + wr*64 + m*16 + 4*g + rg;
      const float4* Tr = (const float4*)(T + (size_t)row * 16);
      const float4 t0 = Tr[0], t1 = Tr[1], t2 = Tr[2], t3 = Tr[3];
      #pragma unroll
      for (int n = 0; n < 4; n++) {
        const int col = col0 + wc*64 + n*16 + r4;
        const float4* Lr = (const float4*)(LB + (size_t)col * 16);
        const float4 l0 = Lr[0], l1 = Lr[1], l2 = Lr[2], l3 = Lr[3];
        const float dot = t0.x*l0.x + t0.y*l0.y + t0.z*l0.z + t0.w*l0.w
                        + t1.x*l1.x + t1.y*l1.y + t1.z*l1.z + t1.w*l1.w
                        + t2.x*l2.x + t2.y*l2.y + t2.z*l2.z + t2.w*l2.w
                        + t3.x*l3.x + t3.y*l3.y + t3.z*l3.z + t3.w*l3.w;
        const float val = acc[m][n][rg] + lscale * dot;
        if constexpr (OUTF32) {
          Of[(size_t)row * DNUM + col] = val + resid[(size_t)row * DNUM + col];
        } else {
          Ob[(size_t)row * DNUM + col] = f2bf(val);
        }
      }
    }
  }
}

// ---------------- RoPE in-place (Q also pre-scaled by 1/sqrt(DH)) ----------------
__global__ __launch_bounds__(256) void rope_k(unsigned short* __restrict__ Qm,
                                              unsigned short* __restrict__ Km) {
  const int u = blockIdx.x * 256 + threadIdx.x;
  const int t = u & 63;
  const int hh = (u >> 6) & (HNUM-1);
  const int i = u >> 10;
  const int l = i & (LNUM - 1);
  const float theta = __expf(-(float)t * 0.14391156831212787f);  // ln(10000)/64
  const float ang = (float)l * theta;
  float sn, cs;
  __sincosf(ang, &sn, &cs);
  const size_t base = (size_t)i * DNUM + hh * DHNUM + t;
  const float qs = 0.08838834764831845f;  // 1/sqrt(128)
  const float q1 = bf2f(Qm[base]), q2 = bf2f(Qm[base + 64]);
  Qm[base]      = f2bf((q1*cs - q2*sn) * qs);
  Qm[base + 64] = f2bf((q2*cs + q1*sn) * qs);
  const float k1 = bf2f(Km[base]), k2 = bf2f(Km[base + 64]);
  Km[base]      = f2bf(k1*cs - k2*sn);
  Km[base + 64] = f2bf(k2*cs + k1*sn);
}

// ---------------- sliding-window flash attention ----------------
// One wave owns 16 queries. Swapped QK^T: st = mfma(K_frag, Q_frag) gives
// S^T with C-layout (col=r4 -> query, row=4g+reg -> key). The resulting
// P fragment pf[j] = P[q=r4][key=4g+j] is EXACTLY the A-operand frag of P
// for a 16x16x16 PV mfma (A[row=r4][k=4g+j]). V B-frag is read transposed
// from a padded row-major LDS tile with scalar ds_reads.
// NOTE: oacc D-layout has query on 4g+rg (NOT r4) -> all per-query scalars
// applied to oacc (rescale, 1/l) must be shuffle-gathered from lane 4g+rg.
__global__ __launch_bounds__(256) void attn_k(const unsigned short* __restrict__ Q,
                                              const unsigned short* __restrict__ K,
                                              const unsigned short* __restrict__ V,
                                              unsigned short* __restrict__ O) {
  __shared__ unsigned short vsl[4][2176];  // per-wave [16 rows][136 shorts] (pad 8)
  const int tid = threadIdx.x, wv = tid >> 6, lane = tid & 63;
  const int g = lane >> 4, r4 = lane & 15;
  const int bidx = blockIdx.x;
  const int q4 = bidx & 31, hh = (bidx >> 5) & 15, b = bidx >> 9;
  const int q0 = q4 * 64 + wv * 16;
  const size_t bh = (size_t)b * LNUM * DNUM + (size_t)hh * DHNUM;

  unsigned short* vs = &vsl[wv][0];

  // Q fragments (B-operand of swapped QK^T): lane holds Q[q0+r4][dc*32+g*8 ..+7]
  bf16x8 qf[4];
  {
    const unsigned short* qr = Q + bh + (size_t)(q0 + r4) * DNUM;
    #pragma unroll
    for (int dc = 0; dc < 4; dc++) qf[dc] = *(const bf16x8*)(qr + dc*32 + g*8);
  }
  f32x4 oacc[8];
  #pragma unroll
  for (int c = 0; c < 8; c++) oacc[c] = f32x4{0.f,0.f,0.f,0.f};
  float mrun = -1e30f, lrun = 0.f;

  const int kt_lo = (q0 >= WINSZ) ? ((q0 - WINSZ + 1) >> 4) : 0;
  const int kt_hi = q0 >> 4;
  const int qi = q0 + r4;

  for (int kt = kt_lo; kt <= kt_hi; kt++) {
    const int k0 = kt * 16;
    // stage V tile (16 keys x 128 d) row-major into padded LDS
    {
      const unsigned short* vb = V + bh + (size_t)k0 * DNUM;
      #pragma unroll
      for (int p = 0; p < 4; p++) {
        const int key = g + p*4;
        *(uint4*)(vs + key*136 + r4*8) = *(const uint4*)(vb + (size_t)key * DNUM + r4*8);
      }
    }
    // S^T = K . Q^T  (D: row=key=4g+reg, col=q=r4)
    f32x4 st = f32x4{0.f,0.f,0.f,0.f};
    {
      const unsigned short* kr = K + bh + (size_t)(k0 + r4) * DNUM;
      #pragma unroll
      for (int dc = 0; dc < 4; dc++) {
        const bf16x8 kf = *(const bf16x8*)(kr + dc*32 + g*8);
        st = __builtin_amdgcn_mfma_f32_16x16x32_bf16(kf, qf[dc], st, 0, 0, 0);
      }
    }
    // mask + online softmax (per q-column = r4; keys spread over reg and lane-groups)
    const int kj = k0 + 4*g;
    const float sv0 = (kj   <= qi && kj   > qi - WINSZ) ? st[0] : -1e30f;
    const float sv1 = (kj+1 <= qi && kj+1 > qi - WINSZ) ? st[1] : -1e30f;
    const float sv2 = (kj+2 <= qi && kj+2 > qi - WINSZ) ? st[2] : -1e30f;
    const float sv3 = (kj+3 <= qi && kj+3 > qi - WINSZ) ? st[3] : -1e30f;
    float pmax = fmaxf(fmaxf(sv0, sv1), fmaxf(sv2, sv3));
    pmax = fmaxf(pmax, __shfl_xor(pmax, 16));
    pmax = fmaxf(pmax, __shfl_xor(pmax, 32));
    const float mnew = fmaxf(mrun, pmax);
    const float sc_old = __expf(mrun - mnew);   // per query r4
    const float p0 = __expf(sv0 - mnew), p1 = __expf(sv1 - mnew);
    const float p2 = __expf(sv2 - mnew), p3 = __expf(sv3 - mnew);
    float psum = p0 + p1 + p2 + p3;
    psum += __shfl_xor(psum, 16);
    psum += __shfl_xor(psum, 32);
    lrun = lrun * sc_old + psum;
    mrun = mnew;
    bf16x4 pf;
    pf[0] = (short)f2bf(p0); pf[1] = (short)f2bf(p1);
    pf[2] = (short)f2bf(p2); pf[3] = (short)f2bf(p3);
    // rescale oacc: its rows are queries 4g+rg -> gather each row's own sc_old
    float sc4[4];
    #pragma unroll
    for (int rg = 0; rg < 4; rg++) sc4[rg] = __shfl(sc_old, 4*g + rg);
    #pragma unroll
    for (int c = 0; c < 8; c++) {
      oacc[c][0] *= sc4[0]; oacc[c][1] *= sc4[1];
      oacc[c][2] *= sc4[2]; oacc[c][3] *= sc4[3];
    }
    // PV: O[q][d] += P . V   (A-frag = pf; B-frag = V[key=4g+j][d=dblk*16+r4])
    #pragma unroll
    for (int dblk = 0; dblk < 8; dblk++) {
      bf16x4 vf;
      vf[0] = (short)vs[(4*g+0)*136 + dblk*16 + r4];
      vf[1] = (short)vs[(4*g+1)*136 + dblk*16 + r4];
      vf[2] = (short)vs[(4*g+2)*136 + dblk*16 + r4];
      vf[3] = (short)vs[(4*g+3)*136 + dblk*16 + r4];
      oacc[dblk] = __builtin_amdgcn_mfma_f32_16x16x16bf16_1k(pf, vf, oacc[dblk], 0, 0, 0);
    }
  }

  // epilogue: normalize (per-query l gathered via shuffle), transpose via LDS, store
  const float inv = 1.0f / lrun;   // valid for query q0 + r4
  float linv[4];
  #pragma unroll
  for (int rg = 0; rg < 4; rg++) linv[rg] = __shfl(inv, 4*g + rg);
  #pragma unroll
  for (int dblk = 0; dblk < 8; dblk++) {
    #pragma unroll
    for (int rg = 0; rg < 4; rg++) {
      vs[(4*g + rg)*136 + dblk*16 + r4] = f2bf(oacc[dblk][rg] * linv[rg]);
    }
  }
  #pragma unroll
  for (int p = 0; p < 4; p++) {
    const int qq = p*4 + g;
    const uint4 vvv = *(const uint4*)(vs + qq*136 + r4*8);
    *(uint4*)(O + bh + (size_t)(q0 + qq) * DNUM + r4*8) = vvv;
  }
}

// ---------------- launch ----------------
extern "C" void kernel_launch(void* const* d_in, const int* in_sizes, int n_in,
                              void* d_out, int out_size, void* d_ws, size_t ws_size,
                              hipStream_t stream) {
  (void)in_sizes; (void)n_in; (void)out_size; (void)ws_size;
  const float* x     = (const float*)d_in[0];
  const float* normw = (const float*)d_in[1];
  const float* wq = (const float*)d_in[2];
  const float* wk = (const float*)d_in[3];
  const float* wvm = (const float*)d_in[4];
  const float* wo = (const float*)d_in[5];
  const float* qA = (const float*)d_in[6];
  const float* qB = (const float*)d_in[7];
  const float* kA = (const float*)d_in[8];
  const float* kB = (const float*)d_in[9];
  const float* vA = (const float*)d_in[10];
  const float* vB = (const float*)d_in[11];
  const float* oA = (const float*)d_in[12];
  const float* oB = (const float*)d_in[13];

  char* w = (char*)d_ws;
  const size_t SZ = (size_t)MTOK * DNUM * 2;   // 16 MiB per bf16 activation
  unsigned short* h  = (unsigned short*)(w);
  unsigned short* Qb = (unsigned short*)(w + SZ);
  unsigned short* Kb = (unsigned short*)(w + 2*SZ);
  unsigned short* Vb = (unsigned short*)(w + 3*SZ);
  unsigned short* AO = (unsigned short*)(w + 4*SZ);
  unsigned short* Wq = (unsigned short*)(w + 5*SZ);
  unsigned short* Wk = Wq + (size_t)DNUM*DNUM;
  unsigned short* Wv = Wk + (size_t)DNUM*DNUM;
  unsigned short* Wo = Wv + (size_t)DNUM*DNUM;
  float* tq = (float*)(Wo + (size_t)DNUM*DNUM);
  float* tk = tq + MTOK*16;
  float* tv = tk + MTOK*16;
  float* to = tv + MTOK*16;

  const float lscale = 1.0f / 16.0f;

  cvtw_k<<<dim3(2048,4), 256, 0, stream>>>(wq,wk,wvm,wo, Wq,Wk,Wv,Wo);
  rmsnorm_k<<<dim3(4096), 256, 0, stream>>>(x, normw, h);
  lorat_k<<<dim3(1024,3), 256, 0, stream>>>(h, qA,kA,vA, tq,tk,tv);
  gemm_k<false><<<dim3(16,32,3), 256, 0, stream>>>(h, Wq,Wk,Wv, tq,tk,tv, qB,kB,vB,
                                                   Qb,Kb,Vb, nullptr, nullptr, lscale);
  rope_k<<<dim3(16384), 256, 0, stream>>>(Qb, Kb);
  attn_k<<<dim3(1024), 256, 0, stream>>>(Qb, Kb, Vb, AO);
  lorat_k<<<dim3(1024,1), 256, 0, stream>>>(AO, oA,oA,oA, to,to,to);
  gemm_k<true><<<dim3(16,32,1), 256, 0, stream>>>(AO, Wo,Wo,Wo, to,to,to, oB,oB,oB,
                                                  nullptr,nullptr,nullptr, x, (float*)d_out, lscale);
}

// Round 4
// 310.134 us; speedup vs baseline: 3.9174x; 3.9174x over previous
//
#include <hip/hip_runtime.h>
#include <hip/hip_bf16.h>

#define LNUM 2048
#define DNUM 2048
#define HNUM 16
#define DHNUM 128
#define MTOK 4096   // B*L
#define WINSZ 512

typedef __attribute__((ext_vector_type(8))) short bf16x8;
typedef __attribute__((ext_vector_type(4))) short bf16x4;
typedef __attribute__((ext_vector_type(4))) float f32x4;

#define GLOBAL_AS __attribute__((address_space(1)))
#define LDS_AS __attribute__((address_space(3)))

__device__ __forceinline__ unsigned short f2bf(float f) {
  union { float f; unsigned u; } v; v.f = f;
  unsigned r = v.u + 0x7FFFu + ((v.u >> 16) & 1u);
  return (unsigned short)(r >> 16);
}
__device__ __forceinline__ float bf2f(unsigned short h) {
  union { unsigned u; float f; } v; v.u = ((unsigned)h) << 16;
  return v.f;
}

// ---------------- W_eff = W + s * Bm @ Am  (rank-16 fold), fp32 -> bf16 ----------------
// All four matrices are (2048 x 2048); Bm is (2048 x 16), Am is (16 x 2048).
__global__ __launch_bounds__(256) void weff_k(
    const float* __restrict__ w0, const float* __restrict__ w1,
    const float* __restrict__ w2, const float* __restrict__ w3,
    const float* __restrict__ b0, const float* __restrict__ b1,
    const float* __restrict__ b2, const float* __restrict__ b3,
    const float* __restrict__ a0, const float* __restrict__ a1,
    const float* __restrict__ a2, const float* __restrict__ a3,
    unsigned short* __restrict__ o0, unsigned short* __restrict__ o1,
    unsigned short* __restrict__ o2, unsigned short* __restrict__ o3,
    float s) {
  const int z = blockIdx.z;
  const float* W = z==0?w0:z==1?w1:z==2?w2:w3;
  const float* Bm = z==0?b0:z==1?b1:z==2?b2:b3;
  const float* Am = z==0?a0:z==1?a1:z==2?a2:a3;
  unsigned short* out = z==0?o0:z==1?o1:z==2?o2:o3;

  const int col0 = blockIdx.x * 256;
  const int row0 = blockIdx.y * 64;
  const int tid = threadIdx.x;

  __shared__ float Als[16][256];
  #pragma unroll
  for (int idx = tid; idx < 4096; idx += 256)
    Als[idx >> 8][idx & 255] = Am[(size_t)(idx >> 8) * DNUM + col0 + (idx & 255)];
  __syncthreads();

  const int col = col0 + tid;
  for (int r = 0; r < 64; r++) {
    const int n = row0 + r;
    const float* brow = Bm + (size_t)n * 16;
    float dot = 0.f;
    #pragma unroll
    for (int j = 0; j < 16; j++) dot = fmaf(brow[j], Als[j][tid], dot);
    out[(size_t)n * DNUM + col] = f2bf(W[(size_t)n * DNUM + col] + s * dot);
  }
}

// ---------------- RMSNorm -> bf16 ----------------
__global__ __launch_bounds__(256) void rmsnorm_k(const float* __restrict__ x,
                                                 const float* __restrict__ w,
                                                 unsigned short* __restrict__ h) {
  const int row = blockIdx.x;
  const int t = threadIdx.x;
  const float4* xr = (const float4*)(x + (size_t)row * DNUM);
  float4 v0 = xr[t];
  float4 v1 = xr[t + 256];
  float ss = v0.x*v0.x + v0.y*v0.y + v0.z*v0.z + v0.w*v0.w +
             v1.x*v1.x + v1.y*v1.y + v1.z*v1.z + v1.w*v1.w;
  #pragma unroll
  for (int off = 32; off > 0; off >>= 1) ss += __shfl_xor(ss, off);
  __shared__ float red[4];
  if ((t & 63) == 0) red[t >> 6] = ss;
  __syncthreads();
  const float r = rsqrtf((red[0]+red[1]+red[2]+red[3]) * (1.0f/DNUM) + 1e-6f);
  const float4* wr4 = (const float4*)w;
  float4 w0 = wr4[t], w1 = wr4[t+256];
  ushort4 o0, o1;
  o0.x = f2bf(v0.x*r*w0.x); o0.y = f2bf(v0.y*r*w0.y);
  o0.z = f2bf(v0.z*r*w0.z); o0.w = f2bf(v0.w*r*w0.w);
  o1.x = f2bf(v1.x*r*w1.x); o1.y = f2bf(v1.y*r*w1.y);
  o1.z = f2bf(v1.z*r*w1.z); o1.w = f2bf(v1.w*r*w1.w);
  ushort4* hp = (ushort4*)(h + (size_t)row * DNUM);
  hp[t] = o0; hp[t + 256] = o1;
}

// ---------------- GEMM: C = A(bf16,MxK) @ W^T(bf16,NxK) [+resid] ----------------
template<bool OUTF32>
__global__ __launch_bounds__(256, 3) void gemm_k(
    const unsigned short* __restrict__ Am,
    const unsigned short* __restrict__ W0, const unsigned short* __restrict__ W1, const unsigned short* __restrict__ W2,
    unsigned short* __restrict__ O0, unsigned short* __restrict__ O1, unsigned short* __restrict__ O2,
    const float* __restrict__ resid, float* __restrict__ Of)
{
  const int z = blockIdx.z;
  const unsigned short* W = z==0?W0:(z==1?W1:W2);
  unsigned short* Ob = z==0?O0:(z==1?O1:O2);

  const int row0 = blockIdx.y * 128;
  const int col0 = blockIdx.x * 128;
  const int tid = threadIdx.x;
  const int wv = tid >> 6, lane = tid & 63;
  const int wr = wv >> 1, wc = wv & 1;
  const int g = lane >> 4, r4 = lane & 15;

  __shared__ unsigned short lds[2][2][4096];   // [buf][A/B][128*32]

  f32x4 acc[4][4];
  #pragma unroll
  for (int m=0;m<4;m++)
    #pragma unroll
    for (int n=0;n<4;n++) acc[m][n] = f32x4{0.f,0.f,0.f,0.f};

  auto stage = [&](int buf, int k0) {
    #pragma unroll
    for (int qq = 0; qq < 2; qq++) {
      const int chunk = wv*2 + qq;
      const int rp = chunk*16 + (lane >> 2);
      const int cl = (lane & 3) ^ ((rp >> 1) & 3);   // XOR swizzle (involution)
      const unsigned short* ga = Am + (size_t)(row0 + rp) * DNUM + k0 + cl*8;
      __builtin_amdgcn_global_load_lds((const GLOBAL_AS void*)ga,
          (LDS_AS void*)&lds[buf][0][chunk*512], 16, 0, 0);
      const unsigned short* gb = W + (size_t)(col0 + rp) * DNUM + k0 + cl*8;
      __builtin_amdgcn_global_load_lds((const GLOBAL_AS void*)gb,
          (LDS_AS void*)&lds[buf][1][chunk*512], 16, 0, 0);
    }
  };

  stage(0, 0);
  const int nk = DNUM / 32;
  for (int kt = 0; kt < nk; kt++) {
    __syncthreads();
    if (kt + 1 < nk) stage((kt+1) & 1, (kt+1)*32);
    const unsigned short* As = &lds[kt&1][0][0];
    const unsigned short* Bs = &lds[kt&1][1][0];
    bf16x8 af[4], bb[4];
    #pragma unroll
    for (int m = 0; m < 4; m++) {
      const int R = wr*64 + m*16 + r4;
      af[m] = *(const bf16x8*)((const char*)As + R*64 + ((g ^ ((R>>1)&3))*16));
    }
    #pragma unroll
    for (int n = 0; n < 4; n++) {
      const int R = wc*64 + n*16 + r4;
      bb[n] = *(const bf16x8*)((const char*)Bs + R*64 + ((g ^ ((R>>1)&3))*16));
    }
    #pragma unroll
    for (int m = 0; m < 4; m++)
      #pragma unroll
      for (int n = 0; n < 4; n++)
        acc[m][n] = __builtin_amdgcn_mfma_f32_16x16x32_bf16(af[m], bb[n], acc[m][n], 0, 0, 0);
  }

  #pragma unroll
  for (int m = 0; m < 4; m++) {
    #pragma unroll
    for (int rg = 0; rg < 4; rg++) {
      const int row = row0 + wr*64 + m*16 + 4*g + rg;
      #pragma unroll
      for (int n = 0; n < 4; n++) {
        const int col = col0 + wc*64 + n*16 + r4;
        const float val = acc[m][n][rg];
        if constexpr (OUTF32) {
          Of[(size_t)row * DNUM + col] = val + resid[(size_t)row * DNUM + col];
        } else {
          Ob[(size_t)row * DNUM + col] = f2bf(val);
        }
      }
    }
  }
}

// ---------------- RoPE in-place (Q also pre-scaled by 1/sqrt(DH)), uint-pair vectorized ----------------
__global__ __launch_bounds__(256) void rope_k(unsigned short* __restrict__ Qm,
                                              unsigned short* __restrict__ Km) {
  const int u = blockIdx.x * 256 + threadIdx.x;
  const int t2 = u & 31;              // d-pair index: d0 = 2*t2
  const int hh = (u >> 5) & (HNUM-1);
  const int i = u >> 9;               // token
  const int l = i & (LNUM - 1);
  const int d0 = 2 * t2;
  const float C = 0.14391156831212787f;  // ln(10000)/64
  const float th0 = __expf(-(float)d0 * C);
  const float th1 = __expf(-(float)(d0+1) * C);
  float sn0, cs0, sn1, cs1;
  __sincosf((float)l * th0, &sn0, &cs0);
  __sincosf((float)l * th1, &sn1, &cs1);
  const size_t base = (size_t)i * DNUM + hh * DHNUM + d0;
  const float qs = 0.08838834764831845f;  // 1/sqrt(128)

  unsigned qa = *(const unsigned*)(Qm + base);
  unsigned qb = *(const unsigned*)(Qm + base + 64);
  float a0 = bf2f((unsigned short)qa), a1 = bf2f((unsigned short)(qa >> 16));
  float b0 = bf2f((unsigned short)qb), b1 = bf2f((unsigned short)(qb >> 16));
  unsigned lo = (unsigned)f2bf((a0*cs0 - b0*sn0) * qs) | ((unsigned)f2bf((a1*cs1 - b1*sn1) * qs) << 16);
  unsigned hi = (unsigned)f2bf((b0*cs0 + a0*sn0) * qs) | ((unsigned)f2bf((b1*cs1 + a1*sn1) * qs) << 16);
  *(unsigned*)(Qm + base) = lo;
  *(unsigned*)(Qm + base + 64) = hi;

  unsigned ka = *(const unsigned*)(Km + base);
  unsigned kb = *(const unsigned*)(Km + base + 64);
  a0 = bf2f((unsigned short)ka); a1 = bf2f((unsigned short)(ka >> 16));
  b0 = bf2f((unsigned short)kb); b1 = bf2f((unsigned short)(kb >> 16));
  lo = (unsigned)f2bf(a0*cs0 - b0*sn0) | ((unsigned)f2bf(a1*cs1 - b1*sn1) << 16);
  hi = (unsigned)f2bf(b0*cs0 + a0*sn0) | ((unsigned)f2bf(b1*cs1 + a1*sn1) << 16);
  *(unsigned*)(Km + base) = lo;
  *(unsigned*)(Km + base + 64) = hi;
}

// ---------------- sliding-window flash attention ----------------
// One wave owns 16 queries. Swapped QK^T: st = mfma(K_frag, Q_frag) gives
// S^T with C-layout (col=r4 -> query, row=4g+reg -> key). The resulting
// P fragment pf[j] = P[q=r4][key=4g+j] is EXACTLY the A-operand frag of P
// for a 16x16x16 PV mfma (A[row=r4][k=4g+j]). V B-frag is read transposed
// from a padded row-major LDS tile with scalar ds_reads.
// NOTE: oacc D-layout has query on 4g+rg (NOT r4) -> all per-query scalars
// applied to oacc (rescale, 1/l) must be shuffle-gathered from lane 4g+rg.
__global__ __launch_bounds__(256) void attn_k(const unsigned short* __restrict__ Q,
                                              const unsigned short* __restrict__ K,
                                              const unsigned short* __restrict__ V,
                                              unsigned short* __restrict__ O) {
  __shared__ unsigned short vsl[4][2176];  // per-wave [16 rows][136 shorts] (pad 8)
  const int tid = threadIdx.x, wv = tid >> 6, lane = tid & 63;
  const int g = lane >> 4, r4 = lane & 15;
  const int bidx = blockIdx.x;
  const int q4 = bidx & 31, hh = (bidx >> 5) & 15, b = bidx >> 9;
  const int q0 = q4 * 64 + wv * 16;
  const size_t bh = (size_t)b * LNUM * DNUM + (size_t)hh * DHNUM;

  unsigned short* vs = &vsl[wv][0];

  // Q fragments (B-operand of swapped QK^T): lane holds Q[q0+r4][dc*32+g*8 ..+7]
  bf16x8 qf[4];
  {
    const unsigned short* qr = Q + bh + (size_t)(q0 + r4) * DNUM;
    #pragma unroll
    for (int dc = 0; dc < 4; dc++) qf[dc] = *(const bf16x8*)(qr + dc*32 + g*8);
  }
  f32x4 oacc[8];
  #pragma unroll
  for (int c = 0; c < 8; c++) oacc[c] = f32x4{0.f,0.f,0.f,0.f};
  float mrun = -1e30f, lrun = 0.f;

  const int kt_lo = (q0 >= WINSZ) ? ((q0 - WINSZ + 1) >> 4) : 0;
  const int kt_hi = q0 >> 4;
  const int qi = q0 + r4;

  for (int kt = kt_lo; kt <= kt_hi; kt++) {
    const int k0 = kt * 16;
    // stage V tile (16 keys x 128 d) row-major into padded LDS
    {
      const unsigned short* vb = V + bh + (size_t)k0 * DNUM;
      #pragma unroll
      for (int p = 0; p < 4; p++) {
        const int key = g + p*4;
        *(uint4*)(vs + key*136 + r4*8) = *(const uint4*)(vb + (size_t)key * DNUM + r4*8);
      }
    }
    // S^T = K . Q^T  (D: row=key=4g+reg, col=q=r4)
    f32x4 st = f32x4{0.f,0.f,0.f,0.f};
    {
      const unsigned short* kr = K + bh + (size_t)(k0 + r4) * DNUM;
      #pragma unroll
      for (int dc = 0; dc < 4; dc++) {
        const bf16x8 kf = *(const bf16x8*)(kr + dc*32 + g*8);
        st = __builtin_amdgcn_mfma_f32_16x16x32_bf16(kf, qf[dc], st, 0, 0, 0);
      }
    }
    // mask + online softmax (per q-column = r4; keys spread over reg and lane-groups)
    const int kj = k0 + 4*g;
    const float sv0 = (kj   <= qi && kj   > qi - WINSZ) ? st[0] : -1e30f;
    const float sv1 = (kj+1 <= qi && kj+1 > qi - WINSZ) ? st[1] : -1e30f;
    const float sv2 = (kj+2 <= qi && kj+2 > qi - WINSZ) ? st[2] : -1e30f;
    const float sv3 = (kj+3 <= qi && kj+3 > qi - WINSZ) ? st[3] : -1e30f;
    float pmax = fmaxf(fmaxf(sv0, sv1), fmaxf(sv2, sv3));
    pmax = fmaxf(pmax, __shfl_xor(pmax, 16));
    pmax = fmaxf(pmax, __shfl_xor(pmax, 32));
    const float mnew = fmaxf(mrun, pmax);
    const float sc_old = __expf(mrun - mnew);   // per query r4
    const float p0 = __expf(sv0 - mnew), p1 = __expf(sv1 - mnew);
    const float p2 = __expf(sv2 - mnew), p3 = __expf(sv3 - mnew);
    float psum = p0 + p1 + p2 + p3;
    psum += __shfl_xor(psum, 16);
    psum += __shfl_xor(psum, 32);
    lrun = lrun * sc_old + psum;
    mrun = mnew;
    bf16x4 pf;
    pf[0] = (short)f2bf(p0); pf[1] = (short)f2bf(p1);
    pf[2] = (short)f2bf(p2); pf[3] = (short)f2bf(p3);
    // rescale oacc: its rows are queries 4g+rg -> gather each row's own sc_old
    float sc4[4];
    #pragma unroll
    for (int rg = 0; rg < 4; rg++) sc4[rg] = __shfl(sc_old, 4*g + rg);
    #pragma unroll
    for (int c = 0; c < 8; c++) {
      oacc[c][0] *= sc4[0]; oacc[c][1] *= sc4[1];
      oacc[c][2] *= sc4[2]; oacc[c][3] *= sc4[3];
    }
    // PV: O[q][d] += P . V   (A-frag = pf; B-frag = V[key=4g+j][d=dblk*16+r4])
    #pragma unroll
    for (int dblk = 0; dblk < 8; dblk++) {
      bf16x4 vf;
      vf[0] = (short)vs[(4*g+0)*136 + dblk*16 + r4];
      vf[1] = (short)vs[(4*g+1)*136 + dblk*16 + r4];
      vf[2] = (short)vs[(4*g+2)*136 + dblk*16 + r4];
      vf[3] = (short)vs[(4*g+3)*136 + dblk*16 + r4];
      oacc[dblk] = __builtin_amdgcn_mfma_f32_16x16x16bf16_1k(pf, vf, oacc[dblk], 0, 0, 0);
    }
  }

  // epilogue: normalize (per-query l gathered via shuffle), transpose via LDS, store
  const float inv = 1.0f / lrun;   // valid for query q0 + r4
  float linv[4];
  #pragma unroll
  for (int rg = 0; rg < 4; rg++) linv[rg] = __shfl(inv, 4*g + rg);
  #pragma unroll
  for (int dblk = 0; dblk < 8; dblk++) {
    #pragma unroll
    for (int rg = 0; rg < 4; rg++) {
      vs[(4*g + rg)*136 + dblk*16 + r4] = f2bf(oacc[dblk][rg] * linv[rg]);
    }
  }
  #pragma unroll
  for (int p = 0; p < 4; p++) {
    const int qq = p*4 + g;
    const uint4 vvv = *(const uint4*)(vs + qq*136 + r4*8);
    *(uint4*)(O + bh + (size_t)(q0 + qq) * DNUM + r4*8) = vvv;
  }
}

// ---------------- launch ----------------
extern "C" void kernel_launch(void* const* d_in, const int* in_sizes, int n_in,
                              void* d_out, int out_size, void* d_ws, size_t ws_size,
                              hipStream_t stream) {
  (void)in_sizes; (void)n_in; (void)out_size; (void)ws_size;
  const float* x     = (const float*)d_in[0];
  const float* normw = (const float*)d_in[1];
  const float* wq = (const float*)d_in[2];
  const float* wk = (const float*)d_in[3];
  const float* wvm = (const float*)d_in[4];
  const float* wo = (const float*)d_in[5];
  const float* qA = (const float*)d_in[6];
  const float* qB = (const float*)d_in[7];
  const float* kA = (const float*)d_in[8];
  const float* kB = (const float*)d_in[9];
  const float* vA = (const float*)d_in[10];
  const float* vB = (const float*)d_in[11];
  const float* oA = (const float*)d_in[12];
  const float* oB = (const float*)d_in[13];

  char* w = (char*)d_ws;
  const size_t SZ = (size_t)MTOK * DNUM * 2;   // 16 MiB per bf16 activation
  unsigned short* h  = (unsigned short*)(w);
  unsigned short* Qb = (unsigned short*)(w + SZ);
  unsigned short* Kb = (unsigned short*)(w + 2*SZ);
  unsigned short* Vb = (unsigned short*)(w + 3*SZ);
  unsigned short* AO = (unsigned short*)(w + 4*SZ);
  unsigned short* Wq = (unsigned short*)(w + 5*SZ);
  unsigned short* Wk = Wq + (size_t)DNUM*DNUM;
  unsigned short* Wv = Wk + (size_t)DNUM*DNUM;
  unsigned short* Wo = Wv + (size_t)DNUM*DNUM;

  const float lscale = 1.0f / 16.0f;

  // W_eff = W + s*B@A for q,k,v,o  (associativity fold of the LoRA branch)
  weff_k<<<dim3(8, 32, 4), 256, 0, stream>>>(wq, wk, wvm, wo,
                                             qB, kB, vB, oB,
                                             qA, kA, vA, oA,
                                             Wq, Wk, Wv, Wo, lscale);
  rmsnorm_k<<<dim3(4096), 256, 0, stream>>>(x, normw, h);
  gemm_k<false><<<dim3(16,32,3), 256, 0, stream>>>(h, Wq,Wk,Wv, Qb,Kb,Vb, nullptr, nullptr);
  rope_k<<<dim3(8192), 256, 0, stream>>>(Qb, Kb);
  attn_k<<<dim3(1024), 256, 0, stream>>>(Qb, Kb, Vb, AO);
  gemm_k<true><<<dim3(16,32,1), 256, 0, stream>>>(AO, Wo,Wo,Wo, nullptr,nullptr,nullptr,
                                                  x, (float*)d_out);
}

// Round 5
// 307.876 us; speedup vs baseline: 3.9461x; 1.0073x over previous
//
#include <hip/hip_runtime.h>
#include <hip/hip_bf16.h>

#define LNUM 2048
#define DNUM 2048
#define HNUM 16
#define DHNUM 128
#define MTOK 4096   // B*L
#define WINSZ 512

typedef __attribute__((ext_vector_type(8))) short bf16x8;
typedef __attribute__((ext_vector_type(4))) short bf16x4;
typedef __attribute__((ext_vector_type(4))) float f32x4;

#define GLOBAL_AS __attribute__((address_space(1)))
#define LDS_AS __attribute__((address_space(3)))

__device__ __forceinline__ unsigned short f2bf(float f) {
  union { float f; unsigned u; } v; v.f = f;
  unsigned r = v.u + 0x7FFFu + ((v.u >> 16) & 1u);
  return (unsigned short)(r >> 16);
}
__device__ __forceinline__ float bf2f(unsigned short h) {
  union { unsigned u; float f; } v; v.u = ((unsigned)h) << 16;
  return v.f;
}

// ---------------- W_eff = W + s * Bm @ Am  (rank-16 fold), fp32 -> bf16 ----------------
// W: (2048 x 2048); Bm: (2048 x 16); Am: (16 x 2048). Vectorized: A-stripe in regs.
__global__ __launch_bounds__(256) void weff_k(
    const float* __restrict__ w0, const float* __restrict__ w1,
    const float* __restrict__ w2, const float* __restrict__ w3,
    const float* __restrict__ b0, const float* __restrict__ b1,
    const float* __restrict__ b2, const float* __restrict__ b3,
    const float* __restrict__ a0, const float* __restrict__ a1,
    const float* __restrict__ a2, const float* __restrict__ a3,
    unsigned short* __restrict__ o0, unsigned short* __restrict__ o1,
    unsigned short* __restrict__ o2, unsigned short* __restrict__ o3,
    float s) {
  const int z = blockIdx.z;
  const float* W = z==0?w0:z==1?w1:z==2?w2:w3;
  const float* Bm = z==0?b0:z==1?b1:z==2?b2:b3;
  const float* Am = z==0?a0:z==1?a1:z==2?a2:a3;
  unsigned short* out = z==0?o0:z==1?o1:z==2?o2:o3;

  const int col = blockIdx.x * 1024 + threadIdx.x * 4;
  const int row0 = blockIdx.y * 64;

  float4 av[16];
  #pragma unroll
  for (int j = 0; j < 16; j++) av[j] = *(const float4*)(Am + (size_t)j * DNUM + col);

  for (int r = 0; r < 64; r++) {
    const int n = row0 + r;
    const float* brow = Bm + (size_t)n * 16;
    float dx = 0.f, dy = 0.f, dz = 0.f, dw = 0.f;
    #pragma unroll
    for (int j = 0; j < 16; j++) {
      const float bj = brow[j];
      dx = fmaf(bj, av[j].x, dx); dy = fmaf(bj, av[j].y, dy);
      dz = fmaf(bj, av[j].z, dz); dw = fmaf(bj, av[j].w, dw);
    }
    const float4 wv = *(const float4*)(W + (size_t)n * DNUM + col);
    ushort4 o;
    o.x = f2bf(wv.x + s*dx); o.y = f2bf(wv.y + s*dy);
    o.z = f2bf(wv.z + s*dz); o.w = f2bf(wv.w + s*dw);
    *(ushort4*)(out + (size_t)n * DNUM + col) = o;
  }
}

// ---------------- RMSNorm -> bf16 ----------------
__global__ __launch_bounds__(256) void rmsnorm_k(const float* __restrict__ x,
                                                 const float* __restrict__ w,
                                                 unsigned short* __restrict__ h) {
  const int row = blockIdx.x;
  const int t = threadIdx.x;
  const float4* xr = (const float4*)(x + (size_t)row * DNUM);
  float4 v0 = xr[t];
  float4 v1 = xr[t + 256];
  float ss = v0.x*v0.x + v0.y*v0.y + v0.z*v0.z + v0.w*v0.w +
             v1.x*v1.x + v1.y*v1.y + v1.z*v1.z + v1.w*v1.w;
  #pragma unroll
  for (int off = 32; off > 0; off >>= 1) ss += __shfl_xor(ss, off);
  __shared__ float red[4];
  if ((t & 63) == 0) red[t >> 6] = ss;
  __syncthreads();
  const float r = rsqrtf((red[0]+red[1]+red[2]+red[3]) * (1.0f/DNUM) + 1e-6f);
  const float4* wr4 = (const float4*)w;
  float4 w0 = wr4[t], w1 = wr4[t+256];
  ushort4 o0, o1;
  o0.x = f2bf(v0.x*r*w0.x); o0.y = f2bf(v0.y*r*w0.y);
  o0.z = f2bf(v0.z*r*w0.z); o0.w = f2bf(v0.w*r*w0.w);
  o1.x = f2bf(v1.x*r*w1.x); o1.y = f2bf(v1.y*r*w1.y);
  o1.z = f2bf(v1.z*r*w1.z); o1.w = f2bf(v1.w*r*w1.w);
  ushort4* hp = (ushort4*)(h + (size_t)row * DNUM);
  hp[t] = o0; hp[t + 256] = o1;
}

// ---------------- 256x256-tile GEMM, BK=64, 8 waves, counted-vmcnt pipeline ----------------
// C = A(bf16, M x K) @ W^T(bf16, N x K), bf16 out. LDS 128 KiB, 2-deep dbuf.
// Chunk layout (proven 0-conflict in the 128^2 version): each (khalf, rowchunk)
// is 16 rows x 32 shorts; within a chunk, col-group position p holds global
// col-group p ^ ((row>>1)&3); achieved by pre-swizzling the GLOBAL source and
// keeping the LDS destination linear (global_load_lds constraint).
__global__ __launch_bounds__(512, 2) void gemm256_k(
    const unsigned short* __restrict__ Am,
    const unsigned short* __restrict__ W0, const unsigned short* __restrict__ W1, const unsigned short* __restrict__ W2,
    unsigned short* __restrict__ O0, unsigned short* __restrict__ O1, unsigned short* __restrict__ O2)
{
  const int z = blockIdx.z;
  const unsigned short* W = z==0?W0:(z==1?W1:W2);
  unsigned short* Ob = z==0?O0:(z==1?O1:O2);

  const int row0 = blockIdx.y * 256;
  const int col0 = blockIdx.x * 256;
  const int tid = threadIdx.x;
  const int wv = tid >> 6, lane = tid & 63;
  const int wr = wv >> 2, wc = wv & 3;        // wave grid 2 (M) x 4 (N)
  const int g = lane >> 4, r4 = lane & 15;

  __shared__ unsigned short lds[2][2][16384];  // [buf][A/B][2 khalf * 16 chunks * 512]

  f32x4 acc[8][4];
  #pragma unroll
  for (int m = 0; m < 8; m++)
    #pragma unroll
    for (int n = 0; n < 4; n++) acc[m][n] = f32x4{0.f,0.f,0.f,0.f};

  auto stage = [&](int buf, int k0) {
    #pragma unroll
    for (int q = 0; q < 4; q++) {
      const int c  = q*8 + wv;
      const int kh = c & 1, rc = c >> 1;
      const int rp = lane >> 2;
      const int row = rc*16 + rp;
      const int scol = kh*32 + (((lane & 3) ^ ((rp >> 1) & 3)) * 8);
      const unsigned short* ga = Am + (size_t)(row0 + row) * DNUM + k0 + scol;
      __builtin_amdgcn_global_load_lds((const GLOBAL_AS void*)ga,
          (LDS_AS void*)&lds[buf][0][kh*8192 + rc*512], 16, 0, 0);
      const unsigned short* gb = W + (size_t)(col0 + row) * DNUM + k0 + scol;
      __builtin_amdgcn_global_load_lds((const GLOBAL_AS void*)gb,
          (LDS_AS void*)&lds[buf][1][kh*8192 + rc*512], 16, 0, 0);
    }
  };

  auto compute = [&](int buf) {
    const int sw = (r4 >> 1) & 3;
    const int cg = (g ^ sw) * 8;
    #pragma unroll
    for (int kh = 0; kh < 2; kh++) {
      const unsigned short* As = &lds[buf][0][kh*8192];
      const unsigned short* Bs = &lds[buf][1][kh*8192];
      bf16x8 af[8], bb[4];
      #pragma unroll
      for (int m = 0; m < 8; m++)
        af[m] = *(const bf16x8*)(As + (wr*8 + m)*512 + r4*32 + cg);
      #pragma unroll
      for (int n = 0; n < 4; n++)
        bb[n] = *(const bf16x8*)(Bs + (wc*4 + n)*512 + r4*32 + cg);
      #pragma unroll
      for (int m = 0; m < 8; m++)
        #pragma unroll
        for (int n = 0; n < 4; n++)
          acc[m][n] = __builtin_amdgcn_mfma_f32_16x16x32_bf16(af[m], bb[n], acc[m][n], 0, 0, 0);
    }
  };

  const int nt = DNUM / 64;   // 32 K-tiles
  stage(0, 0);
  for (int t = 0; t < nt - 1; t++) {
    stage((t + 1) & 1, (t + 1) * 64);             // 8 loads for next tile, stay in flight
    asm volatile("s_waitcnt vmcnt(8)" ::: "memory");  // drain ONLY this tile's 8
    __builtin_amdgcn_s_barrier();
    compute(t & 1);
    __builtin_amdgcn_s_barrier();                 // all reads of buf done before restage
  }
  asm volatile("s_waitcnt vmcnt(0)" ::: "memory");
  __builtin_amdgcn_s_barrier();
  compute((nt - 1) & 1);

  #pragma unroll
  for (int m = 0; m < 8; m++) {
    #pragma unroll
    for (int rg = 0; rg < 4; rg++) {
      const int row = row0 + wr*128 + m*16 + 4*g + rg;
      #pragma unroll
      for (int n = 0; n < 4; n++) {
        const int col = col0 + wc*64 + n*16 + r4;
        Ob[(size_t)row * DNUM + col] = f2bf(acc[m][n][rg]);
      }
    }
  }
}

// ---------------- 128x128-tile GEMM (m97 structure), used for the final O-proj ----------------
__global__ __launch_bounds__(256, 3) void gemm_k(
    const unsigned short* __restrict__ Am,
    const unsigned short* __restrict__ W0,
    const float* __restrict__ resid, float* __restrict__ Of)
{
  const unsigned short* W = W0;

  const int row0 = blockIdx.y * 128;
  const int col0 = blockIdx.x * 128;
  const int tid = threadIdx.x;
  const int wv = tid >> 6, lane = tid & 63;
  const int wr = wv >> 1, wc = wv & 1;
  const int g = lane >> 4, r4 = lane & 15;

  __shared__ unsigned short lds[2][2][4096];   // [buf][A/B][128*32]

  f32x4 acc[4][4];
  #pragma unroll
  for (int m=0;m<4;m++)
    #pragma unroll
    for (int n=0;n<4;n++) acc[m][n] = f32x4{0.f,0.f,0.f,0.f};

  auto stage = [&](int buf, int k0) {
    #pragma unroll
    for (int qq = 0; qq < 2; qq++) {
      const int chunk = wv*2 + qq;
      const int rp = chunk*16 + (lane >> 2);
      const int cl = (lane & 3) ^ ((rp >> 1) & 3);   // XOR swizzle (involution)
      const unsigned short* ga = Am + (size_t)(row0 + rp) * DNUM + k0 + cl*8;
      __builtin_amdgcn_global_load_lds((const GLOBAL_AS void*)ga,
          (LDS_AS void*)&lds[buf][0][chunk*512], 16, 0, 0);
      const unsigned short* gb = W + (size_t)(col0 + rp) * DNUM + k0 + cl*8;
      __builtin_amdgcn_global_load_lds((const GLOBAL_AS void*)gb,
          (LDS_AS void*)&lds[buf][1][chunk*512], 16, 0, 0);
    }
  };

  stage(0, 0);
  const int nk = DNUM / 32;
  for (int kt = 0; kt < nk; kt++) {
    __syncthreads();
    if (kt + 1 < nk) stage((kt+1) & 1, (kt+1)*32);
    const unsigned short* As = &lds[kt&1][0][0];
    const unsigned short* Bs = &lds[kt&1][1][0];
    bf16x8 af[4], bb[4];
    #pragma unroll
    for (int m = 0; m < 4; m++) {
      const int R = wr*64 + m*16 + r4;
      af[m] = *(const bf16x8*)((const char*)As + R*64 + ((g ^ ((R>>1)&3))*16));
    }
    #pragma unroll
    for (int n = 0; n < 4; n++) {
      const int R = wc*64 + n*16 + r4;
      bb[n] = *(const bf16x8*)((const char*)Bs + R*64 + ((g ^ ((R>>1)&3))*16));
    }
    #pragma unroll
    for (int m = 0; m < 4; m++)
      #pragma unroll
      for (int n = 0; n < 4; n++)
        acc[m][n] = __builtin_amdgcn_mfma_f32_16x16x32_bf16(af[m], bb[n], acc[m][n], 0, 0, 0);
  }

  #pragma unroll
  for (int m = 0; m < 4; m++) {
    #pragma unroll
    for (int rg = 0; rg < 4; rg++) {
      const int row = row0 + wr*64 + m*16 + 4*g + rg;
      #pragma unroll
      for (int n = 0; n < 4; n++) {
        const int col = col0 + wc*64 + n*16 + r4;
        Of[(size_t)row * DNUM + col] = acc[m][n][rg] + resid[(size_t)row * DNUM + col];
      }
    }
  }
}

// ---------------- RoPE in-place (Q also pre-scaled by 1/sqrt(DH)), uint-pair vectorized ----------------
__global__ __launch_bounds__(256) void rope_k(unsigned short* __restrict__ Qm,
                                              unsigned short* __restrict__ Km) {
  const int u = blockIdx.x * 256 + threadIdx.x;
  const int t2 = u & 31;              // d-pair index: d0 = 2*t2
  const int hh = (u >> 5) & (HNUM-1);
  const int i = u >> 9;               // token
  const int l = i & (LNUM - 1);
  const int d0 = 2 * t2;
  const float C = 0.14391156831212787f;  // ln(10000)/64
  const float th0 = __expf(-(float)d0 * C);
  const float th1 = __expf(-(float)(d0+1) * C);
  float sn0, cs0, sn1, cs1;
  __sincosf((float)l * th0, &sn0, &cs0);
  __sincosf((float)l * th1, &sn1, &cs1);
  const size_t base = (size_t)i * DNUM + hh * DHNUM + d0;
  const float qs = 0.08838834764831845f;  // 1/sqrt(128)

  unsigned qa = *(const unsigned*)(Qm + base);
  unsigned qb = *(const unsigned*)(Qm + base + 64);
  float a0 = bf2f((unsigned short)qa), a1 = bf2f((unsigned short)(qa >> 16));
  float b0 = bf2f((unsigned short)qb), b1 = bf2f((unsigned short)(qb >> 16));
  unsigned lo = (unsigned)f2bf((a0*cs0 - b0*sn0) * qs) | ((unsigned)f2bf((a1*cs1 - b1*sn1) * qs) << 16);
  unsigned hi = (unsigned)f2bf((b0*cs0 + a0*sn0) * qs) | ((unsigned)f2bf((b1*cs1 + a1*sn1) * qs) << 16);
  *(unsigned*)(Qm + base) = lo;
  *(unsigned*)(Qm + base + 64) = hi;

  unsigned ka = *(const unsigned*)(Km + base);
  unsigned kb = *(const unsigned*)(Km + base + 64);
  a0 = bf2f((unsigned short)ka); a1 = bf2f((unsigned short)(ka >> 16));
  b0 = bf2f((unsigned short)kb); b1 = bf2f((unsigned short)(kb >> 16));
  lo = (unsigned)f2bf(a0*cs0 - b0*sn0) | ((unsigned)f2bf(a1*cs1 - b1*sn1) << 16);
  hi = (unsigned)f2bf(b0*cs0 + a0*sn0) | ((unsigned)f2bf(b1*cs1 + a1*sn1) << 16);
  *(unsigned*)(Km + base) = lo;
  *(unsigned*)(Km + base + 64) = hi;
}

// ---------------- sliding-window flash attention ----------------
// One wave owns 16 queries. Swapped QK^T: st = mfma(K_frag, Q_frag) gives
// S^T with C-layout (col=r4 -> query, row=4g+reg -> key). The resulting
// P fragment pf[j] = P[q=r4][key=4g+j] is EXACTLY the A-operand frag of P
// for a 16x16x16 PV mfma (A[row=r4][k=4g+j]). V B-frag is read transposed
// from a padded row-major LDS tile with scalar ds_reads.
// NOTE: oacc D-layout has query on 4g+rg (NOT r4) -> all per-query scalars
// applied to oacc (rescale, 1/l) must be shuffle-gathered from lane 4g+rg.
__global__ __launch_bounds__(256) void attn_k(const unsigned short* __restrict__ Q,
                                              const unsigned short* __restrict__ K,
                                              const unsigned short* __restrict__ V,
                                              unsigned short* __restrict__ O) {
  __shared__ unsigned short vsl[4][2176];  // per-wave [16 rows][136 shorts] (pad 8)
  const int tid = threadIdx.x, wv = tid >> 6, lane = tid & 63;
  const int g = lane >> 4, r4 = lane & 15;
  const int bidx = blockIdx.x;
  const int q4 = bidx & 31, hh = (bidx >> 5) & 15, b = bidx >> 9;
  const int q0 = q4 * 64 + wv * 16;
  const size_t bh = (size_t)b * LNUM * DNUM + (size_t)hh * DHNUM;

  unsigned short* vs = &vsl[wv][0];

  // Q fragments (B-operand of swapped QK^T): lane holds Q[q0+r4][dc*32+g*8 ..+7]
  bf16x8 qf[4];
  {
    const unsigned short* qr = Q + bh + (size_t)(q0 + r4) * DNUM;
    #pragma unroll
    for (int dc = 0; dc < 4; dc++) qf[dc] = *(const bf16x8*)(qr + dc*32 + g*8);
  }
  f32x4 oacc[8];
  #pragma unroll
  for (int c = 0; c < 8; c++) oacc[c] = f32x4{0.f,0.f,0.f,0.f};
  float mrun = -1e30f, lrun = 0.f;

  const int kt_lo = (q0 >= WINSZ) ? ((q0 - WINSZ + 1) >> 4) : 0;
  const int kt_hi = q0 >> 4;
  const int qi = q0 + r4;

  for (int kt = kt_lo; kt <= kt_hi; kt++) {
    const int k0 = kt * 16;
    // stage V tile (16 keys x 128 d) row-major into padded LDS
    {
      const unsigned short* vb = V + bh + (size_t)k0 * DNUM;
      #pragma unroll
      for (int p = 0; p < 4; p++) {
        const int key = g + p*4;
        *(uint4*)(vs + key*136 + r4*8) = *(const uint4*)(vb + (size_t)key * DNUM + r4*8);
      }
    }
    // S^T = K . Q^T  (D: row=key=4g+reg, col=q=r4)
    f32x4 st = f32x4{0.f,0.f,0.f,0.f};
    {
      const unsigned short* kr = K + bh + (size_t)(k0 + r4) * DNUM;
      #pragma unroll
      for (int dc = 0; dc < 4; dc++) {
        const bf16x8 kf = *(const bf16x8*)(kr + dc*32 + g*8);
        st = __builtin_amdgcn_mfma_f32_16x16x32_bf16(kf, qf[dc], st, 0, 0, 0);
      }
    }
    // mask + online softmax (per q-column = r4; keys spread over reg and lane-groups)
    const int kj = k0 + 4*g;
    const float sv0 = (kj   <= qi && kj   > qi - WINSZ) ? st[0] : -1e30f;
    const float sv1 = (kj+1 <= qi && kj+1 > qi - WINSZ) ? st[1] : -1e30f;
    const float sv2 = (kj+2 <= qi && kj+2 > qi - WINSZ) ? st[2] : -1e30f;
    const float sv3 = (kj+3 <= qi && kj+3 > qi - WINSZ) ? st[3] : -1e30f;
    float pmax = fmaxf(fmaxf(sv0, sv1), fmaxf(sv2, sv3));
    pmax = fmaxf(pmax, __shfl_xor(pmax, 16));
    pmax = fmaxf(pmax, __shfl_xor(pmax, 32));
    const float mnew = fmaxf(mrun, pmax);
    const float sc_old = __expf(mrun - mnew);   // per query r4
    const float p0 = __expf(sv0 - mnew), p1 = __expf(sv1 - mnew);
    const float p2 = __expf(sv2 - mnew), p3 = __expf(sv3 - mnew);
    float psum = p0 + p1 + p2 + p3;
    psum += __shfl_xor(psum, 16);
    psum += __shfl_xor(psum, 32);
    lrun = lrun * sc_old + psum;
    mrun = mnew;
    bf16x4 pf;
    pf[0] = (short)f2bf(p0); pf[1] = (short)f2bf(p1);
    pf[2] = (short)f2bf(p2); pf[3] = (short)f2bf(p3);
    // rescale oacc: its rows are queries 4g+rg -> gather each row's own sc_old
    float sc4[4];
    #pragma unroll
    for (int rg = 0; rg < 4; rg++) sc4[rg] = __shfl(sc_old, 4*g + rg);
    #pragma unroll
    for (int c = 0; c < 8; c++) {
      oacc[c][0] *= sc4[0]; oacc[c][1] *= sc4[1];
      oacc[c][2] *= sc4[2]; oacc[c][3] *= sc4[3];
    }
    // PV: O[q][d] += P . V   (A-frag = pf; B-frag = V[key=4g+j][d=dblk*16+r4])
    #pragma unroll
    for (int dblk = 0; dblk < 8; dblk++) {
      bf16x4 vf;
      vf[0] = (short)vs[(4*g+0)*136 + dblk*16 + r4];
      vf[1] = (short)vs[(4*g+1)*136 + dblk*16 + r4];
      vf[2] = (short)vs[(4*g+2)*136 + dblk*16 + r4];
      vf[3] = (short)vs[(4*g+3)*136 + dblk*16 + r4];
      oacc[dblk] = __builtin_amdgcn_mfma_f32_16x16x16bf16_1k(pf, vf, oacc[dblk], 0, 0, 0);
    }
  }

  // epilogue: normalize (per-query l gathered via shuffle), transpose via LDS, store
  const float inv = 1.0f / lrun;   // valid for query q0 + r4
  float linv[4];
  #pragma unroll
  for (int rg = 0; rg < 4; rg++) linv[rg] = __shfl(inv, 4*g + rg);
  #pragma unroll
  for (int dblk = 0; dblk < 8; dblk++) {
    #pragma unroll
    for (int rg = 0; rg < 4; rg++) {
      vs[(4*g + rg)*136 + dblk*16 + r4] = f2bf(oacc[dblk][rg] * linv[rg]);
    }
  }
  #pragma unroll
  for (int p = 0; p < 4; p++) {
    const int qq = p*4 + g;
    const uint4 vvv = *(const uint4*)(vs + qq*136 + r4*8);
    *(uint4*)(O + bh + (size_t)(q0 + qq) * DNUM + r4*8) = vvv;
  }
}

// ---------------- launch ----------------
extern "C" void kernel_launch(void* const* d_in, const int* in_sizes, int n_in,
                              void* d_out, int out_size, void* d_ws, size_t ws_size,
                              hipStream_t stream) {
  (void)in_sizes; (void)n_in; (void)out_size; (void)ws_size;
  const float* x     = (const float*)d_in[0];
  const float* normw = (const float*)d_in[1];
  const float* wq = (const float*)d_in[2];
  const float* wk = (const float*)d_in[3];
  const float* wvm = (const float*)d_in[4];
  const float* wo = (const float*)d_in[5];
  const float* qA = (const float*)d_in[6];
  const float* qB = (const float*)d_in[7];
  const float* kA = (const float*)d_in[8];
  const float* kB = (const float*)d_in[9];
  const float* vA = (const float*)d_in[10];
  const float* vB = (const float*)d_in[11];
  const float* oA = (const float*)d_in[12];
  const float* oB = (const float*)d_in[13];

  char* w = (char*)d_ws;
  const size_t SZ = (size_t)MTOK * DNUM * 2;   // 16 MiB per bf16 activation
  unsigned short* h  = (unsigned short*)(w);
  unsigned short* Qb = (unsigned short*)(w + SZ);
  unsigned short* Kb = (unsigned short*)(w + 2*SZ);
  unsigned short* Vb = (unsigned short*)(w + 3*SZ);
  unsigned short* AO = (unsigned short*)(w + 4*SZ);
  unsigned short* Wq = (unsigned short*)(w + 5*SZ);
  unsigned short* Wk = Wq + (size_t)DNUM*DNUM;
  unsigned short* Wv = Wk + (size_t)DNUM*DNUM;
  unsigned short* Wo = Wv + (size_t)DNUM*DNUM;

  const float lscale = 1.0f / 16.0f;

  // W_eff = W + s*B@A for q,k,v,o  (associativity fold of the LoRA branch)
  weff_k<<<dim3(2, 32, 4), 256, 0, stream>>>(wq, wk, wvm, wo,
                                             qB, kB, vB, oB,
                                             qA, kA, vA, oA,
                                             Wq, Wk, Wv, Wo, lscale);
  rmsnorm_k<<<dim3(4096), 256, 0, stream>>>(x, normw, h);
  gemm256_k<<<dim3(8,16,3), 512, 0, stream>>>(h, Wq,Wk,Wv, Qb,Kb,Vb);
  rope_k<<<dim3(8192), 256, 0, stream>>>(Qb, Kb);
  attn_k<<<dim3(1024), 256, 0, stream>>>(Qb, Kb, Vb, AO);
  gemm_k<<<dim3(16,32,1), 256, 0, stream>>>(AO, Wo, x, (float*)d_out);
}

// Round 6
// 305.091 us; speedup vs baseline: 3.9821x; 1.0091x over previous
//
#include <hip/hip_runtime.h>
#include <hip/hip_bf16.h>

#define LNUM 2048
#define DNUM 2048
#define HNUM 16
#define DHNUM 128
#define MTOK 4096   // B*L
#define WINSZ 512

typedef __attribute__((ext_vector_type(8))) short bf16x8;
typedef __attribute__((ext_vector_type(4))) short bf16x4;
typedef __attribute__((ext_vector_type(4))) float f32x4;

#define GLOBAL_AS __attribute__((address_space(1)))
#define LDS_AS __attribute__((address_space(3)))

__device__ __forceinline__ unsigned short f2bf(float f) {
  union { float f; unsigned u; } v; v.f = f;
  unsigned r = v.u + 0x7FFFu + ((v.u >> 16) & 1u);
  return (unsigned short)(r >> 16);
}
__device__ __forceinline__ float bf2f(unsigned short h) {
  union { unsigned u; float f; } v; v.u = ((unsigned)h) << 16;
  return v.f;
}

// ---------------- W_eff = W + s * Bm @ Am  (rank-16 fold), fp32 -> bf16 ----------------
__global__ __launch_bounds__(256) void weff_k(
    const float* __restrict__ w0, const float* __restrict__ w1,
    const float* __restrict__ w2, const float* __restrict__ w3,
    const float* __restrict__ b0, const float* __restrict__ b1,
    const float* __restrict__ b2, const float* __restrict__ b3,
    const float* __restrict__ a0, const float* __restrict__ a1,
    const float* __restrict__ a2, const float* __restrict__ a3,
    unsigned short* __restrict__ o0, unsigned short* __restrict__ o1,
    unsigned short* __restrict__ o2, unsigned short* __restrict__ o3,
    float s) {
  const int z = blockIdx.z;
  const float* W = z==0?w0:z==1?w1:z==2?w2:w3;
  const float* Bm = z==0?b0:z==1?b1:z==2?b2:b3;
  const float* Am = z==0?a0:z==1?a1:z==2?a2:a3;
  unsigned short* out = z==0?o0:z==1?o1:z==2?o2:o3;

  const int col = blockIdx.x * 1024 + threadIdx.x * 4;
  const int row0 = blockIdx.y * 64;

  float4 av[16];
  #pragma unroll
  for (int j = 0; j < 16; j++) av[j] = *(const float4*)(Am + (size_t)j * DNUM + col);

  for (int r = 0; r < 64; r++) {
    const int n = row0 + r;
    const float* brow = Bm + (size_t)n * 16;
    float dx = 0.f, dy = 0.f, dz = 0.f, dw = 0.f;
    #pragma unroll
    for (int j = 0; j < 16; j++) {
      const float bj = brow[j];
      dx = fmaf(bj, av[j].x, dx); dy = fmaf(bj, av[j].y, dy);
      dz = fmaf(bj, av[j].z, dz); dw = fmaf(bj, av[j].w, dw);
    }
    const float4 wv = *(const float4*)(W + (size_t)n * DNUM + col);
    ushort4 o;
    o.x = f2bf(wv.x + s*dx); o.y = f2bf(wv.y + s*dy);
    o.z = f2bf(wv.z + s*dz); o.w = f2bf(wv.w + s*dw);
    *(ushort4*)(out + (size_t)n * DNUM + col) = o;
  }
}

// ---------------- RMSNorm -> bf16 ----------------
__global__ __launch_bounds__(256) void rmsnorm_k(const float* __restrict__ x,
                                                 const float* __restrict__ w,
                                                 unsigned short* __restrict__ h) {
  const int row = blockIdx.x;
  const int t = threadIdx.x;
  const float4* xr = (const float4*)(x + (size_t)row * DNUM);
  float4 v0 = xr[t];
  float4 v1 = xr[t + 256];
  float ss = v0.x*v0.x + v0.y*v0.y + v0.z*v0.z + v0.w*v0.w +
             v1.x*v1.x + v1.y*v1.y + v1.z*v1.z + v1.w*v1.w;
  #pragma unroll
  for (int off = 32; off > 0; off >>= 1) ss += __shfl_xor(ss, off);
  __shared__ float red[4];
  if ((t & 63) == 0) red[t >> 6] = ss;
  __syncthreads();
  const float r = rsqrtf((red[0]+red[1]+red[2]+red[3]) * (1.0f/DNUM) + 1e-6f);
  const float4* wr4 = (const float4*)w;
  float4 w0 = wr4[t], w1 = wr4[t+256];
  ushort4 o0, o1;
  o0.x = f2bf(v0.x*r*w0.x); o0.y = f2bf(v0.y*r*w0.y);
  o0.z = f2bf(v0.z*r*w0.z); o0.w = f2bf(v0.w*r*w0.w);
  o1.x = f2bf(v1.x*r*w1.x); o1.y = f2bf(v1.y*r*w1.y);
  o1.z = f2bf(v1.z*r*w1.z); o1.w = f2bf(v1.w*r*w1.w);
  ushort4* hp = (ushort4*)(h + (size_t)row * DNUM);
  hp[t] = o0; hp[t + 256] = o1;
}

// ---------------- 256x256 8-phase GEMM (T2+T3+T4+T5), BK=64, 8 waves ----------------
// C = A(bf16, M x K) @ W^T(bf16, N x K), bf16 out.
// Fragment mapping: A-row(m,wr,r4) = m*32 + wr*16 + r4  (m 0..7, wr 0..1)
//                   B-col(n,wc,r4) = n*64 + wc*16 + r4  (n 0..3, wc 0..3)
// so quadrant (mh,nh) reads ONLY A-half mh and B-half nh -> half-tile slots
// free for restaging one phase after their single read phase.
// LDS chunks: [d][h][kh][rc] of 16 rows x 32 shorts (1KB); source-swizzled
// col-groups (proven 0-conflict): write pos p <- global group p^((row>>1)&3),
// read group g at pos g^((r4>>1)&3).
// Schedule per K-tile t (4 phases): ph1 reads A-h0+B-h0, stages A-h1(t+1);
// ph2 reads B-h1, stages A-h0(t+2); ph3 reads A-h1, stages B-h0(t+2);
// ph4 stages B-h1(t+2), vmcnt(6) (=3 half-tiles in flight), barrier.
#define NT8 (DNUM/64)
#define BAR8 asm volatile("s_barrier" ::: "memory")

__global__ __launch_bounds__(512, 1) void gemm8p_k(
    const unsigned short* __restrict__ Am,
    const unsigned short* __restrict__ W0, const unsigned short* __restrict__ W1, const unsigned short* __restrict__ W2,
    unsigned short* __restrict__ O0, unsigned short* __restrict__ O1, unsigned short* __restrict__ O2)
{
  const int z = blockIdx.z;
  const unsigned short* W = z==0?W0:(z==1?W1:W2);
  unsigned short* Ob = z==0?O0:(z==1?O1:O2);

  const int row0 = blockIdx.y * 256;
  const int col0 = blockIdx.x * 256;
  const int tid = threadIdx.x;
  const int wv = tid >> 6, lane = tid & 63;
  const int wr = wv >> 2, wc = wv & 3;
  const int g = lane >> 4, r4 = lane & 15;

  __shared__ unsigned short lds8[65536];   // A: [0,32768), B: [32768,65536)

  // stage source offsets (per lane)
  const int rp = lane >> 2;
  const int sg8 = (((lane & 3) ^ ((rp >> 1) & 3))) * 8;

  // stage one half-tile (2 x global_load_lds per wave)
  auto stage = [&](const unsigned short* P, int tb, int matbase, int d, int h, int k0) {
    const int row = tb + h*128 + wv*16 + rp;
    const size_t so = (size_t)row * DNUM + k0 + sg8;
    #pragma unroll
    for (int kh = 0; kh < 2; kh++) {
      __builtin_amdgcn_global_load_lds((const GLOBAL_AS void*)(P + so + kh*32),
          (LDS_AS void*)&lds8[matbase + (((d*2 + h)*2 + kh)*8 + wv)*512], 16, 0, 0);
    }
  };

  f32x4 acc[8][4];
  #pragma unroll
  for (int m = 0; m < 8; m++)
    #pragma unroll
    for (int n = 0; n < 4; n++) acc[m][n] = f32x4{0.f,0.f,0.f,0.f};

  // prologue: tile0 (4 half-tiles) + tile1 (3 half-tiles; A-h1(1) staged in t=0 ph1)
  stage(Am, row0, 0,     0, 0, 0);
  stage(W,  col0, 32768, 0, 0, 0);
  stage(W,  col0, 32768, 0, 1, 0);
  stage(Am, row0, 0,     0, 1, 0);
  stage(Am, row0, 0,     1, 0, 64);
  stage(W,  col0, 32768, 1, 0, 64);
  stage(W,  col0, 32768, 1, 1, 64);
  asm volatile("s_waitcnt vmcnt(6)" ::: "memory");
  BAR8;

  const int cg = (g ^ ((r4 >> 1) & 3)) * 8;
  bf16x8 af[4][2], bb[4][2];

  for (int t = 0; t < NT8; t++) {
    const int d = t & 1;
    const int kN1 = (t + 1) * 64, kN2 = (t + 2) * 64;

    // ---------- phase 1: read A-h0 + B-h0, compute (mh0,nh0) ----------
    #pragma unroll
    for (int i = 0; i < 4; i++)
      #pragma unroll
      for (int kh = 0; kh < 2; kh++)
        af[i][kh] = *(const bf16x8*)&lds8[(((d*2 + 0)*2 + kh)*8 + i*2 + wr)*512 + r4*32 + cg];
    #pragma unroll
    for (int n = 0; n < 2; n++)
      #pragma unroll
      for (int kh = 0; kh < 2; kh++)
        bb[n][kh] = *(const bf16x8*)&lds8[32768 + (((d*2 + 0)*2 + kh)*8 + n*4 + wc)*512 + r4*32 + cg];
    if (t + 1 < NT8) stage(Am, row0, 0, d^1, 1, kN1);     // A-h1(t+1)
    BAR8;
    __builtin_amdgcn_s_setprio(1);
    #pragma unroll
    for (int i = 0; i < 4; i++)
      #pragma unroll
      for (int n = 0; n < 2; n++)
        #pragma unroll
        for (int kh = 0; kh < 2; kh++)
          acc[i][n] = __builtin_amdgcn_mfma_f32_16x16x32_bf16(af[i][kh], bb[n][kh], acc[i][n], 0, 0, 0);
    __builtin_amdgcn_s_setprio(0);
    BAR8;

    // ---------- phase 2: read B-h1, compute (mh0,nh1) ----------
    #pragma unroll
    for (int n = 2; n < 4; n++)
      #pragma unroll
      for (int kh = 0; kh < 2; kh++)
        bb[n][kh] = *(const bf16x8*)&lds8[32768 + (((d*2 + 1)*2 + kh)*8 + (n-2)*4 + wc)*512 + r4*32 + cg];
    if (t + 2 < NT8) stage(Am, row0, 0, d, 0, kN2);       // A-h0(t+2)
    BAR8;
    __builtin_amdgcn_s_setprio(1);
    #pragma unroll
    for (int i = 0; i < 4; i++)
      #pragma unroll
      for (int n = 2; n < 4; n++)
        #pragma unroll
        for (int kh = 0; kh < 2; kh++)
          acc[i][n] = __builtin_amdgcn_mfma_f32_16x16x32_bf16(af[i][kh], bb[n][kh], acc[i][n], 0, 0, 0);
    __builtin_amdgcn_s_setprio(0);
    BAR8;

    // ---------- phase 3: read A-h1, compute (mh1,nh0) ----------
    #pragma unroll
    for (int i = 0; i < 4; i++)
      #pragma unroll
      for (int kh = 0; kh < 2; kh++)
        af[i][kh] = *(const bf16x8*)&lds8[(((d*2 + 1)*2 + kh)*8 + i*2 + wr)*512 + r4*32 + cg];
    if (t + 2 < NT8) stage(W, col0, 32768, d, 0, kN2);    // B-h0(t+2)
    BAR8;
    __builtin_amdgcn_s_setprio(1);
    #pragma unroll
    for (int i = 0; i < 4; i++)
      #pragma unroll
      for (int n = 0; n < 2; n++)
        #pragma unroll
        for (int kh = 0; kh < 2; kh++)
          acc[4+i][n] = __builtin_amdgcn_mfma_f32_16x16x32_bf16(af[i][kh], bb[n][kh], acc[4+i][n], 0, 0, 0);
    __builtin_amdgcn_s_setprio(0);
    BAR8;

    // ---------- phase 4: compute (mh1,nh1), stage B-h1(t+2), vmcnt ----------
    if (t + 2 < NT8) stage(W, col0, 32768, d, 1, kN2);    // B-h1(t+2)
    BAR8;
    __builtin_amdgcn_s_setprio(1);
    #pragma unroll
    for (int i = 0; i < 4; i++)
      #pragma unroll
      for (int n = 2; n < 4; n++)
        #pragma unroll
        for (int kh = 0; kh < 2; kh++)
          acc[4+i][n] = __builtin_amdgcn_mfma_f32_16x16x32_bf16(af[i][kh], bb[n][kh], acc[4+i][n], 0, 0, 0);
    __builtin_amdgcn_s_setprio(0);
    if (t + 2 < NT8) { asm volatile("s_waitcnt vmcnt(6)" ::: "memory"); }
    else             { asm volatile("s_waitcnt vmcnt(0)" ::: "memory"); }
    BAR8;
  }

  #pragma unroll
  for (int m = 0; m < 8; m++) {
    #pragma unroll
    for (int rg = 0; rg < 4; rg++) {
      const int row = row0 + m*32 + wr*16 + 4*g + rg;
      #pragma unroll
      for (int n = 0; n < 4; n++) {
        const int col = col0 + n*64 + wc*16 + r4;
        Ob[(size_t)row * DNUM + col] = f2bf(acc[m][n][rg]);
      }
    }
  }
}

// ---------------- 128x128-tile GEMM (m97 structure), final O-proj ----------------
__global__ __launch_bounds__(256, 3) void gemm_k(
    const unsigned short* __restrict__ Am,
    const unsigned short* __restrict__ W0,
    const float* __restrict__ resid, float* __restrict__ Of)
{
  const unsigned short* W = W0;

  const int row0 = blockIdx.y * 128;
  const int col0 = blockIdx.x * 128;
  const int tid = threadIdx.x;
  const int wv = tid >> 6, lane = tid & 63;
  const int wr = wv >> 1, wc = wv & 1;
  const int g = lane >> 4, r4 = lane & 15;

  __shared__ unsigned short lds[2][2][4096];   // [buf][A/B][128*32]

  f32x4 acc[4][4];
  #pragma unroll
  for (int m=0;m<4;m++)
    #pragma unroll
    for (int n=0;n<4;n++) acc[m][n] = f32x4{0.f,0.f,0.f,0.f};

  auto stage = [&](int buf, int k0) {
    #pragma unroll
    for (int qq = 0; qq < 2; qq++) {
      const int chunk = wv*2 + qq;
      const int rp = chunk*16 + (lane >> 2);
      const int cl = (lane & 3) ^ ((rp >> 1) & 3);   // XOR swizzle (involution)
      const unsigned short* ga = Am + (size_t)(row0 + rp) * DNUM + k0 + cl*8;
      __builtin_amdgcn_global_load_lds((const GLOBAL_AS void*)ga,
          (LDS_AS void*)&lds[buf][0][chunk*512], 16, 0, 0);
      const unsigned short* gb = W + (size_t)(col0 + rp) * DNUM + k0 + cl*8;
      __builtin_amdgcn_global_load_lds((const GLOBAL_AS void*)gb,
          (LDS_AS void*)&lds[buf][1][chunk*512], 16, 0, 0);
    }
  };

  stage(0, 0);
  const int nk = DNUM / 32;
  for (int kt = 0; kt < nk; kt++) {
    __syncthreads();
    if (kt + 1 < nk) stage((kt+1) & 1, (kt+1)*32);
    const unsigned short* As = &lds[kt&1][0][0];
    const unsigned short* Bs = &lds[kt&1][1][0];
    bf16x8 af[4], bb[4];
    #pragma unroll
    for (int m = 0; m < 4; m++) {
      const int R = wr*64 + m*16 + r4;
      af[m] = *(const bf16x8*)((const char*)As + R*64 + ((g ^ ((R>>1)&3))*16));
    }
    #pragma unroll
    for (int n = 0; n < 4; n++) {
      const int R = wc*64 + n*16 + r4;
      bb[n] = *(const bf16x8*)((const char*)Bs + R*64 + ((g ^ ((R>>1)&3))*16));
    }
    #pragma unroll
    for (int m = 0; m < 4; m++)
      #pragma unroll
      for (int n = 0; n < 4; n++)
        acc[m][n] = __builtin_amdgcn_mfma_f32_16x16x32_bf16(af[m], bb[n], acc[m][n], 0, 0, 0);
  }

  #pragma unroll
  for (int m = 0; m < 4; m++) {
    #pragma unroll
    for (int rg = 0; rg < 4; rg++) {
      const int row = row0 + wr*64 + m*16 + 4*g + rg;
      #pragma unroll
      for (int n = 0; n < 4; n++) {
        const int col = col0 + wc*64 + n*16 + r4;
        Of[(size_t)row * DNUM + col] = acc[m][n][rg] + resid[(size_t)row * DNUM + col];
      }
    }
  }
}

// ---------------- RoPE in-place (Q also pre-scaled by 1/sqrt(DH)), uint-pair vectorized ----------------
__global__ __launch_bounds__(256) void rope_k(unsigned short* __restrict__ Qm,
                                              unsigned short* __restrict__ Km) {
  const int u = blockIdx.x * 256 + threadIdx.x;
  const int t2 = u & 31;              // d-pair index: d0 = 2*t2
  const int hh = (u >> 5) & (HNUM-1);
  const int i = u >> 9;               // token
  const int l = i & (LNUM - 1);
  const int d0 = 2 * t2;
  const float C = 0.14391156831212787f;  // ln(10000)/64
  const float th0 = __expf(-(float)d0 * C);
  const float th1 = __expf(-(float)(d0+1) * C);
  float sn0, cs0, sn1, cs1;
  __sincosf((float)l * th0, &sn0, &cs0);
  __sincosf((float)l * th1, &sn1, &cs1);
  const size_t base = (size_t)i * DNUM + hh * DHNUM + d0;
  const float qs = 0.08838834764831845f;  // 1/sqrt(128)

  unsigned qa = *(const unsigned*)(Qm + base);
  unsigned qb = *(const unsigned*)(Qm + base + 64);
  float a0 = bf2f((unsigned short)qa), a1 = bf2f((unsigned short)(qa >> 16));
  float b0 = bf2f((unsigned short)qb), b1 = bf2f((unsigned short)(qb >> 16));
  unsigned lo = (unsigned)f2bf((a0*cs0 - b0*sn0) * qs) | ((unsigned)f2bf((a1*cs1 - b1*sn1) * qs) << 16);
  unsigned hi = (unsigned)f2bf((b0*cs0 + a0*sn0) * qs) | ((unsigned)f2bf((b1*cs1 + a1*sn1) * qs) << 16);
  *(unsigned*)(Qm + base) = lo;
  *(unsigned*)(Qm + base + 64) = hi;

  unsigned ka = *(const unsigned*)(Km + base);
  unsigned kb = *(const unsigned*)(Km + base + 64);
  a0 = bf2f((unsigned short)ka); a1 = bf2f((unsigned short)(ka >> 16));
  b0 = bf2f((unsigned short)kb); b1 = bf2f((unsigned short)(kb >> 16));
  lo = (unsigned)f2bf(a0*cs0 - b0*sn0) | ((unsigned)f2bf(a1*cs1 - b1*sn1) << 16);
  hi = (unsigned)f2bf(b0*cs0 + a0*sn0) | ((unsigned)f2bf(b1*cs1 + a1*sn1) << 16);
  *(unsigned*)(Km + base) = lo;
  *(unsigned*)(Km + base + 64) = hi;
}

// ---------------- sliding-window flash attention ----------------
__global__ __launch_bounds__(256) void attn_k(const unsigned short* __restrict__ Q,
                                              const unsigned short* __restrict__ K,
                                              const unsigned short* __restrict__ V,
                                              unsigned short* __restrict__ O) {
  __shared__ unsigned short vsl[4][2176];  // per-wave [16 rows][136 shorts] (pad 8)
  const int tid = threadIdx.x, wv = tid >> 6, lane = tid & 63;
  const int g = lane >> 4, r4 = lane & 15;
  const int bidx = blockIdx.x;
  const int q4 = bidx & 31, hh = (bidx >> 5) & 15, b = bidx >> 9;
  const int q0 = q4 * 64 + wv * 16;
  const size_t bh = (size_t)b * LNUM * DNUM + (size_t)hh * DHNUM;

  unsigned short* vs = &vsl[wv][0];

  // Q fragments (B-operand of swapped QK^T): lane holds Q[q0+r4][dc*32+g*8 ..+7]
  bf16x8 qf[4];
  {
    const unsigned short* qr = Q + bh + (size_t)(q0 + r4) * DNUM;
    #pragma unroll
    for (int dc = 0; dc < 4; dc++) qf[dc] = *(const bf16x8*)(qr + dc*32 + g*8);
  }
  f32x4 oacc[8];
  #pragma unroll
  for (int c = 0; c < 8; c++) oacc[c] = f32x4{0.f,0.f,0.f,0.f};
  float mrun = -1e30f, lrun = 0.f;

  const int kt_lo = (q0 >= WINSZ) ? ((q0 - WINSZ + 1) >> 4) : 0;
  const int kt_hi = q0 >> 4;
  const int qi = q0 + r4;

  for (int kt = kt_lo; kt <= kt_hi; kt++) {
    const int k0 = kt * 16;
    // stage V tile (16 keys x 128 d) row-major into padded LDS
    {
      const unsigned short* vb = V + bh + (size_t)k0 * DNUM;
      #pragma unroll
      for (int p = 0; p < 4; p++) {
        const int key = g + p*4;
        *(uint4*)(vs + key*136 + r4*8) = *(const uint4*)(vb + (size_t)key * DNUM + r4*8);
      }
    }
    // S^T = K . Q^T  (D: row=key=4g+reg, col=q=r4)
    f32x4 st = f32x4{0.f,0.f,0.f,0.f};
    {
      const unsigned short* kr = K + bh + (size_t)(k0 + r4) * DNUM;
      #pragma unroll
      for (int dc = 0; dc < 4; dc++) {
        const bf16x8 kf = *(const bf16x8*)(kr + dc*32 + g*8);
        st = __builtin_amdgcn_mfma_f32_16x16x32_bf16(kf, qf[dc], st, 0, 0, 0);
      }
    }
    // mask + online softmax (per q-column = r4)
    const int kj = k0 + 4*g;
    const float sv0 = (kj   <= qi && kj   > qi - WINSZ) ? st[0] : -1e30f;
    const float sv1 = (kj+1 <= qi && kj+1 > qi - WINSZ) ? st[1] : -1e30f;
    const float sv2 = (kj+2 <= qi && kj+2 > qi - WINSZ) ? st[2] : -1e30f;
    const float sv3 = (kj+3 <= qi && kj+3 > qi - WINSZ) ? st[3] : -1e30f;
    float pmax = fmaxf(fmaxf(sv0, sv1), fmaxf(sv2, sv3));
    pmax = fmaxf(pmax, __shfl_xor(pmax, 16));
    pmax = fmaxf(pmax, __shfl_xor(pmax, 32));
    const float mnew = fmaxf(mrun, pmax);
    const float sc_old = __expf(mrun - mnew);   // per query r4
    const float p0 = __expf(sv0 - mnew), p1 = __expf(sv1 - mnew);
    const float p2 = __expf(sv2 - mnew), p3 = __expf(sv3 - mnew);
    float psum = p0 + p1 + p2 + p3;
    psum += __shfl_xor(psum, 16);
    psum += __shfl_xor(psum, 32);
    lrun = lrun * sc_old + psum;
    mrun = mnew;
    bf16x4 pf;
    pf[0] = (short)f2bf(p0); pf[1] = (short)f2bf(p1);
    pf[2] = (short)f2bf(p2); pf[3] = (short)f2bf(p3);
    // rescale oacc: its rows are queries 4g+rg -> gather each row's own sc_old
    float sc4[4];
    #pragma unroll
    for (int rg = 0; rg < 4; rg++) sc4[rg] = __shfl(sc_old, 4*g + rg);
    #pragma unroll
    for (int c = 0; c < 8; c++) {
      oacc[c][0] *= sc4[0]; oacc[c][1] *= sc4[1];
      oacc[c][2] *= sc4[2]; oacc[c][3] *= sc4[3];
    }
    // PV: O[q][d] += P . V   (A-frag = pf; B-frag = V[key=4g+j][d=dblk*16+r4])
    #pragma unroll
    for (int dblk = 0; dblk < 8; dblk++) {
      bf16x4 vf;
      vf[0] = (short)vs[(4*g+0)*136 + dblk*16 + r4];
      vf[1] = (short)vs[(4*g+1)*136 + dblk*16 + r4];
      vf[2] = (short)vs[(4*g+2)*136 + dblk*16 + r4];
      vf[3] = (short)vs[(4*g+3)*136 + dblk*16 + r4];
      oacc[dblk] = __builtin_amdgcn_mfma_f32_16x16x16bf16_1k(pf, vf, oacc[dblk], 0, 0, 0);
    }
  }

  // epilogue: normalize (per-query l gathered via shuffle), transpose via LDS, store
  const float inv = 1.0f / lrun;   // valid for query q0 + r4
  float linv[4];
  #pragma unroll
  for (int rg = 0; rg < 4; rg++) linv[rg] = __shfl(inv, 4*g + rg);
  #pragma unroll
  for (int dblk = 0; dblk < 8; dblk++) {
    #pragma unroll
    for (int rg = 0; rg < 4; rg++) {
      vs[(4*g + rg)*136 + dblk*16 + r4] = f2bf(oacc[dblk][rg] * linv[rg]);
    }
  }
  #pragma unroll
  for (int p = 0; p < 4; p++) {
    const int qq = p*4 + g;
    const uint4 vvv = *(const uint4*)(vs + qq*136 + r4*8);
    *(uint4*)(O + bh + (size_t)(q0 + qq) * DNUM + r4*8) = vvv;
  }
}

// ---------------- launch ----------------
extern "C" void kernel_launch(void* const* d_in, const int* in_sizes, int n_in,
                              void* d_out, int out_size, void* d_ws, size_t ws_size,
                              hipStream_t stream) {
  (void)in_sizes; (void)n_in; (void)out_size; (void)ws_size;
  const float* x     = (const float*)d_in[0];
  const float* normw = (const float*)d_in[1];
  const float* wq = (const float*)d_in[2];
  const float* wk = (const float*)d_in[3];
  const float* wvm = (const float*)d_in[4];
  const float* wo = (const float*)d_in[5];
  const float* qA = (const float*)d_in[6];
  const float* qB = (const float*)d_in[7];
  const float* kA = (const float*)d_in[8];
  const float* kB = (const float*)d_in[9];
  const float* vA = (const float*)d_in[10];
  const float* vB = (const float*)d_in[11];
  const float* oA = (const float*)d_in[12];
  const float* oB = (const float*)d_in[13];

  char* w = (char*)d_ws;
  const size_t SZ = (size_t)MTOK * DNUM * 2;   // 16 MiB per bf16 activation
  unsigned short* h  = (unsigned short*)(w);
  unsigned short* Qb = (unsigned short*)(w + SZ);
  unsigned short* Kb = (unsigned short*)(w + 2*SZ);
  unsigned short* Vb = (unsigned short*)(w + 3*SZ);
  unsigned short* AO = (unsigned short*)(w + 4*SZ);
  unsigned short* Wq = (unsigned short*)(w + 5*SZ);
  unsigned short* Wk = Wq + (size_t)DNUM*DNUM;
  unsigned short* Wv = Wk + (size_t)DNUM*DNUM;
  unsigned short* Wo = Wv + (size_t)DNUM*DNUM;

  const float lscale = 1.0f / 16.0f;

  // W_eff = W + s*B@A for q,k,v,o  (associativity fold of the LoRA branch)
  weff_k<<<dim3(2, 32, 4), 256, 0, stream>>>(wq, wk, wvm, wo,
                                             qB, kB, vB, oB,
                                             qA, kA, vA, oA,
                                             Wq, Wk, Wv, Wo, lscale);
  rmsnorm_k<<<dim3(4096), 256, 0, stream>>>(x, normw, h);
  gemm8p_k<<<dim3(8,16,3), 512, 0, stream>>>(h, Wq,Wk,Wv, Qb,Kb,Vb);
  rope_k<<<dim3(8192), 256, 0, stream>>>(Qb, Kb);
  attn_k<<<dim3(1024), 256, 0, stream>>>(Qb, Kb, Vb, AO);
  gemm_k<<<dim3(16,32,1), 256, 0, stream>>>(AO, Wo, x, (float*)d_out);
}

// Round 7
// 295.746 us; speedup vs baseline: 4.1079x; 1.0316x over previous
//
#include <hip/hip_runtime.h>
#include <hip/hip_bf16.h>

#define LNUM 2048
#define DNUM 2048
#define HNUM 16
#define DHNUM 128
#define MTOK 4096   // B*L
#define WINSZ 512

typedef __attribute__((ext_vector_type(8))) short bf16x8;
typedef __attribute__((ext_vector_type(4))) short bf16x4;
typedef __attribute__((ext_vector_type(4))) float f32x4;

#define GLOBAL_AS __attribute__((address_space(1)))
#define LDS_AS __attribute__((address_space(3)))

__device__ __forceinline__ unsigned short f2bf(float f) {
  union { float f; unsigned u; } v; v.f = f;
  unsigned r = v.u + 0x7FFFu + ((v.u >> 16) & 1u);
  return (unsigned short)(r >> 16);
}
__device__ __forceinline__ float bf2f(unsigned short h) {
  union { unsigned u; float f; } v; v.u = ((unsigned)h) << 16;
  return v.f;
}

// ---------------- W_eff = W + s * Bm @ Am  (rank-16 fold), fp32 -> bf16 ----------------
__global__ __launch_bounds__(256) void weff_k(
    const float* __restrict__ w0, const float* __restrict__ w1,
    const float* __restrict__ w2, const float* __restrict__ w3,
    const float* __restrict__ b0, const float* __restrict__ b1,
    const float* __restrict__ b2, const float* __restrict__ b3,
    const float* __restrict__ a0, const float* __restrict__ a1,
    const float* __restrict__ a2, const float* __restrict__ a3,
    unsigned short* __restrict__ o0, unsigned short* __restrict__ o1,
    unsigned short* __restrict__ o2, unsigned short* __restrict__ o3,
    float s) {
  const int z = blockIdx.z;
  const float* W = z==0?w0:z==1?w1:z==2?w2:w3;
  const float* Bm = z==0?b0:z==1?b1:z==2?b2:b3;
  const float* Am = z==0?a0:z==1?a1:z==2?a2:a3;
  unsigned short* out = z==0?o0:z==1?o1:z==2?o2:o3;

  const int col = blockIdx.x * 1024 + threadIdx.x * 4;
  const int row0 = blockIdx.y * 64;

  float4 av[16];
  #pragma unroll
  for (int j = 0; j < 16; j++) av[j] = *(const float4*)(Am + (size_t)j * DNUM + col);

  for (int r = 0; r < 64; r++) {
    const int n = row0 + r;
    const float* brow = Bm + (size_t)n * 16;
    float dx = 0.f, dy = 0.f, dz = 0.f, dw = 0.f;
    #pragma unroll
    for (int j = 0; j < 16; j++) {
      const float bj = brow[j];
      dx = fmaf(bj, av[j].x, dx); dy = fmaf(bj, av[j].y, dy);
      dz = fmaf(bj, av[j].z, dz); dw = fmaf(bj, av[j].w, dw);
    }
    const float4 wv = *(const float4*)(W + (size_t)n * DNUM + col);
    ushort4 o;
    o.x = f2bf(wv.x + s*dx); o.y = f2bf(wv.y + s*dy);
    o.z = f2bf(wv.z + s*dz); o.w = f2bf(wv.w + s*dw);
    *(ushort4*)(out + (size_t)n * DNUM + col) = o;
  }
}

// ---------------- RMSNorm -> bf16 ----------------
__global__ __launch_bounds__(256) void rmsnorm_k(const float* __restrict__ x,
                                                 const float* __restrict__ w,
                                                 unsigned short* __restrict__ h) {
  const int row = blockIdx.x;
  const int t = threadIdx.x;
  const float4* xr = (const float4*)(x + (size_t)row * DNUM);
  float4 v0 = xr[t];
  float4 v1 = xr[t + 256];
  float ss = v0.x*v0.x + v0.y*v0.y + v0.z*v0.z + v0.w*v0.w +
             v1.x*v1.x + v1.y*v1.y + v1.z*v1.z + v1.w*v1.w;
  #pragma unroll
  for (int off = 32; off > 0; off >>= 1) ss += __shfl_xor(ss, off);
  __shared__ float red[4];
  if ((t & 63) == 0) red[t >> 6] = ss;
  __syncthreads();
  const float r = rsqrtf((red[0]+red[1]+red[2]+red[3]) * (1.0f/DNUM) + 1e-6f);
  const float4* wr4 = (const float4*)w;
  float4 w0 = wr4[t], w1 = wr4[t+256];
  ushort4 o0, o1;
  o0.x = f2bf(v0.x*r*w0.x); o0.y = f2bf(v0.y*r*w0.y);
  o0.z = f2bf(v0.z*r*w0.z); o0.w = f2bf(v0.w*r*w0.w);
  o1.x = f2bf(v1.x*r*w1.x); o1.y = f2bf(v1.y*r*w1.y);
  o1.z = f2bf(v1.z*r*w1.z); o1.w = f2bf(v1.w*r*w1.w);
  ushort4* hp = (ushort4*)(h + (size_t)row * DNUM);
  hp[t] = o0; hp[t + 256] = o1;
}

// ---------------- 256x256 8-phase GEMM (T2+T3+T4+T5), BK=64, 8 waves ----------------
#define NT8 (DNUM/64)
#define BAR8 asm volatile("s_barrier" ::: "memory")

__global__ __launch_bounds__(512, 1) void gemm8p_k(
    const unsigned short* __restrict__ Am,
    const unsigned short* __restrict__ W0, const unsigned short* __restrict__ W1, const unsigned short* __restrict__ W2,
    unsigned short* __restrict__ O0, unsigned short* __restrict__ O1, unsigned short* __restrict__ O2)
{
  const int z = blockIdx.z;
  const unsigned short* W = z==0?W0:(z==1?W1:W2);
  unsigned short* Ob = z==0?O0:(z==1?O1:O2);

  const int row0 = blockIdx.y * 256;
  const int col0 = blockIdx.x * 256;
  const int tid = threadIdx.x;
  const int wv = tid >> 6, lane = tid & 63;
  const int wr = wv >> 2, wc = wv & 3;
  const int g = lane >> 4, r4 = lane & 15;

  __shared__ unsigned short lds8[65536];   // A: [0,32768), B: [32768,65536)

  const int rp = lane >> 2;
  const int sg8 = (((lane & 3) ^ ((rp >> 1) & 3))) * 8;

  auto stage = [&](const unsigned short* P, int tb, int matbase, int d, int h, int k0) {
    const int row = tb + h*128 + wv*16 + rp;
    const size_t so = (size_t)row * DNUM + k0 + sg8;
    #pragma unroll
    for (int kh = 0; kh < 2; kh++) {
      __builtin_amdgcn_global_load_lds((const GLOBAL_AS void*)(P + so + kh*32),
          (LDS_AS void*)&lds8[matbase + (((d*2 + h)*2 + kh)*8 + wv)*512], 16, 0, 0);
    }
  };

  f32x4 acc[8][4];
  #pragma unroll
  for (int m = 0; m < 8; m++)
    #pragma unroll
    for (int n = 0; n < 4; n++) acc[m][n] = f32x4{0.f,0.f,0.f,0.f};

  stage(Am, row0, 0,     0, 0, 0);
  stage(W,  col0, 32768, 0, 0, 0);
  stage(W,  col0, 32768, 0, 1, 0);
  stage(Am, row0, 0,     0, 1, 0);
  stage(Am, row0, 0,     1, 0, 64);
  stage(W,  col0, 32768, 1, 0, 64);
  stage(W,  col0, 32768, 1, 1, 64);
  asm volatile("s_waitcnt vmcnt(6)" ::: "memory");
  BAR8;

  const int cg = (g ^ ((r4 >> 1) & 3)) * 8;
  bf16x8 af[4][2], bb[4][2];

  for (int t = 0; t < NT8; t++) {
    const int d = t & 1;
    const int kN1 = (t + 1) * 64, kN2 = (t + 2) * 64;

    // phase 1
    #pragma unroll
    for (int i = 0; i < 4; i++)
      #pragma unroll
      for (int kh = 0; kh < 2; kh++)
        af[i][kh] = *(const bf16x8*)&lds8[(((d*2 + 0)*2 + kh)*8 + i*2 + wr)*512 + r4*32 + cg];
    #pragma unroll
    for (int n = 0; n < 2; n++)
      #pragma unroll
      for (int kh = 0; kh < 2; kh++)
        bb[n][kh] = *(const bf16x8*)&lds8[32768 + (((d*2 + 0)*2 + kh)*8 + n*4 + wc)*512 + r4*32 + cg];
    if (t + 1 < NT8) stage(Am, row0, 0, d^1, 1, kN1);
    BAR8;
    __builtin_amdgcn_s_setprio(1);
    #pragma unroll
    for (int i = 0; i < 4; i++)
      #pragma unroll
      for (int n = 0; n < 2; n++)
        #pragma unroll
        for (int kh = 0; kh < 2; kh++)
          acc[i][n] = __builtin_amdgcn_mfma_f32_16x16x32_bf16(af[i][kh], bb[n][kh], acc[i][n], 0, 0, 0);
    __builtin_amdgcn_s_setprio(0);
    BAR8;

    // phase 2
    #pragma unroll
    for (int n = 2; n < 4; n++)
      #pragma unroll
      for (int kh = 0; kh < 2; kh++)
        bb[n][kh] = *(const bf16x8*)&lds8[32768 + (((d*2 + 1)*2 + kh)*8 + (n-2)*4 + wc)*512 + r4*32 + cg];
    if (t + 2 < NT8) stage(Am, row0, 0, d, 0, kN2);
    BAR8;
    __builtin_amdgcn_s_setprio(1);
    #pragma unroll
    for (int i = 0; i < 4; i++)
      #pragma unroll
      for (int n = 2; n < 4; n++)
        #pragma unroll
        for (int kh = 0; kh < 2; kh++)
          acc[i][n] = __builtin_amdgcn_mfma_f32_16x16x32_bf16(af[i][kh], bb[n][kh], acc[i][n], 0, 0, 0);
    __builtin_amdgcn_s_setprio(0);
    BAR8;

    // phase 3
    #pragma unroll
    for (int i = 0; i < 4; i++)
      #pragma unroll
      for (int kh = 0; kh < 2; kh++)
        af[i][kh] = *(const bf16x8*)&lds8[(((d*2 + 1)*2 + kh)*8 + i*2 + wr)*512 + r4*32 + cg];
    if (t + 2 < NT8) stage(W, col0, 32768, d, 0, kN2);
    BAR8;
    __builtin_amdgcn_s_setprio(1);
    #pragma unroll
    for (int i = 0; i < 4; i++)
      #pragma unroll
      for (int n = 0; n < 2; n++)
        #pragma unroll
        for (int kh = 0; kh < 2; kh++)
          acc[4+i][n] = __builtin_amdgcn_mfma_f32_16x16x32_bf16(af[i][kh], bb[n][kh], acc[4+i][n], 0, 0, 0);
    __builtin_amdgcn_s_setprio(0);
    BAR8;

    // phase 4
    if (t + 2 < NT8) stage(W, col0, 32768, d, 1, kN2);
    BAR8;
    __builtin_amdgcn_s_setprio(1);
    #pragma unroll
    for (int i = 0; i < 4; i++)
      #pragma unroll
      for (int n = 2; n < 4; n++)
        #pragma unroll
        for (int kh = 0; kh < 2; kh++)
          acc[4+i][n] = __builtin_amdgcn_mfma_f32_16x16x32_bf16(af[i][kh], bb[n][kh], acc[4+i][n], 0, 0, 0);
    __builtin_amdgcn_s_setprio(0);
    if (t + 2 < NT8) { asm volatile("s_waitcnt vmcnt(6)" ::: "memory"); }
    else             { asm volatile("s_waitcnt vmcnt(0)" ::: "memory"); }
    BAR8;
  }

  #pragma unroll
  for (int m = 0; m < 8; m++) {
    #pragma unroll
    for (int rg = 0; rg < 4; rg++) {
      const int row = row0 + m*32 + wr*16 + 4*g + rg;
      #pragma unroll
      for (int n = 0; n < 4; n++) {
        const int col = col0 + n*64 + wc*16 + r4;
        Ob[(size_t)row * DNUM + col] = f2bf(acc[m][n][rg]);
      }
    }
  }
}

// ---------------- 128x128-tile GEMM (m97 structure), final O-proj ----------------
__global__ __launch_bounds__(256, 3) void gemm_k(
    const unsigned short* __restrict__ Am,
    const unsigned short* __restrict__ W0,
    const float* __restrict__ resid, float* __restrict__ Of)
{
  const unsigned short* W = W0;

  const int row0 = blockIdx.y * 128;
  const int col0 = blockIdx.x * 128;
  const int tid = threadIdx.x;
  const int wv = tid >> 6, lane = tid & 63;
  const int wr = wv >> 1, wc = wv & 1;
  const int g = lane >> 4, r4 = lane & 15;

  __shared__ unsigned short lds[2][2][4096];

  f32x4 acc[4][4];
  #pragma unroll
  for (int m=0;m<4;m++)
    #pragma unroll
    for (int n=0;n<4;n++) acc[m][n] = f32x4{0.f,0.f,0.f,0.f};

  auto stage = [&](int buf, int k0) {
    #pragma unroll
    for (int qq = 0; qq < 2; qq++) {
      const int chunk = wv*2 + qq;
      const int rp = chunk*16 + (lane >> 2);
      const int cl = (lane & 3) ^ ((rp >> 1) & 3);
      const unsigned short* ga = Am + (size_t)(row0 + rp) * DNUM + k0 + cl*8;
      __builtin_amdgcn_global_load_lds((const GLOBAL_AS void*)ga,
          (LDS_AS void*)&lds[buf][0][chunk*512], 16, 0, 0);
      const unsigned short* gb = W + (size_t)(col0 + rp) * DNUM + k0 + cl*8;
      __builtin_amdgcn_global_load_lds((const GLOBAL_AS void*)gb,
          (LDS_AS void*)&lds[buf][1][chunk*512], 16, 0, 0);
    }
  };

  stage(0, 0);
  const int nk = DNUM / 32;
  for (int kt = 0; kt < nk; kt++) {
    __syncthreads();
    if (kt + 1 < nk) stage((kt+1) & 1, (kt+1)*32);
    const unsigned short* As = &lds[kt&1][0][0];
    const unsigned short* Bs = &lds[kt&1][1][0];
    bf16x8 af[4], bb[4];
    #pragma unroll
    for (int m = 0; m < 4; m++) {
      const int R = wr*64 + m*16 + r4;
      af[m] = *(const bf16x8*)((const char*)As + R*64 + ((g ^ ((R>>1)&3))*16));
    }
    #pragma unroll
    for (int n = 0; n < 4; n++) {
      const int R = wc*64 + n*16 + r4;
      bb[n] = *(const bf16x8*)((const char*)Bs + R*64 + ((g ^ ((R>>1)&3))*16));
    }
    #pragma unroll
    for (int m = 0; m < 4; m++)
      #pragma unroll
      for (int n = 0; n < 4; n++)
        acc[m][n] = __builtin_amdgcn_mfma_f32_16x16x32_bf16(af[m], bb[n], acc[m][n], 0, 0, 0);
  }

  #pragma unroll
  for (int m = 0; m < 4; m++) {
    #pragma unroll
    for (int rg = 0; rg < 4; rg++) {
      const int row = row0 + wr*64 + m*16 + 4*g + rg;
      #pragma unroll
      for (int n = 0; n < 4; n++) {
        const int col = col0 + wc*64 + n*16 + r4;
        Of[(size_t)row * DNUM + col] = acc[m][n][rg] + resid[(size_t)row * DNUM + col];
      }
    }
  }
}

// ---------------- RoPE in-place (Q also pre-scaled by 1/sqrt(DH)) ----------------
__global__ __launch_bounds__(256) void rope_k(unsigned short* __restrict__ Qm,
                                              unsigned short* __restrict__ Km) {
  const int u = blockIdx.x * 256 + threadIdx.x;
  const int t2 = u & 31;
  const int hh = (u >> 5) & (HNUM-1);
  const int i = u >> 9;
  const int l = i & (LNUM - 1);
  const int d0 = 2 * t2;
  const float C = 0.14391156831212787f;  // ln(10000)/64
  const float th0 = __expf(-(float)d0 * C);
  const float th1 = __expf(-(float)(d0+1) * C);
  float sn0, cs0, sn1, cs1;
  __sincosf((float)l * th0, &sn0, &cs0);
  __sincosf((float)l * th1, &sn1, &cs1);
  const size_t base = (size_t)i * DNUM + hh * DHNUM + d0;
  const float qs = 0.08838834764831845f;  // 1/sqrt(128)

  unsigned qa = *(const unsigned*)(Qm + base);
  unsigned qb = *(const unsigned*)(Qm + base + 64);
  float a0 = bf2f((unsigned short)qa), a1 = bf2f((unsigned short)(qa >> 16));
  float b0 = bf2f((unsigned short)qb), b1 = bf2f((unsigned short)(qb >> 16));
  unsigned lo = (unsigned)f2bf((a0*cs0 - b0*sn0) * qs) | ((unsigned)f2bf((a1*cs1 - b1*sn1) * qs) << 16);
  unsigned hi = (unsigned)f2bf((b0*cs0 + a0*sn0) * qs) | ((unsigned)f2bf((b1*cs1 + a1*sn1) * qs) << 16);
  *(unsigned*)(Qm + base) = lo;
  *(unsigned*)(Qm + base + 64) = hi;

  unsigned ka = *(const unsigned*)(Km + base);
  unsigned kb = *(const unsigned*)(Km + base + 64);
  a0 = bf2f((unsigned short)ka); a1 = bf2f((unsigned short)(ka >> 16));
  b0 = bf2f((unsigned short)kb); b1 = bf2f((unsigned short)(kb >> 16));
  lo = (unsigned)f2bf(a0*cs0 - b0*sn0) | ((unsigned)f2bf(a1*cs1 - b1*sn1) << 16);
  hi = (unsigned)f2bf(b0*cs0 + a0*sn0) | ((unsigned)f2bf(b1*cs1 + a1*sn1) << 16);
  *(unsigned*)(Km + base) = lo;
  *(unsigned*)(Km + base + 64) = hi;
}

// ---------------- sliding-window flash attention (block-cooperative KV) ----------------
// Block = 64 queries (4 waves x 16 q). KV advances in 64-key tiles staged ONCE
// per block: K into chunk-swizzled LDS (global_load_lds; 16-row x 32-short
// chunks, src-side XOR — identical algebra to the GEMM staging, proven
// conflict-free), V reg-staged into padded [64][136] rows. Inner loop = 4
// kt-subtiles of 16 keys, per-wave skipped when outside the wave's window
// (skip ≡ compute: fully-masked tile gives sc_old=1, dl=0). Per-wave math
// identical to the verified round-3 kernel.
__global__ __launch_bounds__(256) void attn_k(const unsigned short* __restrict__ Q,
                                              const unsigned short* __restrict__ K,
                                              const unsigned short* __restrict__ V,
                                              unsigned short* __restrict__ O) {
  __shared__ unsigned short Kls[8192];   // 16 chunks x 512 shorts (chunk = [kh=d/32][rc=key/16])
  __shared__ unsigned short Vls[8704];   // 64 rows x 136 shorts (pad 8)
  const int tid = threadIdx.x, wv = tid >> 6, lane = tid & 63;
  const int g = lane >> 4, r4 = lane & 15;
  const int bidx = blockIdx.x;
  const int q4 = bidx & 31, hh = (bidx >> 5) & 15, b = bidx >> 9;
  const int q_base = q4 * 64;
  const int q0 = q_base + wv * 16;
  const size_t bh = (size_t)b * LNUM * DNUM + (size_t)hh * DHNUM;

  // Q fragments (B-operand of swapped QK^T): lane holds Q[q0+r4][dc*32+g*8 ..+7]
  bf16x8 qf[4];
  {
    const unsigned short* qr = Q + bh + (size_t)(q0 + r4) * DNUM;
    #pragma unroll
    for (int dc = 0; dc < 4; dc++) qf[dc] = *(const bf16x8*)(qr + dc*32 + g*8);
  }
  f32x4 oacc[8];
  #pragma unroll
  for (int c = 0; c < 8; c++) oacc[c] = f32x4{0.f,0.f,0.f,0.f};
  float mrun = -1e30f, lrun = 0.f;

  const int qi = q0 + r4;
  const int lo_key = (q_base >= WINSZ) ? (q_base - WINSZ + 1) : 0;
  const int t_lo = lo_key >> 6, t_hi = q_base >> 6;

  const int rp = lane >> 2;
  const int sg = (((lane & 3) ^ ((rp >> 1) & 3))) * 8;   // src-side chunk swizzle
  const int cgr = (g ^ ((r4 >> 1) & 3)) * 8;             // read-side position

  for (int t64 = t_lo; t64 <= t_hi; t64++) {
    const int k64 = t64 * 64;
    __syncthreads();   // previous tile's LDS reads complete
    // stage K: wave wv stages rows [wv*16, wv*16+16) for all 4 d-chunks
    #pragma unroll
    for (int q = 0; q < 4; q++) {
      const unsigned short* src = K + bh + (size_t)(k64 + wv*16 + rp) * DNUM + q*32 + sg;
      __builtin_amdgcn_global_load_lds((const GLOBAL_AS void*)src,
          (LDS_AS void*)&Kls[(q*4 + wv)*512], 16, 0, 0);
    }
    // stage V: 64 rows x 128 shorts, coalesced, padded rows
    #pragma unroll
    for (int p = 0; p < 4; p++) {
      const int row = (tid >> 4) + p*16;
      const int cg = tid & 15;
      *(uint4*)&Vls[row*136 + cg*8] =
          *(const uint4*)(V + bh + (size_t)(k64 + row) * DNUM + cg*8);
    }
    __syncthreads();   // drains vmcnt (global_load_lds) + lgkm

    #pragma unroll
    for (int kts = 0; kts < 4; kts++) {
      const int k0s = k64 + kts*16;
      if (k0s > q0 + 15 || k0s + 15 < q0 - (WINSZ - 1)) continue;  // wave-uniform
      // S^T = K . Q^T  (K frag from swizzled LDS)
      f32x4 st = f32x4{0.f,0.f,0.f,0.f};
      #pragma unroll
      for (int dc = 0; dc < 4; dc++) {
        const bf16x8 kf = *(const bf16x8*)&Kls[(dc*4 + kts)*512 + r4*32 + cgr];
        st = __builtin_amdgcn_mfma_f32_16x16x32_bf16(kf, qf[dc], st, 0, 0, 0);
      }
      // mask + online softmax (per q-column = r4)
      const int kj = k0s + 4*g;
      const float sv0 = (kj   <= qi && kj   > qi - WINSZ) ? st[0] : -1e30f;
      const float sv1 = (kj+1 <= qi && kj+1 > qi - WINSZ) ? st[1] : -1e30f;
      const float sv2 = (kj+2 <= qi && kj+2 > qi - WINSZ) ? st[2] : -1e30f;
      const float sv3 = (kj+3 <= qi && kj+3 > qi - WINSZ) ? st[3] : -1e30f;
      float pmax = fmaxf(fmaxf(sv0, sv1), fmaxf(sv2, sv3));
      pmax = fmaxf(pmax, __shfl_xor(pmax, 16));
      pmax = fmaxf(pmax, __shfl_xor(pmax, 32));
      const float mnew = fmaxf(mrun, pmax);
      const float sc_old = __expf(mrun - mnew);   // per query r4
      const float p0 = __expf(sv0 - mnew), p1 = __expf(sv1 - mnew);
      const float p2 = __expf(sv2 - mnew), p3 = __expf(sv3 - mnew);
      float psum = p0 + p1 + p2 + p3;
      psum += __shfl_xor(psum, 16);
      psum += __shfl_xor(psum, 32);
      lrun = lrun * sc_old + psum;
      mrun = mnew;
      bf16x4 pf;
      pf[0] = (short)f2bf(p0); pf[1] = (short)f2bf(p1);
      pf[2] = (short)f2bf(p2); pf[3] = (short)f2bf(p3);
      // rescale oacc: its rows are queries 4g+rg -> gather each row's own sc_old
      float sc4[4];
      #pragma unroll
      for (int rg = 0; rg < 4; rg++) sc4[rg] = __shfl(sc_old, 4*g + rg);
      #pragma unroll
      for (int c = 0; c < 8; c++) {
        oacc[c][0] *= sc4[0]; oacc[c][1] *= sc4[1];
        oacc[c][2] *= sc4[2]; oacc[c][3] *= sc4[3];
      }
      // PV: O[q][d] += P . V   (A-frag = pf; B-frag = V[key][d] transposed-scalar)
      const int vrow = kts*16 + 4*g;
      #pragma unroll
      for (int dblk = 0; dblk < 8; dblk++) {
        bf16x4 vf;
        vf[0] = (short)Vls[(vrow+0)*136 + dblk*16 + r4];
        vf[1] = (short)Vls[(vrow+1)*136 + dblk*16 + r4];
        vf[2] = (short)Vls[(vrow+2)*136 + dblk*16 + r4];
        vf[3] = (short)Vls[(vrow+3)*136 + dblk*16 + r4];
        oacc[dblk] = __builtin_amdgcn_mfma_f32_16x16x16bf16_1k(pf, vf, oacc[dblk], 0, 0, 0);
      }
    }
  }

  // epilogue: normalize, transpose via per-wave LDS slice, coalesced store
  __syncthreads();   // all PV reads of Vls done before reuse
  unsigned short* vs = &Vls[wv * 16 * 136];
  const float inv = 1.0f / lrun;   // valid for query q0 + r4
  float linv[4];
  #pragma unroll
  for (int rg = 0; rg < 4; rg++) linv[rg] = __shfl(inv, 4*g + rg);
  #pragma unroll
  for (int dblk = 0; dblk < 8; dblk++) {
    #pragma unroll
    for (int rg = 0; rg < 4; rg++) {
      vs[(4*g + rg)*136 + dblk*16 + r4] = f2bf(oacc[dblk][rg] * linv[rg]);
    }
  }
  #pragma unroll
  for (int p = 0; p < 4; p++) {
    const int qq = p*4 + g;
    const uint4 vvv = *(const uint4*)(vs + qq*136 + r4*8);
    *(uint4*)(O + bh + (size_t)(q0 + qq) * DNUM + r4*8) = vvv;
  }
}

// ---------------- launch ----------------
extern "C" void kernel_launch(void* const* d_in, const int* in_sizes, int n_in,
                              void* d_out, int out_size, void* d_ws, size_t ws_size,
                              hipStream_t stream) {
  (void)in_sizes; (void)n_in; (void)out_size; (void)ws_size;
  const float* x     = (const float*)d_in[0];
  const float* normw = (const float*)d_in[1];
  const float* wq = (const float*)d_in[2];
  const float* wk = (const float*)d_in[3];
  const float* wvm = (const float*)d_in[4];
  const float* wo = (const float*)d_in[5];
  const float* qA = (const float*)d_in[6];
  const float* qB = (const float*)d_in[7];
  const float* kA = (const float*)d_in[8];
  const float* kB = (const float*)d_in[9];
  const float* vA = (const float*)d_in[10];
  const float* vB = (const float*)d_in[11];
  const float* oA = (const float*)d_in[12];
  const float* oB = (const float*)d_in[13];

  char* w = (char*)d_ws;
  const size_t SZ = (size_t)MTOK * DNUM * 2;   // 16 MiB per bf16 activation
  unsigned short* h  = (unsigned short*)(w);
  unsigned short* Qb = (unsigned short*)(w + SZ);
  unsigned short* Kb = (unsigned short*)(w + 2*SZ);
  unsigned short* Vb = (unsigned short*)(w + 3*SZ);
  unsigned short* AO = (unsigned short*)(w + 4*SZ);
  unsigned short* Wq = (unsigned short*)(w + 5*SZ);
  unsigned short* Wk = Wq + (size_t)DNUM*DNUM;
  unsigned short* Wv = Wk + (size_t)DNUM*DNUM;
  unsigned short* Wo = Wv + (size_t)DNUM*DNUM;

  const float lscale = 1.0f / 16.0f;

  weff_k<<<dim3(2, 32, 4), 256, 0, stream>>>(wq, wk, wvm, wo,
                                             qB, kB, vB, oB,
                                             qA, kA, vA, oA,
                                             Wq, Wk, Wv, Wo, lscale);
  rmsnorm_k<<<dim3(4096), 256, 0, stream>>>(x, normw, h);
  gemm8p_k<<<dim3(8,16,3), 512, 0, stream>>>(h, Wq,Wk,Wv, Qb,Kb,Vb);
  rope_k<<<dim3(8192), 256, 0, stream>>>(Qb, Kb);
  attn_k<<<dim3(1024), 256, 0, stream>>>(Qb, Kb, Vb, AO);
  gemm_k<<<dim3(16,32,1), 256, 0, stream>>>(AO, Wo, x, (float*)d_out);
}

// Round 8
// 268.292 us; speedup vs baseline: 4.5283x; 1.1023x over previous
//
#include <hip/hip_runtime.h>
#include <hip/hip_bf16.h>

#define LNUM 2048
#define DNUM 2048
#define HNUM 16
#define DHNUM 128
#define MTOK 4096   // B*L
#define WINSZ 512

typedef __attribute__((ext_vector_type(8))) short bf16x8;
typedef __attribute__((ext_vector_type(4))) short bf16x4;
typedef __attribute__((ext_vector_type(4))) float f32x4;

#define GLOBAL_AS __attribute__((address_space(1)))
#define LDS_AS __attribute__((address_space(3)))
#define BARX asm volatile("s_barrier" ::: "memory")

__device__ __forceinline__ unsigned short f2bf(float f) {
  union { float f; unsigned u; } v; v.f = f;
  unsigned r = v.u + 0x7FFFu + ((v.u >> 16) & 1u);
  return (unsigned short)(r >> 16);
}
__device__ __forceinline__ float bf2f(unsigned short h) {
  union { unsigned u; float f; } v; v.u = ((unsigned)h) << 16;
  return v.f;
}

// ---------------- W_eff = W + s * Bm @ Am  (rank-16 fold), fp32 -> bf16 ----------------
__global__ __launch_bounds__(256) void weff_k(
    const float* __restrict__ w0, const float* __restrict__ w1,
    const float* __restrict__ w2, const float* __restrict__ w3,
    const float* __restrict__ b0, const float* __restrict__ b1,
    const float* __restrict__ b2, const float* __restrict__ b3,
    const float* __restrict__ a0, const float* __restrict__ a1,
    const float* __restrict__ a2, const float* __restrict__ a3,
    unsigned short* __restrict__ o0, unsigned short* __restrict__ o1,
    unsigned short* __restrict__ o2, unsigned short* __restrict__ o3,
    float s) {
  const int z = blockIdx.z;
  const float* W = z==0?w0:z==1?w1:z==2?w2:w3;
  const float* Bm = z==0?b0:z==1?b1:z==2?b2:b3;
  const float* Am = z==0?a0:z==1?a1:z==2?a2:a3;
  unsigned short* out = z==0?o0:z==1?o1:z==2?o2:o3;

  const int col = blockIdx.x * 1024 + threadIdx.x * 4;
  const int row0 = blockIdx.y * 64;

  float4 av[16];
  #pragma unroll
  for (int j = 0; j < 16; j++) av[j] = *(const float4*)(Am + (size_t)j * DNUM + col);

  for (int r = 0; r < 64; r++) {
    const int n = row0 + r;
    const float* brow = Bm + (size_t)n * 16;
    float dx = 0.f, dy = 0.f, dz = 0.f, dw = 0.f;
    #pragma unroll
    for (int j = 0; j < 16; j++) {
      const float bj = brow[j];
      dx = fmaf(bj, av[j].x, dx); dy = fmaf(bj, av[j].y, dy);
      dz = fmaf(bj, av[j].z, dz); dw = fmaf(bj, av[j].w, dw);
    }
    const float4 wv = *(const float4*)(W + (size_t)n * DNUM + col);
    ushort4 o;
    o.x = f2bf(wv.x + s*dx); o.y = f2bf(wv.y + s*dy);
    o.z = f2bf(wv.z + s*dz); o.w = f2bf(wv.w + s*dw);
    *(ushort4*)(out + (size_t)n * DNUM + col) = o;
  }
}

// ---------------- RMSNorm -> bf16 ----------------
__global__ __launch_bounds__(256) void rmsnorm_k(const float* __restrict__ x,
                                                 const float* __restrict__ w,
                                                 unsigned short* __restrict__ h) {
  const int row = blockIdx.x;
  const int t = threadIdx.x;
  const float4* xr = (const float4*)(x + (size_t)row * DNUM);
  float4 v0 = xr[t];
  float4 v1 = xr[t + 256];
  float ss = v0.x*v0.x + v0.y*v0.y + v0.z*v0.z + v0.w*v0.w +
             v1.x*v1.x + v1.y*v1.y + v1.z*v1.z + v1.w*v1.w;
  #pragma unroll
  for (int off = 32; off > 0; off >>= 1) ss += __shfl_xor(ss, off);
  __shared__ float red[4];
  if ((t & 63) == 0) red[t >> 6] = ss;
  __syncthreads();
  const float r = rsqrtf((red[0]+red[1]+red[2]+red[3]) * (1.0f/DNUM) + 1e-6f);
  const float4* wr4 = (const float4*)w;
  float4 w0 = wr4[t], w1 = wr4[t+256];
  ushort4 o0, o1;
  o0.x = f2bf(v0.x*r*w0.x); o0.y = f2bf(v0.y*r*w0.y);
  o0.z = f2bf(v0.z*r*w0.z); o0.w = f2bf(v0.w*r*w0.w);
  o1.x = f2bf(v1.x*r*w1.x); o1.y = f2bf(v1.y*r*w1.y);
  o1.z = f2bf(v1.z*r*w1.z); o1.w = f2bf(v1.w*r*w1.w);
  ushort4* hp = (ushort4*)(h + (size_t)row * DNUM);
  hp[t] = o0; hp[t + 256] = o1;
}

// ---------------- fused QKV GEMM: 256x192 tiles over N=6144, 512 blocks ----------------
// C[M=4096][N=6144] = h @ [Wq;Wk;Wv]^T, BK=64, 8 waves (2Mx4N), counted vmcnt.
// Wq/Wk/Wv contiguous in ws; Qb/Kb/Vb contiguous -> epilogue splits z = col>>11.
// Chunk layout (proven 0-conflict): 16 rows x 32 shorts; src-side XOR swizzle.
__global__ __launch_bounds__(512, 1) void gemmqkv_k(
    const unsigned short* __restrict__ Am,    // h
    const unsigned short* __restrict__ Wall,  // [6144][2048]
    unsigned short* __restrict__ Oall)        // Qb base
{
  const int row0 = blockIdx.y * 256;
  const int col0 = blockIdx.x * 192;
  const int tid = threadIdx.x;
  const int wv = tid >> 6, lane = tid & 63;
  const int wr = wv >> 2, wc = wv & 3;
  const int g = lane >> 4, r4 = lane & 15;

  __shared__ unsigned short lds[57344];  // A: buf*16384 (32 chunks), B: 32768+buf*12288 (24 chunks)

  const int rp = lane >> 2;
  const int sg8 = ((lane & 3) ^ ((rp >> 1) & 3)) * 8;

  auto stage = [&](int buf, int k0) {
    #pragma unroll
    for (int q = 0; q < 4; q++) {
      const int c = q*8 + wv;               // 0..31
      const int kh = c & 1, rc = c >> 1;    // rc 0..15
      const unsigned short* ga = Am + (size_t)(row0 + rc*16 + rp) * DNUM + k0 + kh*32 + sg8;
      __builtin_amdgcn_global_load_lds((const GLOBAL_AS void*)ga,
          (LDS_AS void*)&lds[buf*16384 + (kh*16 + rc)*512], 16, 0, 0);
    }
    #pragma unroll
    for (int q = 0; q < 3; q++) {
      const int c = q*8 + wv;               // 0..23
      const int kh = c & 1, rc = c >> 1;    // rc 0..11
      const unsigned short* gb = Wall + (size_t)(col0 + rc*16 + rp) * DNUM + k0 + kh*32 + sg8;
      __builtin_amdgcn_global_load_lds((const GLOBAL_AS void*)gb,
          (LDS_AS void*)&lds[32768 + buf*12288 + (kh*12 + rc)*512], 16, 0, 0);
    }
  };

  f32x4 acc[8][3];
  #pragma unroll
  for (int m = 0; m < 8; m++)
    #pragma unroll
    for (int n = 0; n < 3; n++) acc[m][n] = f32x4{0.f,0.f,0.f,0.f};

  const int cg = (g ^ ((r4 >> 1) & 3)) * 8;

  auto compute = [&](int buf) {
    #pragma unroll
    for (int kh = 0; kh < 2; kh++) {
      const unsigned short* As = &lds[buf*16384 + kh*8192];
      const unsigned short* Bs = &lds[32768 + buf*12288 + kh*6144];
      bf16x8 af[8], bb[3];
      #pragma unroll
      for (int m = 0; m < 8; m++)
        af[m] = *(const bf16x8*)&As[(wr*8 + m)*512 + r4*32 + cg];
      #pragma unroll
      for (int n = 0; n < 3; n++)
        bb[n] = *(const bf16x8*)&Bs[(wc*3 + n)*512 + r4*32 + cg];
      #pragma unroll
      for (int m = 0; m < 8; m++)
        #pragma unroll
        for (int n = 0; n < 3; n++)
          acc[m][n] = __builtin_amdgcn_mfma_f32_16x16x32_bf16(af[m], bb[n], acc[m][n], 0, 0, 0);
    }
  };

  stage(0, 0);
  const int nt = DNUM / 64;  // 32
  for (int t = 0; t < nt; t++) {
    if (t < nt - 1) {
      stage((t + 1) & 1, (t + 1) * 64);
      asm volatile("s_waitcnt vmcnt(7)" ::: "memory");  // keep next tile's 7 in flight
    } else {
      asm volatile("s_waitcnt vmcnt(0)" ::: "memory");
    }
    BARX;
    compute(t & 1);
    BARX;
  }

  #pragma unroll
  for (int m = 0; m < 8; m++) {
    #pragma unroll
    for (int rg = 0; rg < 4; rg++) {
      const int row = row0 + wr*128 + m*16 + 4*g + rg;
      #pragma unroll
      for (int n = 0; n < 3; n++) {
        const int colg = col0 + wc*48 + n*16 + r4;
        const int z = colg >> 11, c = colg & 2047;
        Oall[((size_t)z * MTOK + row) * DNUM + c] = f2bf(acc[m][n][rg]);
      }
    }
  }
}

// ---------------- 128x128-tile GEMM (m97 structure), final O-proj ----------------
__global__ __launch_bounds__(256, 3) void gemm_k(
    const unsigned short* __restrict__ Am,
    const unsigned short* __restrict__ W0,
    const float* __restrict__ resid, float* __restrict__ Of)
{
  const unsigned short* W = W0;

  const int row0 = blockIdx.y * 128;
  const int col0 = blockIdx.x * 128;
  const int tid = threadIdx.x;
  const int wv = tid >> 6, lane = tid & 63;
  const int wr = wv >> 1, wc = wv & 1;
  const int g = lane >> 4, r4 = lane & 15;

  __shared__ unsigned short lds[2][2][4096];

  f32x4 acc[4][4];
  #pragma unroll
  for (int m=0;m<4;m++)
    #pragma unroll
    for (int n=0;n<4;n++) acc[m][n] = f32x4{0.f,0.f,0.f,0.f};

  auto stage = [&](int buf, int k0) {
    #pragma unroll
    for (int qq = 0; qq < 2; qq++) {
      const int chunk = wv*2 + qq;
      const int rp = chunk*16 + (lane >> 2);
      const int cl = (lane & 3) ^ ((rp >> 1) & 3);
      const unsigned short* ga = Am + (size_t)(row0 + rp) * DNUM + k0 + cl*8;
      __builtin_amdgcn_global_load_lds((const GLOBAL_AS void*)ga,
          (LDS_AS void*)&lds[buf][0][chunk*512], 16, 0, 0);
      const unsigned short* gb = W + (size_t)(col0 + rp) * DNUM + k0 + cl*8;
      __builtin_amdgcn_global_load_lds((const GLOBAL_AS void*)gb,
          (LDS_AS void*)&lds[buf][1][chunk*512], 16, 0, 0);
    }
  };

  stage(0, 0);
  const int nk = DNUM / 32;
  for (int kt = 0; kt < nk; kt++) {
    __syncthreads();
    if (kt + 1 < nk) stage((kt+1) & 1, (kt+1)*32);
    const unsigned short* As = &lds[kt&1][0][0];
    const unsigned short* Bs = &lds[kt&1][1][0];
    bf16x8 af[4], bb[4];
    #pragma unroll
    for (int m = 0; m < 4; m++) {
      const int R = wr*64 + m*16 + r4;
      af[m] = *(const bf16x8*)((const char*)As + R*64 + ((g ^ ((R>>1)&3))*16));
    }
    #pragma unroll
    for (int n = 0; n < 4; n++) {
      const int R = wc*64 + n*16 + r4;
      bb[n] = *(const bf16x8*)((const char*)Bs + R*64 + ((g ^ ((R>>1)&3))*16));
    }
    #pragma unroll
    for (int m = 0; m < 4; m++)
      #pragma unroll
      for (int n = 0; n < 4; n++)
        acc[m][n] = __builtin_amdgcn_mfma_f32_16x16x32_bf16(af[m], bb[n], acc[m][n], 0, 0, 0);
  }

  #pragma unroll
  for (int m = 0; m < 4; m++) {
    #pragma unroll
    for (int rg = 0; rg < 4; rg++) {
      const int row = row0 + wr*64 + m*16 + 4*g + rg;
      #pragma unroll
      for (int n = 0; n < 4; n++) {
        const int col = col0 + wc*64 + n*16 + r4;
        Of[(size_t)row * DNUM + col] = acc[m][n][rg] + resid[(size_t)row * DNUM + col];
      }
    }
  }
}

// ---------------- RoPE in-place (Q also pre-scaled by 1/sqrt(DH)) ----------------
__global__ __launch_bounds__(256) void rope_k(unsigned short* __restrict__ Qm,
                                              unsigned short* __restrict__ Km) {
  const int u = blockIdx.x * 256 + threadIdx.x;
  const int t2 = u & 31;
  const int hh = (u >> 5) & (HNUM-1);
  const int i = u >> 9;
  const int l = i & (LNUM - 1);
  const int d0 = 2 * t2;
  const float C = 0.14391156831212787f;  // ln(10000)/64
  const float th0 = __expf(-(float)d0 * C);
  const float th1 = __expf(-(float)(d0+1) * C);
  float sn0, cs0, sn1, cs1;
  __sincosf((float)l * th0, &sn0, &cs0);
  __sincosf((float)l * th1, &sn1, &cs1);
  const size_t base = (size_t)i * DNUM + hh * DHNUM + d0;
  const float qs = 0.08838834764831845f;  // 1/sqrt(128)

  unsigned qa = *(const unsigned*)(Qm + base);
  unsigned qb = *(const unsigned*)(Qm + base + 64);
  float a0 = bf2f((unsigned short)qa), a1 = bf2f((unsigned short)(qa >> 16));
  float b0 = bf2f((unsigned short)qb), b1 = bf2f((unsigned short)(qb >> 16));
  unsigned lo = (unsigned)f2bf((a0*cs0 - b0*sn0) * qs) | ((unsigned)f2bf((a1*cs1 - b1*sn1) * qs) << 16);
  unsigned hi = (unsigned)f2bf((b0*cs0 + a0*sn0) * qs) | ((unsigned)f2bf((b1*cs1 + a1*sn1) * qs) << 16);
  *(unsigned*)(Qm + base) = lo;
  *(unsigned*)(Qm + base + 64) = hi;

  unsigned ka = *(const unsigned*)(Km + base);
  unsigned kb = *(const unsigned*)(Km + base + 64);
  a0 = bf2f((unsigned short)ka); a1 = bf2f((unsigned short)(ka >> 16));
  b0 = bf2f((unsigned short)kb); b1 = bf2f((unsigned short)(kb >> 16));
  lo = (unsigned)f2bf(a0*cs0 - b0*sn0) | ((unsigned)f2bf(a1*cs1 - b1*sn1) << 16);
  hi = (unsigned)f2bf(b0*cs0 + a0*sn0) | ((unsigned)f2bf(b1*cs1 + a1*sn1) << 16);
  *(unsigned*)(Km + base) = lo;
  *(unsigned*)(Km + base + 64) = hi;
}

// ---------------- sliding-window flash attention (transposed-V, swapped PV) ----------------
// Block = 64 q (4 waves x 16). K staged in chunk-swizzled LDS (as before).
// V staged TRANSPOSED: Vt[d][key], row stride 68 shorts (b64-aligned), written
// as packed b32 key-pairs (bank-checked ~2-way). PV is operand-swapped:
// oacc[dblk] = mfma(vf, pf): A = V^T (row=d on r4, k=key 4g+j -> vf = b64 from
// Vt), B = P^T (pf unchanged). Output D then has q ON r4 -> sc_old, 1/l are
// LANE-LOCAL (no shuffles); lane holds O[q=r4][d=dblk*16+4g+rg].
__global__ __launch_bounds__(256) void attn_k(const unsigned short* __restrict__ Q,
                                              const unsigned short* __restrict__ K,
                                              const unsigned short* __restrict__ V,
                                              unsigned short* __restrict__ O) {
  __shared__ unsigned short Kls[8192];   // 16 chunks x 512 (chunk = [dchunk][keychunk])
  __shared__ unsigned short Vt[8704];    // [d 0..127] x stride 68 (64 keys + pad 4)
  const int tid = threadIdx.x, wv = tid >> 6, lane = tid & 63;
  const int g = lane >> 4, r4 = lane & 15;
  const int bidx = blockIdx.x;
  const int q4 = bidx & 31, hh = (bidx >> 5) & 15, b = bidx >> 9;
  const int q_base = q4 * 64;
  const int q0 = q_base + wv * 16;
  const size_t bh = (size_t)b * LNUM * DNUM + (size_t)hh * DHNUM;

  // Q fragments (B-operand of swapped QK^T): lane holds Q[q0+r4][dc*32+g*8 ..+7]
  bf16x8 qf[4];
  {
    const unsigned short* qr = Q + bh + (size_t)(q0 + r4) * DNUM;
    #pragma unroll
    for (int dc = 0; dc < 4; dc++) qf[dc] = *(const bf16x8*)(qr + dc*32 + g*8);
  }
  f32x4 oacc[8];
  #pragma unroll
  for (int c = 0; c < 8; c++) oacc[c] = f32x4{0.f,0.f,0.f,0.f};
  float mrun = -1e30f, lrun = 0.f;

  const int qi = q0 + r4;
  const int lo_key = (q_base >= WINSZ) ? (q_base - WINSZ + 1) : 0;
  const int t_lo = lo_key >> 6, t_hi = q_base >> 6;

  const int rp = lane >> 2;
  const int sg = (((lane & 3) ^ ((rp >> 1) & 3))) * 8;   // src-side chunk swizzle
  const int cgr = (g ^ ((r4 >> 1) & 3)) * 8;             // read-side position

  const int vc = wv*8 + (lane >> 3);   // key-pair index 0..31
  const int vd = lane & 7;             // dgroup low

  for (int t64 = t_lo; t64 <= t_hi; t64++) {
    const int k64 = t64 * 64;
    __syncthreads();   // previous tile's LDS reads complete
    // stage K (chunk-swizzled, global_load_lds)
    #pragma unroll
    for (int q = 0; q < 4; q++) {
      const unsigned short* src = K + bh + (size_t)(k64 + wv*16 + rp) * DNUM + q*32 + sg;
      __builtin_amdgcn_global_load_lds((const GLOBAL_AS void*)src,
          (LDS_AS void*)&Kls[(q*4 + wv)*512], 16, 0, 0);
    }
    // stage V transposed: key-pair vc, dgroups vd and vd+8
    #pragma unroll
    for (int p = 0; p < 2; p++) {
      const int d0 = (vd + 8*p) * 8;
      const unsigned short* vp = V + bh + (size_t)(k64 + 2*vc) * DNUM + d0;
      uint4 va = *(const uint4*)vp;
      uint4 vb = *(const uint4*)(vp + DNUM);
      const unsigned short* as = (const unsigned short*)&va;
      const unsigned short* bs = (const unsigned short*)&vb;
      #pragma unroll
      for (int j = 0; j < 8; j++) {
        *(unsigned*)&Vt[(d0 + j)*68 + 2*vc] = (unsigned)as[j] | ((unsigned)bs[j] << 16);
      }
    }
    __syncthreads();   // drains gll (vmcnt) + ds_writes (lgkm)

    #pragma unroll
    for (int kts = 0; kts < 4; kts++) {
      const int k0s = k64 + kts*16;
      if (k0s > q0 + 15 || k0s + 15 < q0 - (WINSZ - 1)) continue;  // wave-uniform
      // S^T = K . Q^T  (D: row=key=4g+reg, col=q=r4)
      f32x4 st = f32x4{0.f,0.f,0.f,0.f};
      #pragma unroll
      for (int dc = 0; dc < 4; dc++) {
        const bf16x8 kf = *(const bf16x8*)&Kls[(dc*4 + kts)*512 + r4*32 + cgr];
        st = __builtin_amdgcn_mfma_f32_16x16x32_bf16(kf, qf[dc], st, 0, 0, 0);
      }
      // mask + online softmax (per q = r4)
      const int kj = k0s + 4*g;
      const float sv0 = (kj   <= qi && kj   > qi - WINSZ) ? st[0] : -1e30f;
      const float sv1 = (kj+1 <= qi && kj+1 > qi - WINSZ) ? st[1] : -1e30f;
      const float sv2 = (kj+2 <= qi && kj+2 > qi - WINSZ) ? st[2] : -1e30f;
      const float sv3 = (kj+3 <= qi && kj+3 > qi - WINSZ) ? st[3] : -1e30f;
      float pmax = fmaxf(fmaxf(sv0, sv1), fmaxf(sv2, sv3));
      pmax = fmaxf(pmax, __shfl_xor(pmax, 16));
      pmax = fmaxf(pmax, __shfl_xor(pmax, 32));
      const float mnew = fmaxf(mrun, pmax);
      const float sc_old = __expf(mrun - mnew);   // per query r4 (lane-local now)
      const float p0 = __expf(sv0 - mnew), p1 = __expf(sv1 - mnew);
      const float p2 = __expf(sv2 - mnew), p3 = __expf(sv3 - mnew);
      float psum = p0 + p1 + p2 + p3;
      psum += __shfl_xor(psum, 16);
      psum += __shfl_xor(psum, 32);
      lrun = lrun * sc_old + psum;
      mrun = mnew;
      bf16x4 pf;
      pf[0] = (short)f2bf(p0); pf[1] = (short)f2bf(p1);
      pf[2] = (short)f2bf(p2); pf[3] = (short)f2bf(p3);
      // rescale: q = r4 for ALL of this lane's oacc -> plain scalar multiply
      #pragma unroll
      for (int c = 0; c < 8; c++) {
        oacc[c][0] *= sc_old; oacc[c][1] *= sc_old;
        oacc[c][2] *= sc_old; oacc[c][3] *= sc_old;
      }
      // PV swapped: O^T[d][q] += V^T . P^T  (A = vf from Vt, B = pf)
      #pragma unroll
      for (int dblk = 0; dblk < 8; dblk++) {
        const bf16x4 vf = *(const bf16x4*)&Vt[(dblk*16 + r4)*68 + kts*16 + 4*g];
        oacc[dblk] = __builtin_amdgcn_mfma_f32_16x16x16bf16_1k(vf, pf, oacc[dblk], 0, 0, 0);
      }
    }
  }

  // epilogue: lane holds O[q=r4][d=dblk*16+4g+rg]; normalize lane-locally,
  // transpose via per-wave LDS slice, coalesced store
  __syncthreads();
  unsigned short* scr = &Vt[wv * 2176];   // 16 q-rows x 136 shorts
  const float inv = 1.0f / lrun;
  #pragma unroll
  for (int dblk = 0; dblk < 8; dblk++) {
    #pragma unroll
    for (int rg = 0; rg < 4; rg++) {
      scr[r4*136 + dblk*16 + 4*g + rg] = f2bf(oacc[dblk][rg] * inv);
    }
  }
  #pragma unroll
  for (int p = 0; p < 4; p++) {
    const int qq = p*4 + g;
    const uint4 vvv = *(const uint4*)(scr + qq*136 + r4*8);
    *(uint4*)(O + bh + (size_t)(q0 + qq) * DNUM + r4*8) = vvv;
  }
}

// ---------------- launch ----------------
extern "C" void kernel_launch(void* const* d_in, const int* in_sizes, int n_in,
                              void* d_out, int out_size, void* d_ws, size_t ws_size,
                              hipStream_t stream) {
  (void)in_sizes; (void)n_in; (void)out_size; (void)ws_size;
  const float* x     = (const float*)d_in[0];
  const float* normw = (const float*)d_in[1];
  const float* wq = (const float*)d_in[2];
  const float* wk = (const float*)d_in[3];
  const float* wvm = (const float*)d_in[4];
  const float* wo = (const float*)d_in[5];
  const float* qA = (const float*)d_in[6];
  const float* qB = (const float*)d_in[7];
  const float* kA = (const float*)d_in[8];
  const float* kB = (const float*)d_in[9];
  const float* vA = (const float*)d_in[10];
  const float* vB = (const float*)d_in[11];
  const float* oA = (const float*)d_in[12];
  const float* oB = (const float*)d_in[13];

  char* w = (char*)d_ws;
  const size_t SZ = (size_t)MTOK * DNUM * 2;   // 16 MiB per bf16 activation
  unsigned short* h  = (unsigned short*)(w);
  unsigned short* Qb = (unsigned short*)(w + SZ);        // Qb,Kb,Vb contiguous
  unsigned short* Kb = (unsigned short*)(w + 2*SZ);
  unsigned short* Vb = (unsigned short*)(w + 3*SZ);
  unsigned short* AO = (unsigned short*)(w + 4*SZ);
  unsigned short* Wq = (unsigned short*)(w + 5*SZ);      // Wq,Wk,Wv,Wo contiguous
  unsigned short* Wk = Wq + (size_t)DNUM*DNUM;
  unsigned short* Wv = Wk + (size_t)DNUM*DNUM;
  unsigned short* Wo = Wv + (size_t)DNUM*DNUM;

  const float lscale = 1.0f / 16.0f;

  weff_k<<<dim3(2, 32, 4), 256, 0, stream>>>(wq, wk, wvm, wo,
                                             qB, kB, vB, oB,
                                             qA, kA, vA, oA,
                                             Wq, Wk, Wv, Wo, lscale);
  rmsnorm_k<<<dim3(4096), 256, 0, stream>>>(x, normw, h);
  gemmqkv_k<<<dim3(32, 16), 512, 0, stream>>>(h, Wq, Qb);
  rope_k<<<dim3(8192), 256, 0, stream>>>(Qb, Kb);
  attn_k<<<dim3(1024), 256, 0, stream>>>(Qb, Kb, Vb, AO);
  gemm_k<<<dim3(16,32,1), 256, 0, stream>>>(AO, Wo, x, (float*)d_out);
}

// Round 10
// 260.240 us; speedup vs baseline: 4.6684x; 1.0309x over previous
//
#include <hip/hip_runtime.h>
#include <hip/hip_bf16.h>

#define LNUM 2048
#define DNUM 2048
#define HNUM 16
#define DHNUM 128
#define MTOK 4096   // B*L
#define WINSZ 512

typedef __attribute__((ext_vector_type(8))) short bf16x8;
typedef __attribute__((ext_vector_type(4))) short bf16x4;
typedef __attribute__((ext_vector_type(4))) float f32x4;

#define GLOBAL_AS __attribute__((address_space(1)))
#define LDS_AS __attribute__((address_space(3)))
#define BARX asm volatile("s_barrier" ::: "memory")

__device__ __forceinline__ unsigned short f2bf(float f) {
  union { float f; unsigned u; } v; v.f = f;
  unsigned r = v.u + 0x7FFFu + ((v.u >> 16) & 1u);
  return (unsigned short)(r >> 16);
}
__device__ __forceinline__ float bf2f(unsigned short h) {
  union { unsigned u; float f; } v; v.u = ((unsigned)h) << 16;
  return v.f;
}

// ---------------- W_eff = W + s * Bm @ Am  (rank-16 fold), fp32 -> bf16 ----------------
__global__ __launch_bounds__(256) void weff_k(
    const float* __restrict__ w0, const float* __restrict__ w1,
    const float* __restrict__ w2, const float* __restrict__ w3,
    const float* __restrict__ b0, const float* __restrict__ b1,
    const float* __restrict__ b2, const float* __restrict__ b3,
    const float* __restrict__ a0, const float* __restrict__ a1,
    const float* __restrict__ a2, const float* __restrict__ a3,
    unsigned short* __restrict__ o0, unsigned short* __restrict__ o1,
    unsigned short* __restrict__ o2, unsigned short* __restrict__ o3,
    float s) {
  const int z = blockIdx.z;
  const float* W = z==0?w0:z==1?w1:z==2?w2:w3;
  const float* Bm = z==0?b0:z==1?b1:z==2?b2:b3;
  const float* Am = z==0?a0:z==1?a1:z==2?a2:a3;
  unsigned short* out = z==0?o0:z==1?o1:z==2?o2:o3;

  const int col = blockIdx.x * 1024 + threadIdx.x * 4;
  const int row0 = blockIdx.y * 64;

  float4 av[16];
  #pragma unroll
  for (int j = 0; j < 16; j++) av[j] = *(const float4*)(Am + (size_t)j * DNUM + col);

  for (int r = 0; r < 64; r++) {
    const int n = row0 + r;
    const float* brow = Bm + (size_t)n * 16;
    float dx = 0.f, dy = 0.f, dz = 0.f, dw = 0.f;
    #pragma unroll
    for (int j = 0; j < 16; j++) {
      const float bj = brow[j];
      dx = fmaf(bj, av[j].x, dx); dy = fmaf(bj, av[j].y, dy);
      dz = fmaf(bj, av[j].z, dz); dw = fmaf(bj, av[j].w, dw);
    }
    const float4 wv = *(const float4*)(W + (size_t)n * DNUM + col);
    ushort4 o;
    o.x = f2bf(wv.x + s*dx); o.y = f2bf(wv.y + s*dy);
    o.z = f2bf(wv.z + s*dz); o.w = f2bf(wv.w + s*dw);
    *(ushort4*)(out + (size_t)n * DNUM + col) = o;
  }
}

// ---------------- RMSNorm -> bf16 ----------------
__global__ __launch_bounds__(256) void rmsnorm_k(const float* __restrict__ x,
                                                 const float* __restrict__ w,
                                                 unsigned short* __restrict__ h) {
  const int row = blockIdx.x;
  const int t = threadIdx.x;
  const float4* xr = (const float4*)(x + (size_t)row * DNUM);
  float4 v0 = xr[t];
  float4 v1 = xr[t + 256];
  float ss = v0.x*v0.x + v0.y*v0.y + v0.z*v0.z + v0.w*v0.w +
             v1.x*v1.x + v1.y*v1.y + v1.z*v1.z + v1.w*v1.w;
  #pragma unroll
  for (int off = 32; off > 0; off >>= 1) ss += __shfl_xor(ss, off);
  __shared__ float red[4];
  if ((t & 63) == 0) red[t >> 6] = ss;
  __syncthreads();
  const float r = rsqrtf((red[0]+red[1]+red[2]+red[3]) * (1.0f/DNUM) + 1e-6f);
  const float4* wr4 = (const float4*)w;
  float4 w0 = wr4[t], w1 = wr4[t+256];
  ushort4 o0, o1;
  o0.x = f2bf(v0.x*r*w0.x); o0.y = f2bf(v0.y*r*w0.y);
  o0.z = f2bf(v0.z*r*w0.z); o0.w = f2bf(v0.w*r*w0.w);
  o1.x = f2bf(v1.x*r*w1.x); o1.y = f2bf(v1.y*r*w1.y);
  o1.z = f2bf(v1.z*r*w1.z); o1.w = f2bf(v1.w*r*w1.w);
  ushort4* hp = (ushort4*)(h + (size_t)row * DNUM);
  hp[t] = o0; hp[t + 256] = o1;
}

// ---------------- fused QKV GEMM: 256x192 tiles over N=6144, 512 blocks ----------------
__global__ __launch_bounds__(512, 1) void gemmqkv_k(
    const unsigned short* __restrict__ Am,    // h
    const unsigned short* __restrict__ Wall,  // [6144][2048]
    unsigned short* __restrict__ Oall)        // Qb base
{
  const int row0 = blockIdx.y * 256;
  const int col0 = blockIdx.x * 192;
  const int tid = threadIdx.x;
  const int wv = tid >> 6, lane = tid & 63;
  const int wr = wv >> 2, wc = wv & 3;
  const int g = lane >> 4, r4 = lane & 15;

  __shared__ unsigned short lds[57344];  // A: buf*16384, B: 32768+buf*12288

  const int rp = lane >> 2;
  const int sg8 = ((lane & 3) ^ ((rp >> 1) & 3)) * 8;

  auto stage = [&](int buf, int k0) {
    #pragma unroll
    for (int q = 0; q < 4; q++) {
      const int c = q*8 + wv;
      const int kh = c & 1, rc = c >> 1;
      const unsigned short* ga = Am + (size_t)(row0 + rc*16 + rp) * DNUM + k0 + kh*32 + sg8;
      __builtin_amdgcn_global_load_lds((const GLOBAL_AS void*)ga,
          (LDS_AS void*)&lds[buf*16384 + (kh*16 + rc)*512], 16, 0, 0);
    }
    #pragma unroll
    for (int q = 0; q < 3; q++) {
      const int c = q*8 + wv;
      const int kh = c & 1, rc = c >> 1;
      const unsigned short* gb = Wall + (size_t)(col0 + rc*16 + rp) * DNUM + k0 + kh*32 + sg8;
      __builtin_amdgcn_global_load_lds((const GLOBAL_AS void*)gb,
          (LDS_AS void*)&lds[32768 + buf*12288 + (kh*12 + rc)*512], 16, 0, 0);
    }
  };

  f32x4 acc[8][3];
  #pragma unroll
  for (int m = 0; m < 8; m++)
    #pragma unroll
    for (int n = 0; n < 3; n++) acc[m][n] = f32x4{0.f,0.f,0.f,0.f};

  const int cg = (g ^ ((r4 >> 1) & 3)) * 8;

  auto compute = [&](int buf) {
    #pragma unroll
    for (int kh = 0; kh < 2; kh++) {
      const unsigned short* As = &lds[buf*16384 + kh*8192];
      const unsigned short* Bs = &lds[32768 + buf*12288 + kh*6144];
      bf16x8 af[8], bb[3];
      #pragma unroll
      for (int m = 0; m < 8; m++)
        af[m] = *(const bf16x8*)&As[(wr*8 + m)*512 + r4*32 + cg];
      #pragma unroll
      for (int n = 0; n < 3; n++)
        bb[n] = *(const bf16x8*)&Bs[(wc*3 + n)*512 + r4*32 + cg];
      #pragma unroll
      for (int m = 0; m < 8; m++)
        #pragma unroll
        for (int n = 0; n < 3; n++)
          acc[m][n] = __builtin_amdgcn_mfma_f32_16x16x32_bf16(af[m], bb[n], acc[m][n], 0, 0, 0);
    }
  };

  stage(0, 0);
  const int nt = DNUM / 64;
  for (int t = 0; t < nt; t++) {
    if (t < nt - 1) {
      stage((t + 1) & 1, (t + 1) * 64);
      asm volatile("s_waitcnt vmcnt(7)" ::: "memory");
    } else {
      asm volatile("s_waitcnt vmcnt(0)" ::: "memory");
    }
    BARX;
    compute(t & 1);
    BARX;
  }

  #pragma unroll
  for (int m = 0; m < 8; m++) {
    #pragma unroll
    for (int rg = 0; rg < 4; rg++) {
      const int row = row0 + wr*128 + m*16 + 4*g + rg;
      #pragma unroll
      for (int n = 0; n < 3; n++) {
        const int colg = col0 + wc*48 + n*16 + r4;
        const int z = colg >> 11, c = colg & 2047;
        Oall[((size_t)z * MTOK + row) * DNUM + c] = f2bf(acc[m][n][rg]);
      }
    }
  }
}

// ---------------- O-proj GEMM: 256x128 tiles, 256 blocks = 1 round, f32+resid out ----------------
__global__ __launch_bounds__(512, 1) void gemmo_k(
    const unsigned short* __restrict__ Am,
    const unsigned short* __restrict__ W,
    const float* __restrict__ resid, float* __restrict__ Of)
{
  const int row0 = blockIdx.y * 256;
  const int col0 = blockIdx.x * 128;
  const int tid = threadIdx.x;
  const int wv = tid >> 6, lane = tid & 63;
  const int wr = wv >> 2, wc = wv & 3;
  const int g = lane >> 4, r4 = lane & 15;

  __shared__ unsigned short lds[49152];  // A: buf*16384, B: 32768+buf*8192

  const int rp = lane >> 2;
  const int sg8 = ((lane & 3) ^ ((rp >> 1) & 3)) * 8;

  auto stage = [&](int buf, int k0) {
    #pragma unroll
    for (int q = 0; q < 4; q++) {
      const int c = q*8 + wv;
      const int kh = c & 1, rc = c >> 1;   // rc 0..15
      const unsigned short* ga = Am + (size_t)(row0 + rc*16 + rp) * DNUM + k0 + kh*32 + sg8;
      __builtin_amdgcn_global_load_lds((const GLOBAL_AS void*)ga,
          (LDS_AS void*)&lds[buf*16384 + (kh*16 + rc)*512], 16, 0, 0);
    }
    #pragma unroll
    for (int q = 0; q < 2; q++) {
      const int c = q*8 + wv;
      const int kh = c & 1, rc = c >> 1;   // rc 0..7
      const unsigned short* gb = W + (size_t)(col0 + rc*16 + rp) * DNUM + k0 + kh*32 + sg8;
      __builtin_amdgcn_global_load_lds((const GLOBAL_AS void*)gb,
          (LDS_AS void*)&lds[32768 + buf*8192 + (kh*8 + rc)*512], 16, 0, 0);
    }
  };

  f32x4 acc[8][2];
  #pragma unroll
  for (int m = 0; m < 8; m++)
    #pragma unroll
    for (int n = 0; n < 2; n++) acc[m][n] = f32x4{0.f,0.f,0.f,0.f};

  const int cg = (g ^ ((r4 >> 1) & 3)) * 8;

  auto compute = [&](int buf) {
    #pragma unroll
    for (int kh = 0; kh < 2; kh++) {
      const unsigned short* As = &lds[buf*16384 + kh*8192];
      const unsigned short* Bs = &lds[32768 + buf*8192 + kh*4096];
      bf16x8 af[8], bb[2];
      #pragma unroll
      for (int m = 0; m < 8; m++)
        af[m] = *(const bf16x8*)&As[(wr*8 + m)*512 + r4*32 + cg];
      #pragma unroll
      for (int n = 0; n < 2; n++)
        bb[n] = *(const bf16x8*)&Bs[(wc*2 + n)*512 + r4*32 + cg];
      #pragma unroll
      for (int m = 0; m < 8; m++)
        #pragma unroll
        for (int n = 0; n < 2; n++)
          acc[m][n] = __builtin_amdgcn_mfma_f32_16x16x32_bf16(af[m], bb[n], acc[m][n], 0, 0, 0);
    }
  };

  stage(0, 0);
  const int nt = DNUM / 64;
  for (int t = 0; t < nt; t++) {
    if (t < nt - 1) {
      stage((t + 1) & 1, (t + 1) * 64);
      asm volatile("s_waitcnt vmcnt(6)" ::: "memory");
    } else {
      asm volatile("s_waitcnt vmcnt(0)" ::: "memory");
    }
    BARX;
    compute(t & 1);
    BARX;
  }

  #pragma unroll
  for (int m = 0; m < 8; m++) {
    #pragma unroll
    for (int rg = 0; rg < 4; rg++) {
      const int row = row0 + wr*128 + m*16 + 4*g + rg;
      #pragma unroll
      for (int n = 0; n < 2; n++) {
        const int col = col0 + wc*32 + n*16 + r4;
        Of[(size_t)row * DNUM + col] = acc[m][n][rg] + resid[(size_t)row * DNUM + col];
      }
    }
  }
}

// ---------------- RoPE in-place (Q also pre-scaled by 1/sqrt(DH)) ----------------
__global__ __launch_bounds__(256) void rope_k(unsigned short* __restrict__ Qm,
                                              unsigned short* __restrict__ Km) {
  const int u = blockIdx.x * 256 + threadIdx.x;
  const int t2 = u & 31;
  const int hh = (u >> 5) & (HNUM-1);
  const int i = u >> 9;
  const int l = i & (LNUM - 1);
  const int d0 = 2 * t2;
  const float C = 0.14391156831212787f;  // ln(10000)/64
  const float th0 = __expf(-(float)d0 * C);
  const float th1 = __expf(-(float)(d0+1) * C);
  float sn0, cs0, sn1, cs1;
  __sincosf((float)l * th0, &sn0, &cs0);
  __sincosf((float)l * th1, &sn1, &cs1);
  const size_t base = (size_t)i * DNUM + hh * DHNUM + d0;
  const float qs = 0.08838834764831845f;  // 1/sqrt(128)

  unsigned qa = *(const unsigned*)(Qm + base);
  unsigned qb = *(const unsigned*)(Qm + base + 64);
  float a0 = bf2f((unsigned short)qa), a1 = bf2f((unsigned short)(qa >> 16));
  float b0 = bf2f((unsigned short)qb), b1 = bf2f((unsigned short)(qb >> 16));
  unsigned lo = (unsigned)f2bf((a0*cs0 - b0*sn0) * qs) | ((unsigned)f2bf((a1*cs1 - b1*sn1) * qs) << 16);
  unsigned hi = (unsigned)f2bf((b0*cs0 + a0*sn0) * qs) | ((unsigned)f2bf((b1*cs1 + a1*sn1) * qs) << 16);
  *(unsigned*)(Qm + base) = lo;
  *(unsigned*)(Qm + base + 64) = hi;

  unsigned ka = *(const unsigned*)(Km + base);
  unsigned kb = *(const unsigned*)(Km + base + 64);
  a0 = bf2f((unsigned short)ka); a1 = bf2f((unsigned short)(ka >> 16));
  b0 = bf2f((unsigned short)kb); b1 = bf2f((unsigned short)(kb >> 16));
  lo = (unsigned)f2bf(a0*cs0 - b0*sn0) | ((unsigned)f2bf(a1*cs1 - b1*sn1) << 16);
  hi = (unsigned)f2bf(b0*cs0 + a0*sn0) | ((unsigned)f2bf(b1*cs1 + a1*sn1) << 16);
  *(unsigned*)(Km + base) = lo;
  *(unsigned*)(Km + base + 64) = hi;
}

// ---------------- sliding-window flash attention (transposed-V, swapped PV) ----------------
// ROUND-8 VERSION (known-passing). Block = 64 q (4 waves x 16). K staged in
// chunk-swizzled LDS. V staged TRANSPOSED: Vt[d][key], row stride 68 shorts,
// packed b32 key-pair writes. PV operand-swapped: oacc[dblk] = mfma(vf, pf)
// -> output D has q on r4 -> sc_old, 1/l lane-local.
__global__ __launch_bounds__(256) void attn_k(const unsigned short* __restrict__ Q,
                                              const unsigned short* __restrict__ K,
                                              const unsigned short* __restrict__ V,
                                              unsigned short* __restrict__ O) {
  __shared__ unsigned short Kls[8192];   // 16 chunks x 512 (chunk = [dchunk][keychunk])
  __shared__ unsigned short Vt[8704];    // [d 0..127] x stride 68 (64 keys + pad 4)
  const int tid = threadIdx.x, wv = tid >> 6, lane = tid & 63;
  const int g = lane >> 4, r4 = lane & 15;
  const int bidx = blockIdx.x;
  const int q4 = bidx & 31, hh = (bidx >> 5) & 15, b = bidx >> 9;
  const int q_base = q4 * 64;
  const int q0 = q_base + wv * 16;
  const size_t bh = (size_t)b * LNUM * DNUM + (size_t)hh * DHNUM;

  // Q fragments (B-operand of swapped QK^T): lane holds Q[q0+r4][dc*32+g*8 ..+7]
  bf16x8 qf[4];
  {
    const unsigned short* qr = Q + bh + (size_t)(q0 + r4) * DNUM;
    #pragma unroll
    for (int dc = 0; dc < 4; dc++) qf[dc] = *(const bf16x8*)(qr + dc*32 + g*8);
  }
  f32x4 oacc[8];
  #pragma unroll
  for (int c = 0; c < 8; c++) oacc[c] = f32x4{0.f,0.f,0.f,0.f};
  float mrun = -1e30f, lrun = 0.f;

  const int qi = q0 + r4;
  const int lo_key = (q_base >= WINSZ) ? (q_base - WINSZ + 1) : 0;
  const int t_lo = lo_key >> 6, t_hi = q_base >> 6;

  const int rp = lane >> 2;
  const int sg = (((lane & 3) ^ ((rp >> 1) & 3))) * 8;   // src-side chunk swizzle
  const int cgr = (g ^ ((r4 >> 1) & 3)) * 8;             // read-side position

  const int vc = wv*8 + (lane >> 3);   // key-pair index 0..31
  const int vd = lane & 7;             // dgroup low

  for (int t64 = t_lo; t64 <= t_hi; t64++) {
    const int k64 = t64 * 64;
    __syncthreads();   // previous tile's LDS reads complete
    // stage K (chunk-swizzled, global_load_lds)
    #pragma unroll
    for (int q = 0; q < 4; q++) {
      const unsigned short* src = K + bh + (size_t)(k64 + wv*16 + rp) * DNUM + q*32 + sg;
      __builtin_amdgcn_global_load_lds((const GLOBAL_AS void*)src,
          (LDS_AS void*)&Kls[(q*4 + wv)*512], 16, 0, 0);
    }
    // stage V transposed: key-pair vc, dgroups vd and vd+8
    #pragma unroll
    for (int p = 0; p < 2; p++) {
      const int d0 = (vd + 8*p) * 8;
      const unsigned short* vp = V + bh + (size_t)(k64 + 2*vc) * DNUM + d0;
      uint4 va = *(const uint4*)vp;
      uint4 vb = *(const uint4*)(vp + DNUM);
      const unsigned short* as = (const unsigned short*)&va;
      const unsigned short* bs = (const unsigned short*)&vb;
      #pragma unroll
      for (int j = 0; j < 8; j++) {
        *(unsigned*)&Vt[(d0 + j)*68 + 2*vc] = (unsigned)as[j] | ((unsigned)bs[j] << 16);
      }
    }
    __syncthreads();   // drains gll (vmcnt) + ds_writes (lgkm)

    #pragma unroll
    for (int kts = 0; kts < 4; kts++) {
      const int k0s = k64 + kts*16;
      if (k0s > q0 + 15 || k0s + 15 < q0 - (WINSZ - 1)) continue;  // wave-uniform
      // S^T = K . Q^T  (D: row=key=4g+reg, col=q=r4)
      f32x4 st = f32x4{0.f,0.f,0.f,0.f};
      #pragma unroll
      for (int dc = 0; dc < 4; dc++) {
        const bf16x8 kf = *(const bf16x8*)&Kls[(dc*4 + kts)*512 + r4*32 + cgr];
        st = __builtin_amdgcn_mfma_f32_16x16x32_bf16(kf, qf[dc], st, 0, 0, 0);
      }
      // mask + online softmax (per q = r4)
      const int kj = k0s + 4*g;
      const float sv0 = (kj   <= qi && kj   > qi - WINSZ) ? st[0] : -1e30f;
      const float sv1 = (kj+1 <= qi && kj+1 > qi - WINSZ) ? st[1] : -1e30f;
      const float sv2 = (kj+2 <= qi && kj+2 > qi - WINSZ) ? st[2] : -1e30f;
      const float sv3 = (kj+3 <= qi && kj+3 > qi - WINSZ) ? st[3] : -1e30f;
      float pmax = fmaxf(fmaxf(sv0, sv1), fmaxf(sv2, sv3));
      pmax = fmaxf(pmax, __shfl_xor(pmax, 16));
      pmax = fmaxf(pmax, __shfl_xor(pmax, 32));
      const float mnew = fmaxf(mrun, pmax);
      const float sc_old = __expf(mrun - mnew);   // per query r4 (lane-local)
      const float p0 = __expf(sv0 - mnew), p1 = __expf(sv1 - mnew);
      const float p2 = __expf(sv2 - mnew), p3 = __expf(sv3 - mnew);
      float psum = p0 + p1 + p2 + p3;
      psum += __shfl_xor(psum, 16);
      psum += __shfl_xor(psum, 32);
      lrun = lrun * sc_old + psum;
      mrun = mnew;
      bf16x4 pf;
      pf[0] = (short)f2bf(p0); pf[1] = (short)f2bf(p1);
      pf[2] = (short)f2bf(p2); pf[3] = (short)f2bf(p3);
      // rescale: q = r4 for ALL of this lane's oacc -> plain scalar multiply
      #pragma unroll
      for (int c = 0; c < 8; c++) {
        oacc[c][0] *= sc_old; oacc[c][1] *= sc_old;
        oacc[c][2] *= sc_old; oacc[c][3] *= sc_old;
      }
      // PV swapped: O^T[d][q] += V^T . P^T  (A = vf from Vt, B = pf)
      #pragma unroll
      for (int dblk = 0; dblk < 8; dblk++) {
        const bf16x4 vf = *(const bf16x4*)&Vt[(dblk*16 + r4)*68 + kts*16 + 4*g];
        oacc[dblk] = __builtin_amdgcn_mfma_f32_16x16x16bf16_1k(vf, pf, oacc[dblk], 0, 0, 0);
      }
    }
  }

  // epilogue: lane holds O[q=r4][d=dblk*16+4g+rg]; normalize lane-locally,
  // transpose via per-wave LDS slice, coalesced store
  __syncthreads();
  unsigned short* scr = &Vt[wv * 2176];   // 16 q-rows x 136 shorts
  const float inv = 1.0f / lrun;
  #pragma unroll
  for (int dblk = 0; dblk < 8; dblk++) {
    #pragma unroll
    for (int rg = 0; rg < 4; rg++) {
      scr[r4*136 + dblk*16 + 4*g + rg] = f2bf(oacc[dblk][rg] * inv);
    }
  }
  #pragma unroll
  for (int p = 0; p < 4; p++) {
    const int qq = p*4 + g;
    const uint4 vvv = *(const uint4*)(scr + qq*136 + r4*8);
    *(uint4*)(O + bh + (size_t)(q0 + qq) * DNUM + r4*8) = vvv;
  }
}

// ---------------- launch ----------------
extern "C" void kernel_launch(void* const* d_in, const int* in_sizes, int n_in,
                              void* d_out, int out_size, void* d_ws, size_t ws_size,
                              hipStream_t stream) {
  (void)in_sizes; (void)n_in; (void)out_size; (void)ws_size;
  const float* x     = (const float*)d_in[0];
  const float* normw = (const float*)d_in[1];
  const float* wq = (const float*)d_in[2];
  const float* wk = (const float*)d_in[3];
  const float* wvm = (const float*)d_in[4];
  const float* wo = (const float*)d_in[5];
  const float* qA = (const float*)d_in[6];
  const float* qB = (const float*)d_in[7];
  const float* kA = (const float*)d_in[8];
  const float* kB = (const float*)d_in[9];
  const float* vA = (const float*)d_in[10];
  const float* vB = (const float*)d_in[11];
  const float* oA = (const float*)d_in[12];
  const float* oB = (const float*)d_in[13];

  char* w = (char*)d_ws;
  const size_t SZ = (size_t)MTOK * DNUM * 2;   // 16 MiB per bf16 activation
  unsigned short* h  = (unsigned short*)(w);
  unsigned short* Qb = (unsigned short*)(w + SZ);        // Qb,Kb,Vb contiguous
  unsigned short* Kb = (unsigned short*)(w + 2*SZ);
  unsigned short* Vb = (unsigned short*)(w + 3*SZ);
  unsigned short* AO = (unsigned short*)(w + 4*SZ);
  unsigned short* Wq = (unsigned short*)(w + 5*SZ);      // Wq,Wk,Wv,Wo contiguous
  unsigned short* Wk = Wq + (size_t)DNUM*DNUM;
  unsigned short* Wv = Wk + (size_t)DNUM*DNUM;
  unsigned short* Wo = Wv + (size_t)DNUM*DNUM;

  const float lscale = 1.0f / 16.0f;

  weff_k<<<dim3(2, 32, 4), 256, 0, stream>>>(wq, wk, wvm, wo,
                                             qB, kB, vB, oB,
                                             qA, kA, vA, oA,
                                             Wq, Wk, Wv, Wo, lscale);
  rmsnorm_k<<<dim3(4096), 256, 0, stream>>>(x, normw, h);
  gemmqkv_k<<<dim3(32, 16), 512, 0, stream>>>(h, Wq, Qb);
  rope_k<<<dim3(8192), 256, 0, stream>>>(Qb, Kb);
  attn_k<<<dim3(1024), 256, 0, stream>>>(Qb, Kb, Vb, AO);
  gemmo_k<<<dim3(16, 16), 512, 0, stream>>>(AO, Wo, x, (float*)d_out);
}

// Round 12
// 223.281 us; speedup vs baseline: 5.4412x; 1.1655x over previous
//
#include <hip/hip_runtime.h>
#include <hip/hip_bf16.h>

#define LNUM 2048
#define DNUM 2048
#define HNUM 16
#define DHNUM 128
#define MTOK 4096   // B*L
#define WINSZ 512

typedef __attribute__((ext_vector_type(8))) short bf16x8;
typedef __attribute__((ext_vector_type(4))) short bf16x4;
typedef __attribute__((ext_vector_type(4))) float f32x4;

#define GLOBAL_AS __attribute__((address_space(1)))
#define LDS_AS __attribute__((address_space(3)))
#define BARX asm volatile("s_barrier" ::: "memory")

__device__ __forceinline__ unsigned short f2bf(float f) {
  union { float f; unsigned u; } v; v.f = f;
  unsigned r = v.u + 0x7FFFu + ((v.u >> 16) & 1u);
  return (unsigned short)(r >> 16);
}
__device__ __forceinline__ float bf2f(unsigned short h) {
  union { unsigned u; float f; } v; v.u = ((unsigned)h) << 16;
  return v.f;
}

// ---------------- W_eff = W + s * Bm @ Am  (rank-16 fold), fp32 -> bf16 ----------------
__global__ __launch_bounds__(256) void weff_k(
    const float* __restrict__ w0, const float* __restrict__ w1,
    const float* __restrict__ w2, const float* __restrict__ w3,
    const float* __restrict__ b0, const float* __restrict__ b1,
    const float* __restrict__ b2, const float* __restrict__ b3,
    const float* __restrict__ a0, const float* __restrict__ a1,
    const float* __restrict__ a2, const float* __restrict__ a3,
    unsigned short* __restrict__ o0, unsigned short* __restrict__ o1,
    unsigned short* __restrict__ o2, unsigned short* __restrict__ o3,
    float s) {
  const int z = blockIdx.z;
  const float* W = z==0?w0:z==1?w1:z==2?w2:w3;
  const float* Bm = z==0?b0:z==1?b1:z==2?b2:b3;
  const float* Am = z==0?a0:z==1?a1:z==2?a2:a3;
  unsigned short* out = z==0?o0:z==1?o1:z==2?o2:o3;

  const int col = blockIdx.x * 1024 + threadIdx.x * 4;
  const int row0 = blockIdx.y * 16;

  float4 av[16];
  #pragma unroll
  for (int j = 0; j < 16; j++) av[j] = *(const float4*)(Am + (size_t)j * DNUM + col);

  for (int r = 0; r < 16; r++) {
    const int n = row0 + r;
    const float* brow = Bm + (size_t)n * 16;
    float dx = 0.f, dy = 0.f, dz = 0.f, dw = 0.f;
    #pragma unroll
    for (int j = 0; j < 16; j++) {
      const float bj = brow[j];
      dx = fmaf(bj, av[j].x, dx); dy = fmaf(bj, av[j].y, dy);
      dz = fmaf(bj, av[j].z, dz); dw = fmaf(bj, av[j].w, dw);
    }
    const float4 wv = *(const float4*)(W + (size_t)n * DNUM + col);
    ushort4 o;
    o.x = f2bf(wv.x + s*dx); o.y = f2bf(wv.y + s*dy);
    o.z = f2bf(wv.z + s*dz); o.w = f2bf(wv.w + s*dw);
    *(ushort4*)(out + (size_t)n * DNUM + col) = o;
  }
}

// ---------------- RMSNorm -> bf16 ----------------
__global__ __launch_bounds__(256) void rmsnorm_k(const float* __restrict__ x,
                                                 const float* __restrict__ w,
                                                 unsigned short* __restrict__ h) {
  const int row = blockIdx.x;
  const int t = threadIdx.x;
  const float4* xr = (const float4*)(x + (size_t)row * DNUM);
  float4 v0 = xr[t];
  float4 v1 = xr[t + 256];
  float ss = v0.x*v0.x + v0.y*v0.y + v0.z*v0.z + v0.w*v0.w +
             v1.x*v1.x + v1.y*v1.y + v1.z*v1.z + v1.w*v1.w;
  #pragma unroll
  for (int off = 32; off > 0; off >>= 1) ss += __shfl_xor(ss, off);
  __shared__ float red[4];
  if ((t & 63) == 0) red[t >> 6] = ss;
  __syncthreads();
  const float r = rsqrtf((red[0]+red[1]+red[2]+red[3]) * (1.0f/DNUM) + 1e-6f);
  const float4* wr4 = (const float4*)w;
  float4 w0 = wr4[t], w1 = wr4[t+256];
  ushort4 o0, o1;
  o0.x = f2bf(v0.x*r*w0.x); o0.y = f2bf(v0.y*r*w0.y);
  o0.z = f2bf(v0.z*r*w0.z); o0.w = f2bf(v0.w*r*w0.w);
  o1.x = f2bf(v1.x*r*w1.x); o1.y = f2bf(v1.y*r*w1.y);
  o1.z = f2bf(v1.z*r*w1.z); o1.w = f2bf(v1.w*r*w1.w);
  ushort4* hp = (ushort4*)(h + (size_t)row * DNUM);
  hp[t] = o0; hp[t + 256] = o1;
}

// ---------------- fused QKV GEMM: 256x192 tiles over N=6144, 512 blocks ----------------
__global__ __launch_bounds__(512, 1) void gemmqkv_k(
    const unsigned short* __restrict__ Am,    // h
    const unsigned short* __restrict__ Wall,  // [6144][2048]
    unsigned short* __restrict__ Oall)        // Qb base
{
  const int row0 = blockIdx.y * 256;
  const int col0 = blockIdx.x * 192;
  const int tid = threadIdx.x;
  const int wv = tid >> 6, lane = tid & 63;
  const int wr = wv >> 2, wc = wv & 3;
  const int g = lane >> 4, r4 = lane & 15;

  __shared__ unsigned short lds[57344];  // A: buf*16384, B: 32768+buf*12288

  const int rp = lane >> 2;
  const int sg8 = ((lane & 3) ^ ((rp >> 1) & 3)) * 8;

  auto stage = [&](int buf, int k0) {
    #pragma unroll
    for (int q = 0; q < 4; q++) {
      const int c = q*8 + wv;
      const int kh = c & 1, rc = c >> 1;
      const unsigned short* ga = Am + (size_t)(row0 + rc*16 + rp) * DNUM + k0 + kh*32 + sg8;
      __builtin_amdgcn_global_load_lds((const GLOBAL_AS void*)ga,
          (LDS_AS void*)&lds[buf*16384 + (kh*16 + rc)*512], 16, 0, 0);
    }
    #pragma unroll
    for (int q = 0; q < 3; q++) {
      const int c = q*8 + wv;
      const int kh = c & 1, rc = c >> 1;
      const unsigned short* gb = Wall + (size_t)(col0 + rc*16 + rp) * DNUM + k0 + kh*32 + sg8;
      __builtin_amdgcn_global_load_lds((const GLOBAL_AS void*)gb,
          (LDS_AS void*)&lds[32768 + buf*12288 + (kh*12 + rc)*512], 16, 0, 0);
    }
  };

  f32x4 acc[8][3];
  #pragma unroll
  for (int m = 0; m < 8; m++)
    #pragma unroll
    for (int n = 0; n < 3; n++) acc[m][n] = f32x4{0.f,0.f,0.f,0.f};

  const int cg = (g ^ ((r4 >> 1) & 3)) * 8;

  auto compute = [&](int buf) {
    #pragma unroll
    for (int kh = 0; kh < 2; kh++) {
      const unsigned short* As = &lds[buf*16384 + kh*8192];
      const unsigned short* Bs = &lds[32768 + buf*12288 + kh*6144];
      bf16x8 af[8], bb[3];
      #pragma unroll
      for (int m = 0; m < 8; m++)
        af[m] = *(const bf16x8*)&As[(wr*8 + m)*512 + r4*32 + cg];
      #pragma unroll
      for (int n = 0; n < 3; n++)
        bb[n] = *(const bf16x8*)&Bs[(wc*3 + n)*512 + r4*32 + cg];
      #pragma unroll
      for (int m = 0; m < 8; m++)
        #pragma unroll
        for (int n = 0; n < 3; n++)
          acc[m][n] = __builtin_amdgcn_mfma_f32_16x16x32_bf16(af[m], bb[n], acc[m][n], 0, 0, 0);
    }
  };

  stage(0, 0);
  const int nt = DNUM / 64;
  for (int t = 0; t < nt; t++) {
    if (t < nt - 1) {
      stage((t + 1) & 1, (t + 1) * 64);
      asm volatile("s_waitcnt vmcnt(7)" ::: "memory");
    } else {
      asm volatile("s_waitcnt vmcnt(0)" ::: "memory");
    }
    BARX;
    compute(t & 1);
    BARX;
  }

  #pragma unroll
  for (int m = 0; m < 8; m++) {
    #pragma unroll
    for (int rg = 0; rg < 4; rg++) {
      const int row = row0 + wr*128 + m*16 + 4*g + rg;
      #pragma unroll
      for (int n = 0; n < 3; n++) {
        const int colg = col0 + wc*48 + n*16 + r4;
        const int z = colg >> 11, c = colg & 2047;
        Oall[((size_t)z * MTOK + row) * DNUM + c] = f2bf(acc[m][n][rg]);
      }
    }
  }
}

// ---------------- O-proj GEMM: 256x128 tiles, 256 blocks = 1 round, f32+resid out ----------------
__global__ __launch_bounds__(512, 1) void gemmo_k(
    const unsigned short* __restrict__ Am,
    const unsigned short* __restrict__ W,
    const float* __restrict__ resid, float* __restrict__ Of)
{
  const int row0 = blockIdx.y * 256;
  const int col0 = blockIdx.x * 128;
  const int tid = threadIdx.x;
  const int wv = tid >> 6, lane = tid & 63;
  const int wr = wv >> 2, wc = wv & 3;
  const int g = lane >> 4, r4 = lane & 15;

  __shared__ unsigned short lds[49152];  // A: buf*16384, B: 32768+buf*8192

  const int rp = lane >> 2;
  const int sg8 = ((lane & 3) ^ ((rp >> 1) & 3)) * 8;

  auto stage = [&](int buf, int k0) {
    #pragma unroll
    for (int q = 0; q < 4; q++) {
      const int c = q*8 + wv;
      const int kh = c & 1, rc = c >> 1;
      const unsigned short* ga = Am + (size_t)(row0 + rc*16 + rp) * DNUM + k0 + kh*32 + sg8;
      __builtin_amdgcn_global_load_lds((const GLOBAL_AS void*)ga,
          (LDS_AS void*)&lds[buf*16384 + (kh*16 + rc)*512], 16, 0, 0);
    }
    #pragma unroll
    for (int q = 0; q < 2; q++) {
      const int c = q*8 + wv;
      const int kh = c & 1, rc = c >> 1;
      const unsigned short* gb = W + (size_t)(col0 + rc*16 + rp) * DNUM + k0 + kh*32 + sg8;
      __builtin_amdgcn_global_load_lds((const GLOBAL_AS void*)gb,
          (LDS_AS void*)&lds[32768 + buf*8192 + (kh*8 + rc)*512], 16, 0, 0);
    }
  };

  f32x4 acc[8][2];
  #pragma unroll
  for (int m = 0; m < 8; m++)
    #pragma unroll
    for (int n = 0; n < 2; n++) acc[m][n] = f32x4{0.f,0.f,0.f,0.f};

  const int cg = (g ^ ((r4 >> 1) & 3)) * 8;

  auto compute = [&](int buf) {
    #pragma unroll
    for (int kh = 0; kh < 2; kh++) {
      const unsigned short* As = &lds[buf*16384 + kh*8192];
      const unsigned short* Bs = &lds[32768 + buf*8192 + kh*4096];
      bf16x8 af[8], bb[2];
      #pragma unroll
      for (int m = 0; m < 8; m++)
        af[m] = *(const bf16x8*)&As[(wr*8 + m)*512 + r4*32 + cg];
      #pragma unroll
      for (int n = 0; n < 2; n++)
        bb[n] = *(const bf16x8*)&Bs[(wc*2 + n)*512 + r4*32 + cg];
      #pragma unroll
      for (int m = 0; m < 8; m++)
        #pragma unroll
        for (int n = 0; n < 2; n++)
          acc[m][n] = __builtin_amdgcn_mfma_f32_16x16x32_bf16(af[m], bb[n], acc[m][n], 0, 0, 0);
    }
  };

  stage(0, 0);
  const int nt = DNUM / 64;
  for (int t = 0; t < nt; t++) {
    if (t < nt - 1) {
      stage((t + 1) & 1, (t + 1) * 64);
      asm volatile("s_waitcnt vmcnt(6)" ::: "memory");
    } else {
      asm volatile("s_waitcnt vmcnt(0)" ::: "memory");
    }
    BARX;
    compute(t & 1);
    BARX;
  }

  #pragma unroll
  for (int m = 0; m < 8; m++) {
    #pragma unroll
    for (int rg = 0; rg < 4; rg++) {
      const int row = row0 + wr*128 + m*16 + 4*g + rg;
      #pragma unroll
      for (int n = 0; n < 2; n++) {
        const int col = col0 + wc*32 + n*16 + r4;
        Of[(size_t)row * DNUM + col] = acc[m][n][rg] + resid[(size_t)row * DNUM + col];
      }
    }
  }
}

// ---------------- RoPE in-place (Q also pre-scaled by 1/sqrt(DH)) ----------------
__global__ __launch_bounds__(256) void rope_k(unsigned short* __restrict__ Qm,
                                              unsigned short* __restrict__ Km) {
  const int u = blockIdx.x * 256 + threadIdx.x;
  const int t2 = u & 31;
  const int hh = (u >> 5) & (HNUM-1);
  const int i = u >> 9;
  const int l = i & (LNUM - 1);
  const int d0 = 2 * t2;
  const float C = 0.14391156831212787f;  // ln(10000)/64
  const float th0 = __expf(-(float)d0 * C);
  const float th1 = __expf(-(float)(d0+1) * C);
  float sn0, cs0, sn1, cs1;
  __sincosf((float)l * th0, &sn0, &cs0);
  __sincosf((float)l * th1, &sn1, &cs1);
  const size_t base = (size_t)i * DNUM + hh * DHNUM + d0;
  const float qs = 0.08838834764831845f;  // 1/sqrt(128)

  unsigned qa = *(const unsigned*)(Qm + base);
  unsigned qb = *(const unsigned*)(Qm + base + 64);
  float a0 = bf2f((unsigned short)qa), a1 = bf2f((unsigned short)(qa >> 16));
  float b0 = bf2f((unsigned short)qb), b1 = bf2f((unsigned short)(qb >> 16));
  unsigned lo = (unsigned)f2bf((a0*cs0 - b0*sn0) * qs) | ((unsigned)f2bf((a1*cs1 - b1*sn1) * qs) << 16);
  unsigned hi = (unsigned)f2bf((b0*cs0 + a0*sn0) * qs) | ((unsigned)f2bf((b1*cs1 + a1*sn1) * qs) << 16);
  *(unsigned*)(Qm + base) = lo;
  *(unsigned*)(Qm + base + 64) = hi;

  unsigned ka = *(const unsigned*)(Km + base);
  unsigned kb = *(const unsigned*)(Km + base + 64);
  a0 = bf2f((unsigned short)ka); a1 = bf2f((unsigned short)(ka >> 16));
  b0 = bf2f((unsigned short)kb); b1 = bf2f((unsigned short)(kb >> 16));
  lo = (unsigned)f2bf(a0*cs0 - b0*sn0) | ((unsigned)f2bf(a1*cs1 - b1*sn1) << 16);
  hi = (unsigned)f2bf(b0*cs0 + a0*sn0) | ((unsigned)f2bf(b1*cs1 + a1*sn1) << 16);
  *(unsigned*)(Km + base) = lo;
  *(unsigned*)(Km + base + 64) = hi;
}

// ---------------- sliding-window flash attention (128q/8-wave blocks) ----------------
// Round-11 structure with the epilogue-scratch bug fixed: scratch rows hold
// 128 shorts -> stride 136, 2176 shorts/wave (8 waves = 17408). shm sized to
// max(K+V staging = 16896, epilogue = 17408) = 17408 shorts (34816 B;
// 2 blocks/CU at 512 threads).
__global__ __launch_bounds__(512) void attn_k(const unsigned short* __restrict__ Q,
                                              const unsigned short* __restrict__ K,
                                              const unsigned short* __restrict__ V,
                                              unsigned short* __restrict__ O) {
  __shared__ unsigned short shm[17408];  // Kls: [0,8192) ; Vt: [8192, 16896) ; epi reuses all
  unsigned short* Kls = shm;
  unsigned short* Vt  = shm + 8192;      // [d 0..127] x stride 68 (64 keys + pad)
  const int tid = threadIdx.x, wv = tid >> 6, lane = tid & 63;
  const int g = lane >> 4, r4 = lane & 15;
  const int bidx = blockIdx.x;
  const int q7 = bidx & 15, hh = (bidx >> 4) & 15, b = bidx >> 8;
  const int q_base = q7 * 128;
  const int q0 = q_base + wv * 16;
  const size_t bh = (size_t)b * LNUM * DNUM + (size_t)hh * DHNUM;

  // Q fragments (B-operand of swapped QK^T): lane holds Q[q0+r4][dc*32+g*8 ..+7]
  bf16x8 qf[4];
  {
    const unsigned short* qr = Q + bh + (size_t)(q0 + r4) * DNUM;
    #pragma unroll
    for (int dc = 0; dc < 4; dc++) qf[dc] = *(const bf16x8*)(qr + dc*32 + g*8);
  }
  f32x4 oacc[8];
  #pragma unroll
  for (int c = 0; c < 8; c++) oacc[c] = f32x4{0.f,0.f,0.f,0.f};
  float mrun = -1e30f, lrun = 0.f;

  const int qi = q0 + r4;
  const int t_lo = (q_base >= WINSZ) ? ((q_base - WINSZ + 1) >> 6) : 0;
  const int t_hi = (q_base + 127) >> 6;

  const int rp = lane >> 2;
  const int sg = (((lane & 3) ^ ((rp >> 1) & 3))) * 8;   // src-side chunk swizzle
  const int cgr = (g ^ ((r4 >> 1) & 3)) * 8;             // read-side position

  const int vc = tid & 31;    // key-pair 0..31
  const int vd = tid >> 5;    // d-group 0..15

  for (int t64 = t_lo; t64 <= t_hi; t64++) {
    const int k64 = t64 * 64;
    __syncthreads();   // previous tile's LDS reads complete
    // stage K (chunk-swizzled, 2 gll/wave across 8 waves)
    #pragma unroll
    for (int qq = 0; qq < 2; qq++) {
      const int c = wv*2 + qq;            // 0..15
      const int dc = c >> 2, kc = c & 3;
      const unsigned short* src = K + bh + (size_t)(k64 + kc*16 + rp) * DNUM + dc*32 + sg;
      __builtin_amdgcn_global_load_lds((const GLOBAL_AS void*)src,
          (LDS_AS void*)&Kls[(dc*4 + kc)*512], 16, 0, 0);
    }
    // stage V transposed: key-pair vc, d-group vd (one pass, 512 threads)
    {
      const int d0 = vd * 8;
      const unsigned short* vp = V + bh + (size_t)(k64 + 2*vc) * DNUM + d0;
      uint4 va = *(const uint4*)vp;
      uint4 vb = *(const uint4*)(vp + DNUM);
      const unsigned short* as = (const unsigned short*)&va;
      const unsigned short* bs = (const unsigned short*)&vb;
      #pragma unroll
      for (int j = 0; j < 8; j++) {
        *(unsigned*)&Vt[(d0 + j)*68 + 2*vc] = (unsigned)as[j] | ((unsigned)bs[j] << 16);
      }
    }
    __syncthreads();   // drains gll (vmcnt) + ds_writes (lgkm)

    #pragma unroll
    for (int kts = 0; kts < 4; kts++) {
      const int k0s = k64 + kts*16;
      if (k0s > q0 + 15 || k0s + 15 < q0 - (WINSZ - 1)) continue;  // wave-uniform
      // S^T = K . Q^T
      f32x4 st = f32x4{0.f,0.f,0.f,0.f};
      #pragma unroll
      for (int dc = 0; dc < 4; dc++) {
        const bf16x8 kf = *(const bf16x8*)&Kls[(dc*4 + kts)*512 + r4*32 + cgr];
        st = __builtin_amdgcn_mfma_f32_16x16x32_bf16(kf, qf[dc], st, 0, 0, 0);
      }
      // mask only on edge tiles (diagonal / window boundary)
      float sv0, sv1, sv2, sv3;
      const bool interior = (k0s + 15 <= q0) && (k0s >= q0 - (WINSZ - 16));
      if (interior) {
        sv0 = st[0]; sv1 = st[1]; sv2 = st[2]; sv3 = st[3];
      } else {
        const int kj = k0s + 4*g;
        sv0 = (kj   <= qi && kj   > qi - WINSZ) ? st[0] : -INFINITY;
        sv1 = (kj+1 <= qi && kj+1 > qi - WINSZ) ? st[1] : -INFINITY;
        sv2 = (kj+2 <= qi && kj+2 > qi - WINSZ) ? st[2] : -INFINITY;
        sv3 = (kj+3 <= qi && kj+3 > qi - WINSZ) ? st[3] : -INFINITY;
      }
      float pmax = fmaxf(fmaxf(sv0, sv1), fmaxf(sv2, sv3));
      pmax = fmaxf(pmax, __shfl_xor(pmax, 16));
      pmax = fmaxf(pmax, __shfl_xor(pmax, 32));
      float mnew;
      if (__all(pmax - mrun <= 8.0f)) {
        mnew = mrun;                        // defer-max: no rescale this tile
      } else {
        mnew = fmaxf(mrun, pmax);
        const float sc = __expf(mrun - mnew);
        lrun *= sc;
        #pragma unroll
        for (int c = 0; c < 8; c++) {
          oacc[c][0] *= sc; oacc[c][1] *= sc;
          oacc[c][2] *= sc; oacc[c][3] *= sc;
        }
        mrun = mnew;
      }
      const float p0 = __expf(sv0 - mnew), p1 = __expf(sv1 - mnew);
      const float p2 = __expf(sv2 - mnew), p3 = __expf(sv3 - mnew);
      float psum = p0 + p1 + p2 + p3;
      psum += __shfl_xor(psum, 16);
      psum += __shfl_xor(psum, 32);
      lrun += psum;
      bf16x4 pf;
      pf[0] = (short)f2bf(p0); pf[1] = (short)f2bf(p1);
      pf[2] = (short)f2bf(p2); pf[3] = (short)f2bf(p3);
      // PV swapped: O^T[d][q] += V^T . P^T  (A = vf from Vt, B = pf)
      #pragma unroll
      for (int dblk = 0; dblk < 8; dblk++) {
        const bf16x4 vf = *(const bf16x4*)&Vt[(dblk*16 + r4)*68 + kts*16 + 4*g];
        oacc[dblk] = __builtin_amdgcn_mfma_f32_16x16x16bf16_1k(vf, pf, oacc[dblk], 0, 0, 0);
      }
    }
  }

  // epilogue: lane holds O[q=r4][d=dblk*16+4g+rg]; normalize lane-locally,
  // transpose via per-wave LDS slice (stride 136 >= 128-short rows), store.
  __syncthreads();   // all PV/K reads done before scratch reuse
  unsigned short* scr = &shm[wv * 2176];   // 16 q-rows x 136 shorts per wave
  const float inv = 1.0f / lrun;
  #pragma unroll
  for (int dblk = 0; dblk < 8; dblk++) {
    #pragma unroll
    for (int rg = 0; rg < 4; rg++) {
      scr[r4*136 + dblk*16 + 4*g + rg] = f2bf(oacc[dblk][rg] * inv);
    }
  }
  #pragma unroll
  for (int p = 0; p < 4; p++) {
    const int qq = p*4 + g;
    const uint4 vvv = *(const uint4*)(scr + qq*136 + r4*8);
    *(uint4*)(O + bh + (size_t)(q0 + qq) * DNUM + r4*8) = vvv;
  }
}

// ---------------- launch ----------------
extern "C" void kernel_launch(void* const* d_in, const int* in_sizes, int n_in,
                              void* d_out, int out_size, void* d_ws, size_t ws_size,
                              hipStream_t stream) {
  (void)in_sizes; (void)n_in; (void)out_size; (void)ws_size;
  const float* x     = (const float*)d_in[0];
  const float* normw = (const float*)d_in[1];
  const float* wq = (const float*)d_in[2];
  const float* wk = (const float*)d_in[3];
  const float* wvm = (const float*)d_in[4];
  const float* wo = (const float*)d_in[5];
  const float* qA = (const float*)d_in[6];
  const float* qB = (const float*)d_in[7];
  const float* kA = (const float*)d_in[8];
  const float* kB = (const float*)d_in[9];
  const float* vA = (const float*)d_in[10];
  const float* vB = (const float*)d_in[11];
  const float* oA = (const float*)d_in[12];
  const float* oB = (const float*)d_in[13];

  char* w = (char*)d_ws;
  const size_t SZ = (size_t)MTOK * DNUM * 2;   // 16 MiB per bf16 activation
  unsigned short* h  = (unsigned short*)(w);
  unsigned short* Qb = (unsigned short*)(w + SZ);        // Qb,Kb,Vb contiguous
  unsigned short* Kb = (unsigned short*)(w + 2*SZ);
  unsigned short* Vb = (unsigned short*)(w + 3*SZ);
  unsigned short* AO = (unsigned short*)(w + 4*SZ);
  unsigned short* Wq = (unsigned short*)(w + 5*SZ);      // Wq,Wk,Wv,Wo contiguous
  unsigned short* Wk = Wq + (size_t)DNUM*DNUM;
  unsigned short* Wv = Wk + (size_t)DNUM*DNUM;
  unsigned short* Wo = Wv + (size_t)DNUM*DNUM;

  const float lscale = 1.0f / 16.0f;

  weff_k<<<dim3(2, 128, 4), 256, 0, stream>>>(wq, wk, wvm, wo,
                                              qB, kB, vB, oB,
                                              qA, kA, vA, oA,
                                              Wq, Wk, Wv, Wo, lscale);
  rmsnorm_k<<<dim3(4096), 256, 0, stream>>>(x, normw, h);
  gemmqkv_k<<<dim3(32, 16), 512, 0, stream>>>(h, Wq, Qb);
  rope_k<<<dim3(8192), 256, 0, stream>>>(Qb, Kb);
  attn_k<<<dim3(512), 512, 0, stream>>>(Qb, Kb, Vb, AO);
  gemmo_k<<<dim3(16, 16), 512, 0, stream>>>(AO, Wo, x, (float*)d_out);
}